// Round 3
// baseline (422.459 us; speedup 1.0000x reference)
//
#include <hip/hip_runtime.h>
#include <cstdint>
#include <cstddef>

// Problem constants
#define N0c 30000
#define F0c 128
#define Hc  256
#define Cc  16
#define N1c 3000
#define Bc  16
#define E0c 960000
#define E1c 48000
#define NALL 33000            // N0 + N1 (concatenated graphs)
#define EALL 1008000          // E0 + E1
#define EPSc 1e-5f
#define SLICE 188             // clusters per pool_b_partial slice (16*188 >= 3000)

// r17 bucket-sort CSR build: r15/r16 showed the 1M global atomicAdds are at a
// memory-side atomic throughput wall (~21/ns, 32MB sector writeback, NPART
// partitioning null). Replace with LDS-histogram bucket sort: zero global
// atomics. bucket = dst>>5 (32 nodes), NBKT=1032; NSCB=256 scatter blocks.
#define NBKT 1032
#define NSCB 256
#define EPB  3938             // edges per scatter block (256*3938 >= EALL)

static __host__ __device__ inline int cdiv_i(int a, int b) { return (a + b - 1) / b; }

// round-to-nearest-even fp32 -> bf16 (returns the 16 bf16 bits)
static __device__ inline unsigned short bfbits(float f) {
    unsigned u = __float_as_uint(f);
    return (unsigned short)((u + 0x7fffu + ((u >> 16) & 1u)) >> 16);
}

typedef short short8 __attribute__((ext_vector_type(8)));   // 8 bf16 = 4 VGPRs
typedef float floatx4 __attribute__((ext_vector_type(4)));
typedef float float2v __attribute__((ext_vector_type(2)));  // -> v_pk_fma_f32

// ---------------- prep1: bucket count (LDS hist) + indep prep work ------------
#define P1_CNT NSCB
#define P1_CVT 3750
#define P1_PW  386
#define P1_SEG 118

__global__ void prep1(const int* __restrict__ dst0, const int* __restrict__ dst1,
                      int* __restrict__ blockhist,
                      const float* __restrict__ x, unsigned short* __restrict__ xbf,
                      const float* __restrict__ W_in0, const float* __restrict__ W_h0,
                      const float* __restrict__ b0, const float* __restrict__ g0,
                      const float* __restrict__ be0, const float* __restrict__ m0,
                      const float* __restrict__ v0,
                      unsigned short* __restrict__ Wt0, unsigned short* __restrict__ Wt1,
                      float* __restrict__ sc0, float* __restrict__ sh0,
                      float* __restrict__ sc1, float* __restrict__ sh1,
                      const int* __restrict__ pool1, int* __restrict__ start0) {
    __shared__ int hist[NBKT];
    int bx = blockIdx.x, t = threadIdx.x;
    if (bx < P1_CNT) {
        for (int k = t; k < NBKT; k += 256) hist[k] = 0;
        __syncthreads();
        int e0 = bx * EPB, e1 = min(e0 + EPB, EALL);
        for (int e = e0 + t; e < e1; e += 256) {
            int d = (e < E0c) ? dst0[e] : (N0c + dst1[e - E0c]);
            atomicAdd(&hist[d >> 5], 1);
        }
        __syncthreads();
        for (int k = t; k < NBKT; k += 256) blockhist[k * NSCB + bx] = hist[k];
    } else if (bx < P1_CNT + P1_CVT) {
        int i = (bx - P1_CNT) * 256 + t;            // float4 index
        if (i >= N0c * 32) return;
        float4 v = ((const float4*)x)[i];
        ushort4 o;
        o.x = bfbits(v.x); o.y = bfbits(v.y); o.z = bfbits(v.z); o.w = bfbits(v.w);
        ((ushort4*)xbf)[i] = o;
    } else if (bx < P1_CNT + P1_CVT + P1_PW) {
        int pb = bx - P1_CNT - P1_CVT;
        if (pb < 128) {
            int i = pb * 256 + t;
            int k = i >> 8, col = i & 255;
            Wt0[col * 128 + k] = bfbits(W_in0[i]);
        } else if (pb < 384) {
            int i = (pb - 128) * 256 + t;
            int k = i >> 8, col = i & 255;
            Wt1[col * 256 + k] = bfbits(W_h0[i]);
        } else if (pb == 384) {
            float s = g0[t] * rsqrtf(v0[t] + EPSc);
            sc0[t] = s;
            sh0[t] = (b0[t] - m0[t]) * s + be0[t];
        } else {
            int tt = t + 256;
            float s = g0[tt] * rsqrtf(v0[tt] + EPSc);
            sc1[t] = s;
            sh1[t] = (b0[tt] - m0[tt]) * s + be0[tt];
        }
    } else {
        int i = (bx - P1_CNT - P1_CVT - P1_PW) * 256 + t;
        if (i > N0c) return;
        if (i == 0) {
            for (int c = 0; c <= pool1[0]; ++c) start0[c] = 0;
        } else if (i == N0c) {
            for (int c = pool1[N0c - 1] + 1; c <= N1c; ++c) start0[c] = N0c;
        } else {
            int a = pool1[i - 1], b = pool1[i];
            for (int c = a + 1; c <= b; ++c) start0[c] = i;
        }
    }
}

// scanh_block: block b = bucket b; exclusive scan of blockhist[b][0..255]
// -> hx (within-bucket offsets per scatter block) + bktSum[b] (bucket total)
__global__ void scanh_block(const int* __restrict__ blockhist, int* __restrict__ hx,
                            int* __restrict__ bktSum) {
    __shared__ int sh[256];
    int b = blockIdx.x, t = threadIdx.x;
    int v = blockhist[b * NSCB + t];
    sh[t] = v; __syncthreads();
    for (int off = 1; off < 256; off <<= 1) {
        int add = (t >= off) ? sh[t - off] : 0;
        __syncthreads();
        sh[t] += add;
        __syncthreads();
    }
    hx[b * NSCB + t] = sh[t] - v;
    if (t == 255) bktSum[b] = sh[255];
}

// scanh_sums: single block, carry-loop exclusive scan of NBKT bucket totals
__global__ void scanh_sums(const int* __restrict__ bktSum, int* __restrict__ bktOff) {
    __shared__ int sh[256];
    int t = threadIdx.x;
    int carry = 0;
    for (int k = 0; k < (NBKT + 255) / 256; ++k) {
        int i = k * 256 + t;
        int v = (i < NBKT) ? bktSum[i] : 0;
        sh[t] = v; __syncthreads();
        for (int off = 1; off < 256; off <<= 1) {
            int add = (t >= off) ? sh[t - off] : 0;
            __syncthreads();
            sh[t] += add;
            __syncthreads();
        }
        if (i < NBKT) bktOff[i] = carry + sh[t] - v;
        carry += sh[255];
        __syncthreads();
    }
    if (t == 0) bktOff[NBKT] = carry;   // == EALL
}

// scatter_e: re-read edges, place into bucket-grouped order via LDS base bump.
// pk = (dst_global << 16) | src_local  (both < 65536)
__global__ __launch_bounds__(256) void scatter_e(
    const int* __restrict__ src0, const int* __restrict__ dst0,
    const int* __restrict__ src1, const int* __restrict__ dst1,
    const int* __restrict__ hx, const int* __restrict__ bktOff,
    unsigned* __restrict__ ebkt) {
    __shared__ int base[NBKT];
    int blk = blockIdx.x, t = threadIdx.x;
    for (int k = t; k < NBKT; k += 256) base[k] = bktOff[k] + hx[k * NSCB + blk];
    __syncthreads();
    int e0 = blk * EPB, e1 = min(e0 + EPB, EALL);
    for (int e = e0 + t; e < e1; e += 256) {
        int s, d;
        if (e < E0c) { s = src0[e]; d = dst0[e]; }
        else         { s = src1[e - E0c]; d = N0c + dst1[e - E0c]; }
        int bkt = d >> 5;
        int pos = atomicAdd(&base[bkt], 1);
        ebkt[pos] = ((unsigned)d << 16) | (unsigned)s;
    }
}

// count_scan_n: block b owns nodes [b*256, b*256+256) = buckets [8b, 8b+8).
// Degree count from bucketed edges (LDS hist, block-owned nodes -> no global
// atomics), dinv = rsqrt(deg+1), block-level exclusive scan of degrees.
__global__ void count_scan_n(const unsigned* __restrict__ ebkt,
                             const int* __restrict__ bktOff, int n,
                             int* __restrict__ rp, int* __restrict__ blkSum,
                             float* __restrict__ dinv) {
    __shared__ int hist[256];
    __shared__ int sh[256];
    int b = blockIdx.x, t = threadIdx.x;
    hist[t] = 0; __syncthreads();
    int lo = bktOff[b * 8];
    int hi = bktOff[b * 8 + 8];
    for (int e = lo + t; e < hi; e += 256) {
        int d = (int)(ebkt[e] >> 16);
        atomicAdd(&hist[d - b * 256], 1);
    }
    __syncthreads();
    int i = b * 256 + t;
    int v = hist[t];
    if (i < n) dinv[i] = rsqrtf((float)(v + 1));
    sh[t] = v; __syncthreads();
    for (int off = 1; off < 256; off <<= 1) {
        int add = (t >= off) ? sh[t - off] : 0;
        __syncthreads();
        sh[t] += add;
        __syncthreads();
    }
    if (i < n) rp[i] = sh[t] - v;
    if (t == 255) blkSum[b] = sh[255];
}

__global__ void scan_sums(const int* __restrict__ blkSum, int nb, int* __restrict__ blkOff,
                          int* __restrict__ rp, int n) {
    __shared__ int sh[256];
    int t = threadIdx.x;
    int v = (t < nb) ? blkSum[t] : 0;
    sh[t] = v; __syncthreads();
    for (int off = 1; off < 256; off <<= 1) {
        int add = (t >= off) ? sh[t - off] : 0;
        __syncthreads();
        sh[t] += add;
        __syncthreads();
    }
    blkOff[t] = sh[t] - v;
    if (t == 255) rp[n] = sh[255];
}

// fill_csr: one block per bucket; LDS rank counters over the bucket's 32
// nodes place each edge at its final CSR slot. Tail blocks build rpf.
#define FILL_TAIL 129
__global__ __launch_bounds__(256) void fill_csr(
    const unsigned* __restrict__ ebkt, const int* __restrict__ bktOff,
    const int* __restrict__ rp, const int* __restrict__ blkOff,
    const float* __restrict__ dinv, unsigned* __restrict__ csw,
    int* __restrict__ rpf) {
    int bx = blockIdx.x, t = threadIdx.x;
    if (bx < NBKT) {
        __shared__ int lrp[32];
        __shared__ float ldv[32];
        __shared__ int cnt[32];
        if (t < 32) {
            int node = bx * 32 + t;
            cnt[t] = 0;
            if (node < NALL) {
                lrp[t] = rp[node] + blkOff[node >> 8];
                ldv[t] = dinv[node];
            } else { lrp[t] = 0; ldv[t] = 0.f; }
        }
        __syncthreads();
        int lo = bktOff[bx], hi = bktOff[bx + 1];
        for (int e = lo + t; e < hi; e += 256) {
            unsigned pk = ebkt[e];
            int d = (int)(pk >> 16);
            int sloc = (int)(pk & 0xffffu);
            int dl = d & 31;
            int lr = atomicAdd(&cnt[dl], 1);
            int sg = (d >= N0c) ? (N0c + sloc) : sloc;
            float w = dinv[sg] * ldv[dl];
            csw[lrp[dl] + lr] = ((unsigned)bfbits(w) << 16) | (unsigned)sloc;
        }
    } else {
        int i = (bx - NBKT) * 256 + t;
        if (i < NALL) rpf[i] = rp[i] + blkOff[i >> 8];
        else if (i == NALL) rpf[NALL] = rp[NALL];
    }
}

// ---------------- aggregation (bf16 gather, packed fp32 accumulate) ----------

static __device__ inline float2v unp2(unsigned u) {
    float2v r;
    r.x = __uint_as_float(u << 16);
    r.y = __uint_as_float(u & 0xffff0000u);
    return r;
}

// 16 cols per lane: 2 contiguous uint4 (32B) of the source row.
// v_pk_fma_f32 via __builtin_elementwise_fma on float2 -> 8 pk_fma + 16 unpack
// per edge (vs 16 fma + 16 unpack + 2x overhead in the 8-col/lane scheme).
static __device__ inline void accp(float2v a[8], float w, uint4 v0, uint4 v1) {
    float2v w2; w2.x = w; w2.y = w;
    a[0] = __builtin_elementwise_fma(unp2(v0.x), w2, a[0]);
    a[1] = __builtin_elementwise_fma(unp2(v0.y), w2, a[1]);
    a[2] = __builtin_elementwise_fma(unp2(v0.z), w2, a[2]);
    a[3] = __builtin_elementwise_fma(unp2(v0.w), w2, a[3]);
    a[4] = __builtin_elementwise_fma(unp2(v1.x), w2, a[4]);
    a[5] = __builtin_elementwise_fma(unp2(v1.y), w2, a[5]);
    a[6] = __builtin_elementwise_fma(unp2(v1.z), w2, a[6]);
    a[7] = __builtin_elementwise_fma(unp2(v1.w), w2, a[7]);
}

// TWO nodes per wave, EIGHT edge slots each, 4 col-slices of 16 cols (lane =
// ns*32 + par*4 + cl). NCHUNK chunks of 64 cols; chunk = blockIdx&(NCHUNK-1)
// keeps the per-XCD L2 working set at 3.84MB. Branch-free (r16): slots past
// cnt shuffle ew==0 -> +0.0f * row0, exact no-op. r18: 16 cols/lane + packed
// fp32 fma + next-window csw prefetch (VALU-issue-bound per r17 counters:
// VALUBusy 65%, HBM 17%).
template <int RSU, int NCHUNK, bool OBF16>
__global__ __launch_bounds__(256) void agg_bf16(
    const unsigned short* __restrict__ x, const int* __restrict__ rp,
    const unsigned* __restrict__ csw, const float* __restrict__ dinv,
    void* __restrict__ zv, int N) {
    constexpr int SHIFT = (RSU == 32) ? 9 : 8;   // log2(row bytes)
    int b = blockIdx.x;
    int chunk = b & (NCHUNK - 1);
    int wave = threadIdx.x >> 6;
    int lane = threadIdx.x & 63;
    int ns = lane >> 5;                  // node sub (0/1)
    int par = (lane >> 2) & 7;           // edge slot (0..7)
    int cl = lane & 3;                   // 32B slice within 64-col chunk
    int node = (b / NCHUNK) * 8 + wave * 2 + ns;
    bool valid = node < N;
    int nclamp = valid ? node : 0;
    unsigned coff = (unsigned)(chunk * 128 + cl * 32);
    const char* xb = (const char*)x;
    float2v a[8];
#pragma unroll
    for (int k = 0; k < 8; ++k) { a[k].x = 0.f; a[k].y = 0.f; }
    int e0 = rp[nclamp];
    int e1 = valid ? rp[nclamp + 1] : e0;
    if (valid && par == 0) {             // self-loop term exactly once
        float di = dinv[node];
        const char* ps = xb + (((unsigned)node << SHIFT) + coff);
        accp(a, di * di, *(const uint4*)ps, *(const uint4*)(ps + 16));
    }
    int deg = e1 - e0;
    int myw = (deg + 31) >> 5;
    int nwin = max(__shfl(myw, 0, 64), __shfl(myw, 32, 64));   // wave-uniform
    int srcbase = lane & 32;
    int sp = srcbase + par;
    int li = lane & 31;
    unsigned mvn = (nwin > 0) ? csw[min(e0 + li, EALL - 1)] : 0u;  // prefetch w0
    for (int w = 0; w < nwin; ++w) {
        int base = e0 + w * 32;
        int avail = e1 - base;
        int cnt = avail < 0 ? 0 : (avail > 32 ? 32 : avail);   // per-half count
        unsigned my = (li < cnt) ? mvn : 0u;
        if (w + 1 < nwin) mvn = csw[min(base + 32 + li, EALL - 1)];  // prefetch
        int mysteps = (cnt + 7) >> 3;
        int steps = max(__shfl(mysteps, 0, 64), __shfl(mysteps, 32, 64));
        int i = 0;
        for (; i + 1 < steps; i += 2) {      // 4 gathers in flight per lane
            unsigned ewa = (unsigned)__shfl((int)my, sp + i * 8, 64);
            unsigned ewb = (unsigned)__shfl((int)my, sp + i * 8 + 8, 64);
            const char* pa = xb + (((ewa & 0xffffu) << SHIFT) + coff);
            const char* pb = xb + (((ewb & 0xffffu) << SHIFT) + coff);
            uint4 va0 = *(const uint4*)pa;
            uint4 va1 = *(const uint4*)(pa + 16);
            uint4 vb0 = *(const uint4*)pb;
            uint4 vb1 = *(const uint4*)(pb + 16);
            accp(a, __uint_as_float(ewa & 0xffff0000u), va0, va1);
            accp(a, __uint_as_float(ewb & 0xffff0000u), vb0, vb1);
        }
        if (i < steps) {                     // remainder, branch-free
            unsigned ew = (unsigned)__shfl((int)my, sp + i * 8, 64);
            const char* pe = xb + (((ew & 0xffffu) << SHIFT) + coff);
            accp(a, __uint_as_float(ew & 0xffff0000u),
                 *(const uint4*)pe, *(const uint4*)(pe + 16));
        }
    }
    // reduce across the 8 edge slots (3 levels, stays within each node half)
#pragma unroll
    for (int m = 4; m < 32; m <<= 1) {
#pragma unroll
        for (int k = 0; k < 8; ++k) {
            a[k].x += __shfl_xor(a[k].x, m, 64);
            a[k].y += __shfl_xor(a[k].y, m, 64);
        }
    }
    if (valid && par == 0) {
        int c8 = chunk * 8 + cl * 2;         // uint4 index within row
        if (OBF16) {
            uint4 o0, o1;
            o0.x = (unsigned)bfbits(a[0].x) | ((unsigned)bfbits(a[0].y) << 16);
            o0.y = (unsigned)bfbits(a[1].x) | ((unsigned)bfbits(a[1].y) << 16);
            o0.z = (unsigned)bfbits(a[2].x) | ((unsigned)bfbits(a[2].y) << 16);
            o0.w = (unsigned)bfbits(a[3].x) | ((unsigned)bfbits(a[3].y) << 16);
            o1.x = (unsigned)bfbits(a[4].x) | ((unsigned)bfbits(a[4].y) << 16);
            o1.y = (unsigned)bfbits(a[5].x) | ((unsigned)bfbits(a[5].y) << 16);
            o1.z = (unsigned)bfbits(a[6].x) | ((unsigned)bfbits(a[6].y) << 16);
            o1.w = (unsigned)bfbits(a[7].x) | ((unsigned)bfbits(a[7].y) << 16);
            uint4* zp = (uint4*)zv + (size_t)node * RSU + c8;
            zp[0] = o0; zp[1] = o1;
        } else {
            float4* zp = (float4*)zv + (size_t)node * (RSU * 2) + c8 * 2;
            zp[0] = make_float4(a[0].x, a[0].y, a[1].x, a[1].y);
            zp[1] = make_float4(a[2].x, a[2].y, a[3].x, a[3].y);
            zp[2] = make_float4(a[4].x, a[4].y, a[5].x, a[5].y);
            zp[3] = make_float4(a[6].x, a[6].y, a[7].x, a[7].y);
        }
    }
}

// ---------------- MFMA bf16 GEMM: (M x K)bf16 @ Wt(256 x K)bf16 -> bf16 out ----

template <int K>
__global__ __launch_bounds__(256) void gemm_mfma_bn(
    const unsigned short* __restrict__ A, const unsigned short* __restrict__ Wt,
    const float* __restrict__ sc, const float* __restrict__ sh,
    unsigned short* __restrict__ out, int M) {
    constexpr int LDS_S = 40;
    __shared__ unsigned short As[64 * LDS_S];
    __shared__ unsigned short Bs[256 * LDS_S];
    int tid = threadIdx.x;
    int w = tid >> 6, l = tid & 63;
    int quad = l >> 4, lm = l & 15;
    int row0 = blockIdx.x * 64;
    floatx4 acc[4][4];
#pragma unroll
    for (int i = 0; i < 4; ++i)
#pragma unroll
        for (int j = 0; j < 4; ++j) acc[i][j] = (floatx4){0.f, 0.f, 0.f, 0.f};

    int ar = tid >> 2;          // A staging: row 0..63
    int ac = (tid & 3) * 8;     // short offset 0,8,16,24

    for (int k0 = 0; k0 < K; k0 += 32) {
        uint4 av = make_uint4(0, 0, 0, 0);
        if (row0 + ar < M) av = *(const uint4*)(A + (size_t)(row0 + ar) * K + k0 + ac);
        *(uint4*)&As[ar * LDS_S + ac] = av;
#pragma unroll
        for (int c = 0; c < 4; ++c) {    // Bs: thread -> col tid, 4 k-chunks
            uint4 bv = *(const uint4*)(Wt + (size_t)tid * K + k0 + c * 8);
            *(uint4*)&Bs[tid * LDS_S + c * 8] = bv;
        }
        __syncthreads();
        short8 af[4], bf[4];
#pragma unroll
        for (int i = 0; i < 4; ++i)
            af[i] = *(const short8*)&As[(i * 16 + lm) * LDS_S + quad * 8];
#pragma unroll
        for (int j = 0; j < 4; ++j)
            bf[j] = *(const short8*)&Bs[(w * 64 + j * 16 + lm) * LDS_S + quad * 8];
#pragma unroll
        for (int i = 0; i < 4; ++i)
#pragma unroll
            for (int j = 0; j < 4; ++j)
                acc[i][j] = __builtin_amdgcn_mfma_f32_16x16x32_bf16(af[i], bf[j], acc[i][j], 0, 0, 0);
        __syncthreads();
    }
    // epilogue: C/D map col=lane&15, row=quad*4+reg [verified m89/m91]
#pragma unroll
    for (int j = 0; j < 4; ++j) {
        int col = w * 64 + j * 16 + lm;
        float s = sc[col], h = sh[col];
#pragma unroll
        for (int i = 0; i < 4; ++i) {
            int rb = row0 + i * 16 + quad * 4;
#pragma unroll
            for (int r = 0; r < 4; ++r) {
                int row = rb + r;
                if (row < M) {
                    float v = acc[i][j][r] * s + h;
                    v = fmaxf(v, 0.f);
                    out[(size_t)row * 256 + col] = bfbits(v);
                }
            }
        }
    }
}

// ---------------- fp32 vector GEMM (kept for small M=3000, precision-critical) --

template <int K, bool RELU, bool ZEROEMPTY, bool OBF16>
__global__ __launch_bounds__(256) void gemm_bn(
    const float* __restrict__ A, const float* __restrict__ W,
    const float* __restrict__ bias, const float* __restrict__ gam,
    const float* __restrict__ bet, const float* __restrict__ mu,
    const float* __restrict__ var, const int* __restrict__ cnt,
    void* __restrict__ outv, int M) {
    __shared__ __align__(16) float As[16][64];
    __shared__ __align__(16) float Bs[16][64];
    int tid = threadIdx.x;
    int tm = tid >> 4, tn = tid & 15;
    int row0 = blockIdx.x * 64, col0 = blockIdx.y * 64;
    float acc[4][4] = {};
    int ar = tid >> 2;
    int ak = (tid & 3) * 4;
    int bk = tid >> 4;
    int bn = (tid & 15) * 4;

    for (int kk = 0; kk < K; kk += 16) {
        float4 av = make_float4(0.f, 0.f, 0.f, 0.f);
        int grow = row0 + ar;
        if (grow < M) av = *(const float4*)(A + (size_t)grow * K + kk + ak);
        As[ak + 0][ar] = av.x;
        As[ak + 1][ar] = av.y;
        As[ak + 2][ar] = av.z;
        As[ak + 3][ar] = av.w;
        float4 bv = *(const float4*)(W + (size_t)(kk + bk) * 256 + col0 + bn);
        *(float4*)&Bs[bk][bn] = bv;
        __syncthreads();
#pragma unroll
        for (int k = 0; k < 16; ++k) {
            float4 a = *(const float4*)&As[k][tm * 4];
            float4 b = *(const float4*)&Bs[k][tn * 4];
            acc[0][0] += a.x * b.x; acc[0][1] += a.x * b.y; acc[0][2] += a.x * b.z; acc[0][3] += a.x * b.w;
            acc[1][0] += a.y * b.x; acc[1][1] += a.y * b.y; acc[1][2] += a.y * b.z; acc[1][3] += a.y * b.w;
            acc[2][0] += a.z * b.x; acc[2][1] += a.z * b.y; acc[2][2] += a.z * b.z; acc[2][3] += a.z * b.w;
            acc[3][0] += a.w * b.x; acc[3][1] += a.w * b.y; acc[3][2] += a.w * b.z; acc[3][3] += a.w * b.w;
        }
        __syncthreads();
    }
    float bcol[4], scol[4], mcol[4], ecol[4];
#pragma unroll
    for (int j = 0; j < 4; ++j) {
        int col = col0 + tn * 4 + j;
        bcol[j] = bias[col];
        scol[j] = gam[col] * rsqrtf(var[col] + EPSc);
        mcol[j] = mu[col];
        ecol[j] = bet[col];
    }
#pragma unroll
    for (int i = 0; i < 4; ++i) {
        int row = row0 + tm * 4 + i;
        if (row >= M) continue;
        bool zero = false;
        if (ZEROEMPTY) zero = (cnt[row] == 0);
        float r[4];
#pragma unroll
        for (int j = 0; j < 4; ++j) {
            float v = acc[i][j] + bcol[j];
            v = (v - mcol[j]) * scol[j] + ecol[j];
            if (RELU) v = fmaxf(v, 0.f);
            if (zero) v = 0.f;
            r[j] = v;
        }
        if (OBF16) {
            ushort4 o;
            o.x = bfbits(r[0]); o.y = bfbits(r[1]); o.z = bfbits(r[2]); o.w = bfbits(r[3]);
            *(ushort4*)((unsigned short*)outv + (size_t)row * 256 + col0 + tn * 4) = o;
        } else {
            float4 o = make_float4(r[0], r[1], r[2], r[3]);
            *(float4*)((float*)outv + (size_t)row * 256 + col0 + tn * 4) = o;
        }
    }
}

// fused: 17-wide aggregation (graph 1) + K=17 GEMM + BN + ReLU, bf16 out
__global__ void agg17_gemm_bn(const float* __restrict__ xb, const int* __restrict__ rp,
                              const unsigned* __restrict__ csw, const float* __restrict__ dinv,
                              const float* __restrict__ W, const float* __restrict__ bias,
                              const float* __restrict__ gam, const float* __restrict__ bet,
                              const float* __restrict__ mu, const float* __restrict__ var,
                              unsigned short* __restrict__ out) {
    int r = blockIdx.x, t = threadIdx.x;   // 256 threads
    __shared__ float zr[17];
    if (t < 17) {
        float di = dinv[r];
        float acc = di * di * xb[(size_t)r * 17 + t];
        int e0 = rp[r], e1 = rp[r + 1];
        for (int e = e0; e < e1; ++e) {
            unsigned ew = csw[e];
            acc += __uint_as_float(ew & 0xffff0000u) * xb[(size_t)(ew & 0xffffu) * 17 + t];
        }
        zr[t] = acc;
    }
    __syncthreads();
    float acc = bias[t];
#pragma unroll
    for (int k = 0; k < 17; ++k) acc += zr[k] * W[k * 256 + t];
    float s = gam[t] * rsqrtf(var[t] + EPSc);
    acc = (acc - mu[t]) * s + bet[t];
    acc = fmaxf(acc, 0.f);
    out[(size_t)r * 256 + t] = bfbits(acc);
}

// ---------------- pooling ----------------

__global__ void pool_mean(const float* __restrict__ z, const int* __restrict__ start,
                          const int* __restrict__ batch, float* __restrict__ p,
                          int* __restrict__ cnt_out, int* __restrict__ bpool) {
    int c = blockIdx.x, t = threadIdx.x;  // 64 threads
    int s = start[c], e = start[c + 1];
    int cnt = e - s;
    const float4* z4 = (const float4*)z;
    float ax = 0.f, ay = 0.f, az = 0.f, aw = 0.f;
    for (int i = s; i < e; ++i) {
        float4 v = z4[(size_t)i * 64 + t];
        ax += v.x; ay += v.y; az += v.z; aw += v.w;
    }
    float inv = 1.0f / (float)max(cnt, 1);
    ((float4*)p)[(size_t)c * 64 + t] = make_float4(ax * inv, ay * inv, az * inv, aw * inv);
    if (t == 0) {
        cnt_out[c] = cnt;
        int sb = 0;
        for (int i = s; i < e; ++i) sb += batch[i];
        bpool[c] = (int)rintf((float)sb * inv);
    }
}

// stage 1 of atomic-free 3000->16 reduction: 256 blocks = 16 graphs x 16 slices.
__global__ __launch_bounds__(256) void pool_b_partial(
    const float* __restrict__ zbb, const int* __restrict__ bpool,
    float* __restrict__ part, int* __restrict__ pcnt) {
    int b = blockIdx.x;          // 0..255
    int g = b & 15, s = b >> 4;
    int t = threadIdx.x;
    int i0 = s * SLICE;
    int n = min(N1c - i0, SLICE);
    __shared__ int bp[SLICE];
    for (int i = t; i < n; i += 256) bp[i] = bpool[i0 + i];
    __syncthreads();
    float acc = 0.f;
    int c = 0;
    for (int i = 0; i < n; ++i) {
        int hit = (bp[i] == g);
        float sel = hit ? 1.f : 0.f;
        acc += sel * zbb[(size_t)(i0 + i) * 256 + t];   // load NOT branch-gated
        c += hit;
    }
    part[(size_t)b * 256 + t] = acc;
    if (t == 0) pcnt[b] = c;
}

// ---------------- heads ----------------

__global__ void head0(const float* __restrict__ xp, const float* __restrict__ linW,
                      const float* __restrict__ linb, const float* __restrict__ xpool1,
                      float* __restrict__ outp, float* __restrict__ xb) {
    int r = blockIdx.x, t = threadIdx.x;  // 64 threads
    __shared__ float xr[256];
    __shared__ float lg[16];
    __shared__ float ex[16];
#pragma unroll
    for (int j = 0; j < 4; ++j) xr[t + 64 * j] = xp[(size_t)r * 256 + t + 64 * j];
    __syncthreads();
    if (t < 16) {
        float acc = linb[t];
        for (int k = 0; k < 256; ++k) acc += xr[k] * linW[k * 16 + t];
        lg[t] = acc;
    }
    __syncthreads();
    if (t < 16) {
        float mx = lg[0];
#pragma unroll
        for (int c = 1; c < 16; ++c) mx = fmaxf(mx, lg[c]);
        ex[t] = expf(lg[t] - mx);
    }
    __syncthreads();
    if (t < 16) {
        float sum = 0.f;
#pragma unroll
        for (int c = 0; c < 16; ++c) sum += ex[c];
        float pv = ex[t] / sum;
        outp[(size_t)r * 16 + t] = pv;
        xb[(size_t)r * 17 + t] = pv;
    }
    if (t == 16) xb[(size_t)r * 17 + 16] = xpool1[r];
}

// head1: sum 16 partials -> mean -> layer2 GEMM+BN -> logits -> softmax
__global__ void head1(const float* __restrict__ part, const int* __restrict__ pcnt,
                      const float* __restrict__ W, const float* __restrict__ bias,
                      const float* __restrict__ gam, const float* __restrict__ bet,
                      const float* __restrict__ mu, const float* __restrict__ var,
                      const float* __restrict__ linW, const float* __restrict__ linb,
                      float* __restrict__ outp) {
    int b = blockIdx.x, t = threadIdx.x;  // 16 blocks x 256 threads
    __shared__ float pr[256];
    __shared__ float yr[256];
    __shared__ float lg[16];
    __shared__ float ex[16];
    float acc0 = 0.f;
    int c = 0;
#pragma unroll
    for (int s = 0; s < 16; ++s) {
        int pb = s * 16 + b;
        acc0 += part[(size_t)pb * 256 + t];
        c += pcnt[pb];
    }
    float inv = 1.0f / (float)max(c, 1);
    pr[t] = acc0 * inv;
    __syncthreads();
    float acc = bias[t];
    for (int k = 0; k < 256; ++k) acc += pr[k] * W[k * 256 + t];
    float s = gam[t] * rsqrtf(var[t] + EPSc);
    acc = (acc - mu[t]) * s + bet[t];
    if (c == 0) acc = 0.f;
    yr[t] = acc;
    __syncthreads();
    if (t < 16) {
        float l = linb[t];
        for (int k = 0; k < 256; ++k) l += yr[k] * linW[k * 16 + t];
        lg[t] = l;
    }
    __syncthreads();
    if (t < 16) {
        float mx = lg[0];
#pragma unroll
        for (int cc = 1; cc < 16; ++cc) mx = fmaxf(mx, lg[cc]);
        ex[t] = expf(lg[t] - mx);
    }
    __syncthreads();
    if (t < 16) {
        float sum = 0.f;
#pragma unroll
        for (int cc = 0; cc < 16; ++cc) sum += ex[cc];
        outp[48000 + b * 16 + t] = ex[t] / sum;
    }
}

// ---------------- launch ----------------

extern "C" void kernel_launch(void* const* d_in, const int* in_sizes, int n_in,
                              void* d_out, int out_size, void* d_ws, size_t ws_size,
                              hipStream_t stream) {
    const float* x       = (const float*)d_in[0];
    const float* x_pool1 = (const float*)d_in[1];
    const float* W_in0   = (const float*)d_in[2];
    const float* W_h0    = (const float*)d_in[3];
    const float* b0      = (const float*)d_in[4];
    const float* g0      = (const float*)d_in[5];
    const float* be0     = (const float*)d_in[6];
    const float* m0      = (const float*)d_in[7];
    const float* v0      = (const float*)d_in[8];
    const float* W_in1   = (const float*)d_in[9];
    const float* W_h1    = (const float*)d_in[10];
    const float* b1      = (const float*)d_in[11];
    const float* g1      = (const float*)d_in[12];
    const float* be1     = (const float*)d_in[13];
    const float* m1      = (const float*)d_in[14];
    const float* v1      = (const float*)d_in[15];
    const float* linW0   = (const float*)d_in[16];
    const float* linb0   = (const float*)d_in[17];
    const float* linW1   = (const float*)d_in[18];
    const float* linb1   = (const float*)d_in[19];
    const int*   ei      = (const int*)d_in[20];
    const int*   batch   = (const int*)d_in[21];
    const int*   pool1   = (const int*)d_in[22];
    const int*   eip     = (const int*)d_in[23];
    float* outp = (float*)d_out;

    // carve workspace (256B-aligned); NO memset needed (every buffer fully written)
    char* p = (char*)d_ws;
    auto carve = [&](size_t bytes) -> void* {
        void* r = (void*)p;
        p += (bytes + 255) & ~(size_t)255;
        return r;
    };
    int* blockhist = (int*)carve((size_t)NBKT * NSCB * 4);
    int* hx        = (int*)carve((size_t)NBKT * NSCB * 4);
    int* bktSum    = (int*)carve((size_t)NBKT * 4);
    int* bktOff    = (int*)carve((size_t)(NBKT + 1) * 4);
    unsigned* ebkt = (unsigned*)carve((size_t)EALL * 4);

    int*   rp     = (int*)  carve((size_t)(NALL + 1) * 4);
    int*   rpf    = (int*)  carve((size_t)(NALL + 1) * 4);
    float* dinv   = (float*)carve((size_t)NALL * 4);
    int*   blkSum = (int*)  carve(256 * 4);
    int*   blkOff = (int*)  carve(256 * 4);
    unsigned* csw = (unsigned*)carve((size_t)EALL * 4);
    // region1: [xbf | z0bf] aliased later by g1bf (15.36 MB total)
    unsigned short* xbf  = (unsigned short*)carve((size_t)N0c * 256 * 2);
    unsigned short* z0bf = xbf + (size_t)N0c * 128;
    unsigned short* g1bf = xbf;                         // alias (xbf,z0bf dead)
    // region2: [g0bf | z1bf] aliased later by bufA (30.72 MB total)
    unsigned short* g0bf = (unsigned short*)carve((size_t)N0c * 256 * 4);
    unsigned short* z1bf = g0bf + (size_t)N0c * 256;
    float* bufA = (float*)g0bf;                         // alias (g0bf,z1bf dead)

    unsigned short* Wt0 = (unsigned short*)carve((size_t)256 * 128 * 2);
    unsigned short* Wt1 = (unsigned short*)carve((size_t)256 * 256 * 2);
    float* sc0 = (float*)carve(256 * 4);
    float* sh0 = (float*)carve(256 * 4);
    float* sc1 = (float*)carve(256 * 4);
    float* sh1 = (float*)carve(256 * 4);

    int*   start0 = (int*)  carve((size_t)(N1c + 1) * 4);
    int*   cnt0   = (int*)  carve((size_t)N1c * 4);
    float* pmean  = (float*)carve((size_t)N1c * 256 * 4);
    float* xp     = (float*)carve((size_t)N1c * 256 * 4);
    float* xb     = (float*)carve((size_t)N1c * 17 * 4);
    int*   bpool  = (int*)  carve((size_t)N1c * 4);
    unsigned short* hbbbf = (unsigned short*)carve((size_t)N1c * 256 * 2);
    float* zbb    = (float*)carve((size_t)N1c * 256 * 4);
    float* part   = (float*)carve((size_t)256 * 256 * 4);
    int*   pcnt   = (int*)  carve((size_t)256 * 4);

    const int* src0 = ei;
    const int* dst0 = ei + E0c;
    const int* src1 = eip;
    const int* dst1 = eip + E1c;

    // ---- CSR build: bucket sort, zero global atomics ----
    prep1<<<P1_CNT + P1_CVT + P1_PW + P1_SEG, 256, 0, stream>>>(
        dst0, dst1, blockhist, x, xbf, W_in0, W_h0, b0, g0, be0, m0, v0,
        Wt0, Wt1, sc0, sh0, sc1, sh1, pool1, start0);
    scanh_block<<<NBKT, 256, 0, stream>>>(blockhist, hx, bktSum);
    scanh_sums<<<1, 256, 0, stream>>>(bktSum, bktOff);
    scatter_e<<<NSCB, 256, 0, stream>>>(src0, dst0, src1, dst1, hx, bktOff, ebkt);
    int nb = cdiv_i(NALL, 256);                         // 129 (= NBKT/8 + 0)
    count_scan_n<<<nb, 256, 0, stream>>>(ebkt, bktOff, NALL, rp, blkSum, dinv);
    scan_sums<<<1, 256, 0, stream>>>(blkSum, nb, blkOff, rp, NALL);
    fill_csr<<<NBKT + FILL_TAIL, 256, 0, stream>>>(ebkt, bktOff, rp, blkOff, dinv,
                                                   csw, rpf);

    const int*   rp1   = rpf + N0c;
    const float* dinv1 = dinv + N0c;

    // ---- phase A: 3 GCN layers on N0 (layers 0/1: bf16 MFMA path) ----
    agg_bf16<16, 2, true><<<2 * cdiv_i(N0c, 8), 256, 0, stream>>>(xbf, rpf, csw, dinv, z0bf, N0c);
    gemm_mfma_bn<128><<<cdiv_i(N0c, 64), 256, 0, stream>>>(z0bf, Wt0, sc0, sh0, g0bf, N0c);
    agg_bf16<32, 4, true><<<4 * cdiv_i(N0c, 8), 256, 0, stream>>>(g0bf, rpf, csw, dinv, z1bf, N0c);
    gemm_mfma_bn<256><<<cdiv_i(N0c, 64), 256, 0, stream>>>(z1bf, Wt1, sc1, sh1, g1bf, N0c);
    agg_bf16<32, 4, false><<<4 * cdiv_i(N0c, 8), 256, 0, stream>>>(g1bf, rpf, csw, dinv, bufA, N0c);

    // layer 2: pool BEFORE GEMM (affine reorder); fp32 vector GEMM (precision)
    pool_mean<<<N1c, 64, 0, stream>>>(bufA, start0, batch, pmean, cnt0, bpool);
    gemm_bn<256, false, true, false><<<dim3(cdiv_i(N1c, 64), 4), 256, 0, stream>>>(
        pmean, W_h0 + Hc * Hc, b0 + 2 * Hc, g0 + 2 * Hc, be0 + 2 * Hc, m0 + 2 * Hc,
        v0 + 2 * Hc, cnt0, xp, N1c);

    // head0: logits + softmax -> d_out[0:48000], xb = [x0 | x_pool1]
    head0<<<N1c, 64, 0, stream>>>(xp, linW0, linb0, x_pool1, outp, xb);

    // ---- phase B: 3 GCN layers on N1 (fp32 vector GEMMs) ----
    agg17_gemm_bn<<<N1c, 256, 0, stream>>>(xb, rp1, csw, dinv1, W_in1, b1, g1, be1,
                                           m1, v1, hbbbf);
    agg_bf16<32, 4, false><<<4 * cdiv_i(N1c, 8), 256, 0, stream>>>(hbbbf, rp1, csw, dinv1, zbb, N1c);
    gemm_bn<256, true, false, true><<<dim3(cdiv_i(N1c, 64), 4), 256, 0, stream>>>(
        zbb, W_h1, b1 + Hc, g1 + Hc, be1 + Hc, m1 + Hc, v1 + Hc, nullptr, hbbbf, N1c);
    agg_bf16<32, 4, false><<<4 * cdiv_i(N1c, 8), 256, 0, stream>>>(hbbbf, rp1, csw, dinv1, zbb, N1c);

    // atomic-free 3000->16 reduction: 256-block partials, then head1 combines
    pool_b_partial<<<256, 256, 0, stream>>>(zbb, bpool, part, pcnt);
    head1<<<Bc, 256, 0, stream>>>(part, pcnt, W_h1 + Hc * Hc, b1 + 2 * Hc, g1 + 2 * Hc,
                                  be1 + 2 * Hc, m1 + 2 * Hc, v1 + 2 * Hc, linW1, linb1,
                                  outp);
}

// Round 4
// 401.052 us; speedup vs baseline: 1.0534x; 1.0534x over previous
//
#include <hip/hip_runtime.h>
#include <cstdint>
#include <cstddef>

// Problem constants
#define N0c 30000
#define F0c 128
#define Hc  256
#define Cc  16
#define N1c 3000
#define Bc  16
#define E0c 960000
#define E1c 48000
#define NALL 33000            // N0 + N1 (concatenated graphs)
#define EALL 1008000          // E0 + E1
#define EPSc 1e-5f
#define SLICE 188             // clusters per pool_b_partial slice (16*188 >= 3000)

// r17 bucket-sort CSR build: the 1M global atomicAdds were at a memory-side
// atomic throughput wall (~21/ns, 32MB sector writeback). LDS-histogram bucket
// sort: zero global atomics. bucket = dst>>5 (32 nodes), NBKT=1032.
#define NBKT 1032
#define NSCB 256
#define EPB  3938             // edges per scatter block (256*3938 >= EALL)

static __host__ __device__ inline int cdiv_i(int a, int b) { return (a + b - 1) / b; }

// round-to-nearest-even fp32 -> bf16 (returns the 16 bf16 bits)
static __device__ inline unsigned short bfbits(float f) {
    unsigned u = __float_as_uint(f);
    return (unsigned short)((u + 0x7fffu + ((u >> 16) & 1u)) >> 16);
}

typedef short short8 __attribute__((ext_vector_type(8)));   // 8 bf16 = 4 VGPRs
typedef float floatx4 __attribute__((ext_vector_type(4)));

// ---------------- prep1: bucket count (LDS hist) + indep prep work ------------
#define P1_CNT NSCB
#define P1_CVT 3750
#define P1_PW  386
#define P1_SEG 118

__global__ void prep1(const int* __restrict__ dst0, const int* __restrict__ dst1,
                      int* __restrict__ blockhist,
                      const float* __restrict__ x, unsigned short* __restrict__ xbf,
                      const float* __restrict__ W_in0, const float* __restrict__ W_h0,
                      const float* __restrict__ b0, const float* __restrict__ g0,
                      const float* __restrict__ be0, const float* __restrict__ m0,
                      const float* __restrict__ v0,
                      unsigned short* __restrict__ Wt0, unsigned short* __restrict__ Wt1,
                      float* __restrict__ sc0, float* __restrict__ sh0,
                      float* __restrict__ sc1, float* __restrict__ sh1,
                      const int* __restrict__ pool1, int* __restrict__ start0) {
    __shared__ int hist[NBKT];
    int bx = blockIdx.x, t = threadIdx.x;
    if (bx < P1_CNT) {
        for (int k = t; k < NBKT; k += 256) hist[k] = 0;
        __syncthreads();
        int e0 = bx * EPB, e1 = min(e0 + EPB, EALL);
        for (int e = e0 + t; e < e1; e += 256) {
            int d = (e < E0c) ? dst0[e] : (N0c + dst1[e - E0c]);
            atomicAdd(&hist[d >> 5], 1);
        }
        __syncthreads();
        for (int k = t; k < NBKT; k += 256) blockhist[k * NSCB + bx] = hist[k];
    } else if (bx < P1_CNT + P1_CVT) {
        int i = (bx - P1_CNT) * 256 + t;            // float4 index
        if (i >= N0c * 32) return;
        float4 v = ((const float4*)x)[i];
        ushort4 o;
        o.x = bfbits(v.x); o.y = bfbits(v.y); o.z = bfbits(v.z); o.w = bfbits(v.w);
        ((ushort4*)xbf)[i] = o;
    } else if (bx < P1_CNT + P1_CVT + P1_PW) {
        int pb = bx - P1_CNT - P1_CVT;
        if (pb < 128) {
            int i = pb * 256 + t;
            int k = i >> 8, col = i & 255;
            Wt0[col * 128 + k] = bfbits(W_in0[i]);
        } else if (pb < 384) {
            int i = (pb - 128) * 256 + t;
            int k = i >> 8, col = i & 255;
            Wt1[col * 256 + k] = bfbits(W_h0[i]);
        } else if (pb == 384) {
            float s = g0[t] * rsqrtf(v0[t] + EPSc);
            sc0[t] = s;
            sh0[t] = (b0[t] - m0[t]) * s + be0[t];
        } else {
            int tt = t + 256;
            float s = g0[tt] * rsqrtf(v0[tt] + EPSc);
            sc1[t] = s;
            sh1[t] = (b0[tt] - m0[tt]) * s + be0[tt];
        }
    } else {
        int i = (bx - P1_CNT - P1_CVT - P1_PW) * 256 + t;
        if (i > N0c) return;
        if (i == 0) {
            for (int c = 0; c <= pool1[0]; ++c) start0[c] = 0;
        } else if (i == N0c) {
            for (int c = pool1[N0c - 1] + 1; c <= N1c; ++c) start0[c] = N0c;
        } else {
            int a = pool1[i - 1], b = pool1[i];
            for (int c = a + 1; c <= b; ++c) start0[c] = i;
        }
    }
}

// scanh_block: block b = bucket b; exclusive scan of blockhist[b][0..255]
// -> hx (within-bucket offsets per scatter block) + bktSum[b] (bucket total)
__global__ void scanh_block(const int* __restrict__ blockhist, int* __restrict__ hx,
                            int* __restrict__ bktSum) {
    __shared__ int sh[256];
    int b = blockIdx.x, t = threadIdx.x;
    int v = blockhist[b * NSCB + t];
    sh[t] = v; __syncthreads();
    for (int off = 1; off < 256; off <<= 1) {
        int add = (t >= off) ? sh[t - off] : 0;
        __syncthreads();
        sh[t] += add;
        __syncthreads();
    }
    hx[b * NSCB + t] = sh[t] - v;
    if (t == 255) bktSum[b] = sh[255];
}

// scanh_sums: single block, carry-loop exclusive scan of NBKT bucket totals
__global__ void scanh_sums(const int* __restrict__ bktSum, int* __restrict__ bktOff) {
    __shared__ int sh[256];
    int t = threadIdx.x;
    int carry = 0;
    for (int k = 0; k < (NBKT + 255) / 256; ++k) {
        int i = k * 256 + t;
        int v = (i < NBKT) ? bktSum[i] : 0;
        sh[t] = v; __syncthreads();
        for (int off = 1; off < 256; off <<= 1) {
            int add = (t >= off) ? sh[t - off] : 0;
            __syncthreads();
            sh[t] += add;
            __syncthreads();
        }
        if (i < NBKT) bktOff[i] = carry + sh[t] - v;
        carry += sh[255];
        __syncthreads();
    }
    if (t == 0) bktOff[NBKT] = carry;   // == EALL
}

// scatter_e: re-read edges, place into bucket-grouped order via LDS base bump.
// pk = (dst_global << 16) | src_local  (both < 65536)
__global__ __launch_bounds__(256) void scatter_e(
    const int* __restrict__ src0, const int* __restrict__ dst0,
    const int* __restrict__ src1, const int* __restrict__ dst1,
    const int* __restrict__ hx, const int* __restrict__ bktOff,
    unsigned* __restrict__ ebkt) {
    __shared__ int base[NBKT];
    int blk = blockIdx.x, t = threadIdx.x;
    for (int k = t; k < NBKT; k += 256) base[k] = bktOff[k] + hx[k * NSCB + blk];
    __syncthreads();
    int e0 = blk * EPB, e1 = min(e0 + EPB, EALL);
    for (int e = e0 + t; e < e1; e += 256) {
        int s, d;
        if (e < E0c) { s = src0[e]; d = dst0[e]; }
        else         { s = src1[e - E0c]; d = N0c + dst1[e - E0c]; }
        int bkt = d >> 5;
        int pos = atomicAdd(&base[bkt], 1);
        ebkt[pos] = ((unsigned)d << 16) | (unsigned)s;
    }
}

// count_scan_n: block b owns nodes [b*256, b*256+256) = buckets [8b, 8b+8).
// Degree count from bucketed edges (LDS hist, block-owned nodes -> no global
// atomics), dinv = rsqrt(deg+1), block-level exclusive scan of degrees.
__global__ void count_scan_n(const unsigned* __restrict__ ebkt,
                             const int* __restrict__ bktOff, int n,
                             int* __restrict__ rp, int* __restrict__ blkSum,
                             float* __restrict__ dinv) {
    __shared__ int hist[256];
    __shared__ int sh[256];
    int b = blockIdx.x, t = threadIdx.x;
    hist[t] = 0; __syncthreads();
    int lo = bktOff[b * 8];
    int hi = bktOff[b * 8 + 8];
    for (int e = lo + t; e < hi; e += 256) {
        int d = (int)(ebkt[e] >> 16);
        atomicAdd(&hist[d - b * 256], 1);
    }
    __syncthreads();
    int i = b * 256 + t;
    int v = hist[t];
    if (i < n) dinv[i] = rsqrtf((float)(v + 1));
    sh[t] = v; __syncthreads();
    for (int off = 1; off < 256; off <<= 1) {
        int add = (t >= off) ? sh[t - off] : 0;
        __syncthreads();
        sh[t] += add;
        __syncthreads();
    }
    if (i < n) rp[i] = sh[t] - v;
    if (t == 255) blkSum[b] = sh[255];
}

__global__ void scan_sums(const int* __restrict__ blkSum, int nb, int* __restrict__ blkOff,
                          int* __restrict__ rp, int n) {
    __shared__ int sh[256];
    int t = threadIdx.x;
    int v = (t < nb) ? blkSum[t] : 0;
    sh[t] = v; __syncthreads();
    for (int off = 1; off < 256; off <<= 1) {
        int add = (t >= off) ? sh[t - off] : 0;
        __syncthreads();
        sh[t] += add;
        __syncthreads();
    }
    blkOff[t] = sh[t] - v;
    if (t == 255) rp[n] = sh[255];
}

// fill_csr: one block per bucket; LDS rank counters over the bucket's 32
// nodes place each edge at its final CSR slot. Tail blocks build rpf.
#define FILL_TAIL 129
__global__ __launch_bounds__(256) void fill_csr(
    const unsigned* __restrict__ ebkt, const int* __restrict__ bktOff,
    const int* __restrict__ rp, const int* __restrict__ blkOff,
    const float* __restrict__ dinv, unsigned* __restrict__ csw,
    int* __restrict__ rpf) {
    int bx = blockIdx.x, t = threadIdx.x;
    if (bx < NBKT) {
        __shared__ int lrp[32];
        __shared__ float ldv[32];
        __shared__ int cnt[32];
        if (t < 32) {
            int node = bx * 32 + t;
            cnt[t] = 0;
            if (node < NALL) {
                lrp[t] = rp[node] + blkOff[node >> 8];
                ldv[t] = dinv[node];
            } else { lrp[t] = 0; ldv[t] = 0.f; }
        }
        __syncthreads();
        int lo = bktOff[bx], hi = bktOff[bx + 1];
        for (int e = lo + t; e < hi; e += 256) {
            unsigned pk = ebkt[e];
            int d = (int)(pk >> 16);
            int sloc = (int)(pk & 0xffffu);
            int dl = d & 31;
            int lr = atomicAdd(&cnt[dl], 1);
            int sg = (d >= N0c) ? (N0c + sloc) : sloc;
            float w = dinv[sg] * ldv[dl];
            csw[lrp[dl] + lr] = ((unsigned)bfbits(w) << 16) | (unsigned)sloc;
        }
    } else {
        int i = (bx - NBKT) * 256 + t;
        if (i < NALL) rpf[i] = rp[i] + blkOff[i >> 8];
        else if (i == NALL) rpf[NALL] = rp[NALL];
    }
}

// ---------------- aggregation (bf16 gather, fp32 accumulate) ----------------

static __device__ inline void acc8(float a[8], float w, uint4 v) {
    a[0] += w * __uint_as_float(v.x << 16);
    a[1] += w * __uint_as_float(v.x & 0xffff0000u);
    a[2] += w * __uint_as_float(v.y << 16);
    a[3] += w * __uint_as_float(v.y & 0xffff0000u);
    a[4] += w * __uint_as_float(v.z << 16);
    a[5] += w * __uint_as_float(v.z & 0xffff0000u);
    a[6] += w * __uint_as_float(v.w << 16);
    a[7] += w * __uint_as_float(v.w & 0xffff0000u);
}

// TWO nodes per wave, FOUR edge slots each (lane = ns*32 + par*8 + cl).
// NCHUNK chunks of 64 cols; chunk = blockIdx&(NCHUNK-1) keeps XCD pinning
// (64-col bf16 chunk of 30000 rows = 3.84MB, fits 4MB per-XCD L2).
// r19: NO cross-lane edge broadcast. r17's ds_bpermute broadcast put the LDS
// pipe on the gather-address critical path (43us @ 65% VALUBusy = 35% stall).
// Instead each lane loads its par-group's edge word DIRECTLY from csw (8 lanes
// same address -> one L1 request, broadcast by cache). Software pipeline: next
// 4 edge words prefetched under the current 4 gathers. Out-of-range edges are
// cndmask'd to 0 -> weight +0.0f * row0 = exact no-op (r16). csw is carved
// with 4KB padding so no address clamp is needed.
template <int RSU, int NCHUNK, bool OBF16>
__global__ __launch_bounds__(256) void agg_bf16(
    const unsigned short* __restrict__ x, const int* __restrict__ rp,
    const unsigned* __restrict__ csw, const float* __restrict__ dinv,
    void* __restrict__ zv, int N) {
    constexpr int SHIFT = (RSU == 32) ? 9 : 8;   // log2(row bytes)
    int b = blockIdx.x;
    int chunk = b & (NCHUNK - 1);
    int wave = threadIdx.x >> 6;
    int lane = threadIdx.x & 63;
    int ns = lane >> 5;                  // node sub (0/1)
    int par = (lane >> 3) & 3;           // edge slot (0..3)
    int cl = lane & 7;                   // 16B slice within 64-col chunk
    int node = (b / NCHUNK) * 8 + wave * 2 + ns;
    bool valid = node < N;
    int nclamp = valid ? node : 0;
    int c4 = chunk * 8 + cl;
    unsigned coff = (unsigned)c4 << 4;
    const char* xb = (const char*)x;
    float a[8] = {0.f, 0.f, 0.f, 0.f, 0.f, 0.f, 0.f, 0.f};
    int e0 = rp[nclamp];
    int e1 = valid ? rp[nclamp + 1] : e0;
    if (valid && par == 0) {             // self-loop term exactly once
        float di = dinv[node];
        uint4 v = *(const uint4*)(xb + (((unsigned)node << SHIFT) + coff));
        acc8(a, di * di, v);
    }
    int deg = e1 - e0;
    int mysteps = (deg + 3) >> 2;
    int steps = max(__shfl(mysteps, 0, 64), __shfl(mysteps, 32, 64));  // uniform
    int e = e0 + par;                    // this lane's first edge slot
    // direct loads (no clamp: csw padded; garbage is dead via the e<e1 select)
    unsigned cw0 = csw[e];      cw0 = (e      < e1) ? cw0 : 0u;
    unsigned cw1 = csw[e + 4];  cw1 = (e + 4  < e1) ? cw1 : 0u;
    unsigned cw2 = csw[e + 8];  cw2 = (e + 8  < e1) ? cw2 : 0u;
    unsigned cw3 = csw[e + 12]; cw3 = (e + 12 < e1) ? cw3 : 0u;
    int i = 0;
    for (; i + 3 < steps; i += 4) {
        // 4 gathers in flight (addresses depend only on already-loaded cw*)
        uint4 v0 = *(const uint4*)(xb + (((cw0 & 0xffffu) << SHIFT) + coff));
        uint4 v1 = *(const uint4*)(xb + (((cw1 & 0xffffu) << SHIFT) + coff));
        uint4 v2 = *(const uint4*)(xb + (((cw2 & 0xffffu) << SHIFT) + coff));
        uint4 v3 = *(const uint4*)(xb + (((cw3 & 0xffffu) << SHIFT) + coff));
        // prefetch next group's edge words under the gathers
        int en = e + 16;
        unsigned nw0 = csw[en];      nw0 = (en      < e1) ? nw0 : 0u;
        unsigned nw1 = csw[en + 4];  nw1 = (en + 4  < e1) ? nw1 : 0u;
        unsigned nw2 = csw[en + 8];  nw2 = (en + 8  < e1) ? nw2 : 0u;
        unsigned nw3 = csw[en + 12]; nw3 = (en + 12 < e1) ? nw3 : 0u;
        acc8(a, __uint_as_float(cw0 & 0xffff0000u), v0);
        acc8(a, __uint_as_float(cw1 & 0xffff0000u), v1);
        acc8(a, __uint_as_float(cw2 & 0xffff0000u), v2);
        acc8(a, __uint_as_float(cw3 & 0xffff0000u), v3);
        cw0 = nw0; cw1 = nw1; cw2 = nw2; cw3 = nw3;
        e = en;
    }
    // tail (steps is wave-uniform -> uniform branches; cw* already loaded)
    if (i < steps) {
        uint4 v = *(const uint4*)(xb + (((cw0 & 0xffffu) << SHIFT) + coff));
        acc8(a, __uint_as_float(cw0 & 0xffff0000u), v);
    }
    if (i + 1 < steps) {
        uint4 v = *(const uint4*)(xb + (((cw1 & 0xffffu) << SHIFT) + coff));
        acc8(a, __uint_as_float(cw1 & 0xffff0000u), v);
    }
    if (i + 2 < steps) {
        uint4 v = *(const uint4*)(xb + (((cw2 & 0xffffu) << SHIFT) + coff));
        acc8(a, __uint_as_float(cw2 & 0xffff0000u), v);
    }
    // reduce across the 4 edge slots (2 levels, stays within each node half)
#pragma unroll
    for (int m = 8; m < 32; m <<= 1) {
#pragma unroll
        for (int k = 0; k < 8; ++k) a[k] += __shfl_xor(a[k], m, 64);
    }
    if (valid && par == 0) {
        if (OBF16) {
            uint4 o;
            o.x = (unsigned)bfbits(a[0]) | ((unsigned)bfbits(a[1]) << 16);
            o.y = (unsigned)bfbits(a[2]) | ((unsigned)bfbits(a[3]) << 16);
            o.z = (unsigned)bfbits(a[4]) | ((unsigned)bfbits(a[5]) << 16);
            o.w = (unsigned)bfbits(a[6]) | ((unsigned)bfbits(a[7]) << 16);
            ((uint4*)zv)[(size_t)node * RSU + c4] = o;
        } else {
            float4* zp = (float4*)zv + (size_t)node * (RSU * 2) + c4 * 2;
            zp[0] = make_float4(a[0], a[1], a[2], a[3]);
            zp[1] = make_float4(a[4], a[5], a[6], a[7]);
        }
    }
}

// ---------------- MFMA bf16 GEMM: (M x K)bf16 @ Wt(256 x K)bf16 -> bf16 out ----

template <int K>
__global__ __launch_bounds__(256) void gemm_mfma_bn(
    const unsigned short* __restrict__ A, const unsigned short* __restrict__ Wt,
    const float* __restrict__ sc, const float* __restrict__ sh,
    unsigned short* __restrict__ out, int M) {
    constexpr int LDS_S = 40;
    __shared__ unsigned short As[64 * LDS_S];
    __shared__ unsigned short Bs[256 * LDS_S];
    int tid = threadIdx.x;
    int w = tid >> 6, l = tid & 63;
    int quad = l >> 4, lm = l & 15;
    int row0 = blockIdx.x * 64;
    floatx4 acc[4][4];
#pragma unroll
    for (int i = 0; i < 4; ++i)
#pragma unroll
        for (int j = 0; j < 4; ++j) acc[i][j] = (floatx4){0.f, 0.f, 0.f, 0.f};

    int ar = tid >> 2;          // A staging: row 0..63
    int ac = (tid & 3) * 8;     // short offset 0,8,16,24

    for (int k0 = 0; k0 < K; k0 += 32) {
        uint4 av = make_uint4(0, 0, 0, 0);
        if (row0 + ar < M) av = *(const uint4*)(A + (size_t)(row0 + ar) * K + k0 + ac);
        *(uint4*)&As[ar * LDS_S + ac] = av;
#pragma unroll
        for (int c = 0; c < 4; ++c) {    // Bs: thread -> col tid, 4 k-chunks
            uint4 bv = *(const uint4*)(Wt + (size_t)tid * K + k0 + c * 8);
            *(uint4*)&Bs[tid * LDS_S + c * 8] = bv;
        }
        __syncthreads();
        short8 af[4], bf[4];
#pragma unroll
        for (int i = 0; i < 4; ++i)
            af[i] = *(const short8*)&As[(i * 16 + lm) * LDS_S + quad * 8];
#pragma unroll
        for (int j = 0; j < 4; ++j)
            bf[j] = *(const short8*)&Bs[(w * 64 + j * 16 + lm) * LDS_S + quad * 8];
#pragma unroll
        for (int i = 0; i < 4; ++i)
#pragma unroll
            for (int j = 0; j < 4; ++j)
                acc[i][j] = __builtin_amdgcn_mfma_f32_16x16x32_bf16(af[i], bf[j], acc[i][j], 0, 0, 0);
        __syncthreads();
    }
    // epilogue: C/D map col=lane&15, row=quad*4+reg [verified m89/m91]
#pragma unroll
    for (int j = 0; j < 4; ++j) {
        int col = w * 64 + j * 16 + lm;
        float s = sc[col], h = sh[col];
#pragma unroll
        for (int i = 0; i < 4; ++i) {
            int rb = row0 + i * 16 + quad * 4;
#pragma unroll
            for (int r = 0; r < 4; ++r) {
                int row = rb + r;
                if (row < M) {
                    float v = acc[i][j][r] * s + h;
                    v = fmaxf(v, 0.f);
                    out[(size_t)row * 256 + col] = bfbits(v);
                }
            }
        }
    }
}

// ---------------- fp32 vector GEMM (kept for small M=3000, precision-critical) --

template <int K, bool RELU, bool ZEROEMPTY, bool OBF16>
__global__ __launch_bounds__(256) void gemm_bn(
    const float* __restrict__ A, const float* __restrict__ W,
    const float* __restrict__ bias, const float* __restrict__ gam,
    const float* __restrict__ bet, const float* __restrict__ mu,
    const float* __restrict__ var, const int* __restrict__ cnt,
    void* __restrict__ outv, int M) {
    __shared__ __align__(16) float As[16][64];
    __shared__ __align__(16) float Bs[16][64];
    int tid = threadIdx.x;
    int tm = tid >> 4, tn = tid & 15;
    int row0 = blockIdx.x * 64, col0 = blockIdx.y * 64;
    float acc[4][4] = {};
    int ar = tid >> 2;
    int ak = (tid & 3) * 4;
    int bk = tid >> 4;
    int bn = (tid & 15) * 4;

    for (int kk = 0; kk < K; kk += 16) {
        float4 av = make_float4(0.f, 0.f, 0.f, 0.f);
        int grow = row0 + ar;
        if (grow < M) av = *(const float4*)(A + (size_t)grow * K + kk + ak);
        As[ak + 0][ar] = av.x;
        As[ak + 1][ar] = av.y;
        As[ak + 2][ar] = av.z;
        As[ak + 3][ar] = av.w;
        float4 bv = *(const float4*)(W + (size_t)(kk + bk) * 256 + col0 + bn);
        *(float4*)&Bs[bk][bn] = bv;
        __syncthreads();
#pragma unroll
        for (int k = 0; k < 16; ++k) {
            float4 a = *(const float4*)&As[k][tm * 4];
            float4 b = *(const float4*)&Bs[k][tn * 4];
            acc[0][0] += a.x * b.x; acc[0][1] += a.x * b.y; acc[0][2] += a.x * b.z; acc[0][3] += a.x * b.w;
            acc[1][0] += a.y * b.x; acc[1][1] += a.y * b.y; acc[1][2] += a.y * b.z; acc[1][3] += a.y * b.w;
            acc[2][0] += a.z * b.x; acc[2][1] += a.z * b.y; acc[2][2] += a.z * b.z; acc[2][3] += a.z * b.w;
            acc[3][0] += a.w * b.x; acc[3][1] += a.w * b.y; acc[3][2] += a.w * b.z; acc[3][3] += a.w * b.w;
        }
        __syncthreads();
    }
    float bcol[4], scol[4], mcol[4], ecol[4];
#pragma unroll
    for (int j = 0; j < 4; ++j) {
        int col = col0 + tn * 4 + j;
        bcol[j] = bias[col];
        scol[j] = gam[col] * rsqrtf(var[col] + EPSc);
        mcol[j] = mu[col];
        ecol[j] = bet[col];
    }
#pragma unroll
    for (int i = 0; i < 4; ++i) {
        int row = row0 + tm * 4 + i;
        if (row >= M) continue;
        bool zero = false;
        if (ZEROEMPTY) zero = (cnt[row] == 0);
        float r[4];
#pragma unroll
        for (int j = 0; j < 4; ++j) {
            float v = acc[i][j] + bcol[j];
            v = (v - mcol[j]) * scol[j] + ecol[j];
            if (RELU) v = fmaxf(v, 0.f);
            if (zero) v = 0.f;
            r[j] = v;
        }
        if (OBF16) {
            ushort4 o;
            o.x = bfbits(r[0]); o.y = bfbits(r[1]); o.z = bfbits(r[2]); o.w = bfbits(r[3]);
            *(ushort4*)((unsigned short*)outv + (size_t)row * 256 + col0 + tn * 4) = o;
        } else {
            float4 o = make_float4(r[0], r[1], r[2], r[3]);
            *(float4*)((float*)outv + (size_t)row * 256 + col0 + tn * 4) = o;
        }
    }
}

// fused: 17-wide aggregation (graph 1) + K=17 GEMM + BN + ReLU, bf16 out
__global__ void agg17_gemm_bn(const float* __restrict__ xb, const int* __restrict__ rp,
                              const unsigned* __restrict__ csw, const float* __restrict__ dinv,
                              const float* __restrict__ W, const float* __restrict__ bias,
                              const float* __restrict__ gam, const float* __restrict__ bet,
                              const float* __restrict__ mu, const float* __restrict__ var,
                              unsigned short* __restrict__ out) {
    int r = blockIdx.x, t = threadIdx.x;   // 256 threads
    __shared__ float zr[17];
    if (t < 17) {
        float di = dinv[r];
        float acc = di * di * xb[(size_t)r * 17 + t];
        int e0 = rp[r], e1 = rp[r + 1];
        for (int e = e0; e < e1; ++e) {
            unsigned ew = csw[e];
            acc += __uint_as_float(ew & 0xffff0000u) * xb[(size_t)(ew & 0xffffu) * 17 + t];
        }
        zr[t] = acc;
    }
    __syncthreads();
    float acc = bias[t];
#pragma unroll
    for (int k = 0; k < 17; ++k) acc += zr[k] * W[k * 256 + t];
    float s = gam[t] * rsqrtf(var[t] + EPSc);
    acc = (acc - mu[t]) * s + bet[t];
    acc = fmaxf(acc, 0.f);
    out[(size_t)r * 256 + t] = bfbits(acc);
}

// ---------------- pooling ----------------

__global__ void pool_mean(const float* __restrict__ z, const int* __restrict__ start,
                          const int* __restrict__ batch, float* __restrict__ p,
                          int* __restrict__ cnt_out, int* __restrict__ bpool) {
    int c = blockIdx.x, t = threadIdx.x;  // 64 threads
    int s = start[c], e = start[c + 1];
    int cnt = e - s;
    const float4* z4 = (const float4*)z;
    float ax = 0.f, ay = 0.f, az = 0.f, aw = 0.f;
    for (int i = s; i < e; ++i) {
        float4 v = z4[(size_t)i * 64 + t];
        ax += v.x; ay += v.y; az += v.z; aw += v.w;
    }
    float inv = 1.0f / (float)max(cnt, 1);
    ((float4*)p)[(size_t)c * 64 + t] = make_float4(ax * inv, ay * inv, az * inv, aw * inv);
    if (t == 0) {
        cnt_out[c] = cnt;
        int sb = 0;
        for (int i = s; i < e; ++i) sb += batch[i];
        bpool[c] = (int)rintf((float)sb * inv);
    }
}

// stage 1 of atomic-free 3000->16 reduction: 256 blocks = 16 graphs x 16 slices.
__global__ __launch_bounds__(256) void pool_b_partial(
    const float* __restrict__ zbb, const int* __restrict__ bpool,
    float* __restrict__ part, int* __restrict__ pcnt) {
    int b = blockIdx.x;          // 0..255
    int g = b & 15, s = b >> 4;
    int t = threadIdx.x;
    int i0 = s * SLICE;
    int n = min(N1c - i0, SLICE);
    __shared__ int bp[SLICE];
    for (int i = t; i < n; i += 256) bp[i] = bpool[i0 + i];
    __syncthreads();
    float acc = 0.f;
    int c = 0;
    for (int i = 0; i < n; ++i) {
        int hit = (bp[i] == g);
        float sel = hit ? 1.f : 0.f;
        acc += sel * zbb[(size_t)(i0 + i) * 256 + t];   // load NOT branch-gated
        c += hit;
    }
    part[(size_t)b * 256 + t] = acc;
    if (t == 0) pcnt[b] = c;
}

// ---------------- heads ----------------

__global__ void head0(const float* __restrict__ xp, const float* __restrict__ linW,
                      const float* __restrict__ linb, const float* __restrict__ xpool1,
                      float* __restrict__ outp, float* __restrict__ xb) {
    int r = blockIdx.x, t = threadIdx.x;  // 64 threads
    __shared__ float xr[256];
    __shared__ float lg[16];
    __shared__ float ex[16];
#pragma unroll
    for (int j = 0; j < 4; ++j) xr[t + 64 * j] = xp[(size_t)r * 256 + t + 64 * j];
    __syncthreads();
    if (t < 16) {
        float acc = linb[t];
        for (int k = 0; k < 256; ++k) acc += xr[k] * linW[k * 16 + t];
        lg[t] = acc;
    }
    __syncthreads();
    if (t < 16) {
        float mx = lg[0];
#pragma unroll
        for (int c = 1; c < 16; ++c) mx = fmaxf(mx, lg[c]);
        ex[t] = expf(lg[t] - mx);
    }
    __syncthreads();
    if (t < 16) {
        float sum = 0.f;
#pragma unroll
        for (int c = 0; c < 16; ++c) sum += ex[c];
        float pv = ex[t] / sum;
        outp[(size_t)r * 16 + t] = pv;
        xb[(size_t)r * 17 + t] = pv;
    }
    if (t == 16) xb[(size_t)r * 17 + 16] = xpool1[r];
}

// head1: sum 16 partials -> mean -> layer2 GEMM+BN -> logits -> softmax
__global__ void head1(const float* __restrict__ part, const int* __restrict__ pcnt,
                      const float* __restrict__ W, const float* __restrict__ bias,
                      const float* __restrict__ gam, const float* __restrict__ bet,
                      const float* __restrict__ mu, const float* __restrict__ var,
                      const float* __restrict__ linW, const float* __restrict__ linb,
                      float* __restrict__ outp) {
    int b = blockIdx.x, t = threadIdx.x;  // 16 blocks x 256 threads
    __shared__ float pr[256];
    __shared__ float yr[256];
    __shared__ float lg[16];
    __shared__ float ex[16];
    float acc0 = 0.f;
    int c = 0;
#pragma unroll
    for (int s = 0; s < 16; ++s) {
        int pb = s * 16 + b;
        acc0 += part[(size_t)pb * 256 + t];
        c += pcnt[pb];
    }
    float inv = 1.0f / (float)max(c, 1);
    pr[t] = acc0 * inv;
    __syncthreads();
    float acc = bias[t];
    for (int k = 0; k < 256; ++k) acc += pr[k] * W[k * 256 + t];
    float s = gam[t] * rsqrtf(var[t] + EPSc);
    acc = (acc - mu[t]) * s + bet[t];
    if (c == 0) acc = 0.f;
    yr[t] = acc;
    __syncthreads();
    if (t < 16) {
        float l = linb[t];
        for (int k = 0; k < 256; ++k) l += yr[k] * linW[k * 16 + t];
        lg[t] = l;
    }
    __syncthreads();
    if (t < 16) {
        float mx = lg[0];
#pragma unroll
        for (int cc = 1; cc < 16; ++cc) mx = fmaxf(mx, lg[cc]);
        ex[t] = expf(lg[t] - mx);
    }
    __syncthreads();
    if (t < 16) {
        float sum = 0.f;
#pragma unroll
        for (int cc = 0; cc < 16; ++cc) sum += ex[cc];
        outp[48000 + b * 16 + t] = ex[t] / sum;
    }
}

// ---------------- launch ----------------

extern "C" void kernel_launch(void* const* d_in, const int* in_sizes, int n_in,
                              void* d_out, int out_size, void* d_ws, size_t ws_size,
                              hipStream_t stream) {
    const float* x       = (const float*)d_in[0];
    const float* x_pool1 = (const float*)d_in[1];
    const float* W_in0   = (const float*)d_in[2];
    const float* W_h0    = (const float*)d_in[3];
    const float* b0      = (const float*)d_in[4];
    const float* g0      = (const float*)d_in[5];
    const float* be0     = (const float*)d_in[6];
    const float* m0      = (const float*)d_in[7];
    const float* v0      = (const float*)d_in[8];
    const float* W_in1   = (const float*)d_in[9];
    const float* W_h1    = (const float*)d_in[10];
    const float* b1      = (const float*)d_in[11];
    const float* g1      = (const float*)d_in[12];
    const float* be1     = (const float*)d_in[13];
    const float* m1      = (const float*)d_in[14];
    const float* v1      = (const float*)d_in[15];
    const float* linW0   = (const float*)d_in[16];
    const float* linb0   = (const float*)d_in[17];
    const float* linW1   = (const float*)d_in[18];
    const float* linb1   = (const float*)d_in[19];
    const int*   ei      = (const int*)d_in[20];
    const int*   batch   = (const int*)d_in[21];
    const int*   pool1   = (const int*)d_in[22];
    const int*   eip     = (const int*)d_in[23];
    float* outp = (float*)d_out;

    // carve workspace (256B-aligned); NO memset needed (every buffer fully written)
    char* p = (char*)d_ws;
    auto carve = [&](size_t bytes) -> void* {
        void* r = (void*)p;
        p += (bytes + 255) & ~(size_t)255;
        return r;
    };
    int* blockhist = (int*)carve((size_t)NBKT * NSCB * 4);
    int* hx        = (int*)carve((size_t)NBKT * NSCB * 4);
    int* bktSum    = (int*)carve((size_t)NBKT * 4);
    int* bktOff    = (int*)carve((size_t)(NBKT + 1) * 4);
    unsigned* ebkt = (unsigned*)carve((size_t)EALL * 4);

    int*   rp     = (int*)  carve((size_t)(NALL + 1) * 4);
    int*   rpf    = (int*)  carve((size_t)(NALL + 1) * 4);
    float* dinv   = (float*)carve((size_t)NALL * 4);
    int*   blkSum = (int*)  carve(256 * 4);
    int*   blkOff = (int*)  carve(256 * 4);
    unsigned* csw = (unsigned*)carve((size_t)EALL * 4 + 4096);  // +4KB overrun pad
    // region1: [xbf | z0bf] aliased later by g1bf (15.36 MB total)
    unsigned short* xbf  = (unsigned short*)carve((size_t)N0c * 256 * 2);
    unsigned short* z0bf = xbf + (size_t)N0c * 128;
    unsigned short* g1bf = xbf;                         // alias (xbf,z0bf dead)
    // region2: [g0bf | z1bf] aliased later by bufA (30.72 MB total)
    unsigned short* g0bf = (unsigned short*)carve((size_t)N0c * 256 * 4);
    unsigned short* z1bf = g0bf + (size_t)N0c * 256;
    float* bufA = (float*)g0bf;                         // alias (g0bf,z1bf dead)

    unsigned short* Wt0 = (unsigned short*)carve((size_t)256 * 128 * 2);
    unsigned short* Wt1 = (unsigned short*)carve((size_t)256 * 256 * 2);
    float* sc0 = (float*)carve(256 * 4);
    float* sh0 = (float*)carve(256 * 4);
    float* sc1 = (float*)carve(256 * 4);
    float* sh1 = (float*)carve(256 * 4);

    int*   start0 = (int*)  carve((size_t)(N1c + 1) * 4);
    int*   cnt0   = (int*)  carve((size_t)N1c * 4);
    float* pmean  = (float*)carve((size_t)N1c * 256 * 4);
    float* xp     = (float*)carve((size_t)N1c * 256 * 4);
    float* xb     = (float*)carve((size_t)N1c * 17 * 4);
    int*   bpool  = (int*)  carve((size_t)N1c * 4);
    unsigned short* hbbbf = (unsigned short*)carve((size_t)N1c * 256 * 2);
    float* zbb    = (float*)carve((size_t)N1c * 256 * 4);
    float* part   = (float*)carve((size_t)256 * 256 * 4);
    int*   pcnt   = (int*)  carve((size_t)256 * 4);

    const int* src0 = ei;
    const int* dst0 = ei + E0c;
    const int* src1 = eip;
    const int* dst1 = eip + E1c;

    // ---- CSR build: bucket sort, zero global atomics ----
    prep1<<<P1_CNT + P1_CVT + P1_PW + P1_SEG, 256, 0, stream>>>(
        dst0, dst1, blockhist, x, xbf, W_in0, W_h0, b0, g0, be0, m0, v0,
        Wt0, Wt1, sc0, sh0, sc1, sh1, pool1, start0);
    scanh_block<<<NBKT, 256, 0, stream>>>(blockhist, hx, bktSum);
    scanh_sums<<<1, 256, 0, stream>>>(bktSum, bktOff);
    scatter_e<<<NSCB, 256, 0, stream>>>(src0, dst0, src1, dst1, hx, bktOff, ebkt);
    int nb = cdiv_i(NALL, 256);                         // 129
    count_scan_n<<<nb, 256, 0, stream>>>(ebkt, bktOff, NALL, rp, blkSum, dinv);
    scan_sums<<<1, 256, 0, stream>>>(blkSum, nb, blkOff, rp, NALL);
    fill_csr<<<NBKT + FILL_TAIL, 256, 0, stream>>>(ebkt, bktOff, rp, blkOff, dinv,
                                                   csw, rpf);

    const int*   rp1   = rpf + N0c;
    const float* dinv1 = dinv + N0c;

    // ---- phase A: 3 GCN layers on N0 (layers 0/1: bf16 MFMA path) ----
    agg_bf16<16, 2, true><<<2 * cdiv_i(N0c, 8), 256, 0, stream>>>(xbf, rpf, csw, dinv, z0bf, N0c);
    gemm_mfma_bn<128><<<cdiv_i(N0c, 64), 256, 0, stream>>>(z0bf, Wt0, sc0, sh0, g0bf, N0c);
    agg_bf16<32, 4, true><<<4 * cdiv_i(N0c, 8), 256, 0, stream>>>(g0bf, rpf, csw, dinv, z1bf, N0c);
    gemm_mfma_bn<256><<<cdiv_i(N0c, 64), 256, 0, stream>>>(z1bf, Wt1, sc1, sh1, g1bf, N0c);
    agg_bf16<32, 4, false><<<4 * cdiv_i(N0c, 8), 256, 0, stream>>>(g1bf, rpf, csw, dinv, bufA, N0c);

    // layer 2: pool BEFORE GEMM (affine reorder); fp32 vector GEMM (precision)
    pool_mean<<<N1c, 64, 0, stream>>>(bufA, start0, batch, pmean, cnt0, bpool);
    gemm_bn<256, false, true, false><<<dim3(cdiv_i(N1c, 64), 4), 256, 0, stream>>>(
        pmean, W_h0 + Hc * Hc, b0 + 2 * Hc, g0 + 2 * Hc, be0 + 2 * Hc, m0 + 2 * Hc,
        v0 + 2 * Hc, cnt0, xp, N1c);

    // head0: logits + softmax -> d_out[0:48000], xb = [x0 | x_pool1]
    head0<<<N1c, 64, 0, stream>>>(xp, linW0, linb0, x_pool1, outp, xb);

    // ---- phase B: 3 GCN layers on N1 (fp32 vector GEMMs) ----
    agg17_gemm_bn<<<N1c, 256, 0, stream>>>(xb, rp1, csw, dinv1, W_in1, b1, g1, be1,
                                           m1, v1, hbbbf);
    agg_bf16<32, 4, false><<<4 * cdiv_i(N1c, 8), 256, 0, stream>>>(hbbbf, rp1, csw, dinv1, zbb, N1c);
    gemm_bn<256, true, false, true><<<dim3(cdiv_i(N1c, 64), 4), 256, 0, stream>>>(
        zbb, W_h1, b1 + Hc, g1 + Hc, be1 + Hc, m1 + Hc, v1 + Hc, nullptr, hbbbf, N1c);
    agg_bf16<32, 4, false><<<4 * cdiv_i(N1c, 8), 256, 0, stream>>>(hbbbf, rp1, csw, dinv1, zbb, N1c);

    // atomic-free 3000->16 reduction: 256-block partials, then head1 combines
    pool_b_partial<<<256, 256, 0, stream>>>(zbb, bpool, part, pcnt);
    head1<<<Bc, 256, 0, stream>>>(part, pcnt, W_h1 + Hc * Hc, b1 + 2 * Hc, g1 + 2 * Hc,
                                  be1 + 2 * Hc, m1 + 2 * Hc, v1 + 2 * Hc, linW1, linb1,
                                  outp);
}

// Round 5
// 397.096 us; speedup vs baseline: 1.0639x; 1.0100x over previous
//
#include <hip/hip_runtime.h>
#include <cstdint>
#include <cstddef>

// Problem constants
#define N0c 30000
#define F0c 128
#define Hc  256
#define Cc  16
#define N1c 3000
#define Bc  16
#define E0c 960000
#define E1c 48000
#define NALL 33000            // N0 + N1 (concatenated graphs)
#define EALL 1008000          // E0 + E1
#define EPSc 1e-5f
#define SLICE 188             // clusters per pool_b_partial slice (16*188 >= 3000)

// r17 bucket-sort CSR build: the 1M global atomicAdds were at a memory-side
// atomic throughput wall (~21/ns, 32MB sector writeback). LDS-histogram bucket
// sort: zero global atomics. bucket = dst>>5 (32 nodes), NBKT=1032.
#define NBKT 1032
#define NSCB 256
#define EPB  3938             // edges per scatter block (256*3938 >= EALL)

static __host__ __device__ inline int cdiv_i(int a, int b) { return (a + b - 1) / b; }

// round-to-nearest-even fp32 -> bf16 (returns the 16 bf16 bits)
static __device__ inline unsigned short bfbits(float f) {
    unsigned u = __float_as_uint(f);
    return (unsigned short)((u + 0x7fffu + ((u >> 16) & 1u)) >> 16);
}

typedef short short8 __attribute__((ext_vector_type(8)));   // 8 bf16 = 4 VGPRs
typedef float floatx4 __attribute__((ext_vector_type(4)));

// ---------------- prep1: bucket count (LDS hist) + indep prep work ------------
#define P1_CNT NSCB
#define P1_CVT 3750
#define P1_PW  386
#define P1_SEG 118

__global__ void prep1(const int* __restrict__ dst0, const int* __restrict__ dst1,
                      int* __restrict__ blockhist,
                      const float* __restrict__ x, unsigned short* __restrict__ xbf,
                      const float* __restrict__ W_in0, const float* __restrict__ W_h0,
                      const float* __restrict__ b0, const float* __restrict__ g0,
                      const float* __restrict__ be0, const float* __restrict__ m0,
                      const float* __restrict__ v0,
                      unsigned short* __restrict__ Wt0, unsigned short* __restrict__ Wt1,
                      float* __restrict__ sc0, float* __restrict__ sh0,
                      float* __restrict__ sc1, float* __restrict__ sh1,
                      const int* __restrict__ pool1, int* __restrict__ start0) {
    __shared__ int hist[NBKT];
    int bx = blockIdx.x, t = threadIdx.x;
    if (bx < P1_CNT) {
        for (int k = t; k < NBKT; k += 256) hist[k] = 0;
        __syncthreads();
        int e0 = bx * EPB, e1 = min(e0 + EPB, EALL);
        for (int e = e0 + t; e < e1; e += 256) {
            int d = (e < E0c) ? dst0[e] : (N0c + dst1[e - E0c]);
            atomicAdd(&hist[d >> 5], 1);
        }
        __syncthreads();
        for (int k = t; k < NBKT; k += 256) blockhist[k * NSCB + bx] = hist[k];
    } else if (bx < P1_CNT + P1_CVT) {
        int i = (bx - P1_CNT) * 256 + t;            // float4 index
        if (i >= N0c * 32) return;
        float4 v = ((const float4*)x)[i];
        ushort4 o;
        o.x = bfbits(v.x); o.y = bfbits(v.y); o.z = bfbits(v.z); o.w = bfbits(v.w);
        ((ushort4*)xbf)[i] = o;
    } else if (bx < P1_CNT + P1_CVT + P1_PW) {
        int pb = bx - P1_CNT - P1_CVT;
        if (pb < 128) {
            int i = pb * 256 + t;
            int k = i >> 8, col = i & 255;
            Wt0[col * 128 + k] = bfbits(W_in0[i]);
        } else if (pb < 384) {
            int i = (pb - 128) * 256 + t;
            int k = i >> 8, col = i & 255;
            Wt1[col * 256 + k] = bfbits(W_h0[i]);
        } else if (pb == 384) {
            float s = g0[t] * rsqrtf(v0[t] + EPSc);
            sc0[t] = s;
            sh0[t] = (b0[t] - m0[t]) * s + be0[t];
        } else {
            int tt = t + 256;
            float s = g0[tt] * rsqrtf(v0[tt] + EPSc);
            sc1[t] = s;
            sh1[t] = (b0[tt] - m0[tt]) * s + be0[tt];
        }
    } else {
        int i = (bx - P1_CNT - P1_CVT - P1_PW) * 256 + t;
        if (i > N0c) return;
        if (i == 0) {
            for (int c = 0; c <= pool1[0]; ++c) start0[c] = 0;
        } else if (i == N0c) {
            for (int c = pool1[N0c - 1] + 1; c <= N1c; ++c) start0[c] = N0c;
        } else {
            int a = pool1[i - 1], b = pool1[i];
            for (int c = a + 1; c <= b; ++c) start0[c] = i;
        }
    }
}

// scanh_block: block b = bucket b; exclusive scan of blockhist[b][0..255]
// -> hx (within-bucket offsets per scatter block) + bktSum[b] (bucket total)
__global__ void scanh_block(const int* __restrict__ blockhist, int* __restrict__ hx,
                            int* __restrict__ bktSum) {
    __shared__ int sh[256];
    int b = blockIdx.x, t = threadIdx.x;
    int v = blockhist[b * NSCB + t];
    sh[t] = v; __syncthreads();
    for (int off = 1; off < 256; off <<= 1) {
        int add = (t >= off) ? sh[t - off] : 0;
        __syncthreads();
        sh[t] += add;
        __syncthreads();
    }
    hx[b * NSCB + t] = sh[t] - v;
    if (t == 255) bktSum[b] = sh[255];
}

// scanh_sums: single block, carry-loop exclusive scan of NBKT bucket totals
__global__ void scanh_sums(const int* __restrict__ bktSum, int* __restrict__ bktOff) {
    __shared__ int sh[256];
    int t = threadIdx.x;
    int carry = 0;
    for (int k = 0; k < (NBKT + 255) / 256; ++k) {
        int i = k * 256 + t;
        int v = (i < NBKT) ? bktSum[i] : 0;
        sh[t] = v; __syncthreads();
        for (int off = 1; off < 256; off <<= 1) {
            int add = (t >= off) ? sh[t - off] : 0;
            __syncthreads();
            sh[t] += add;
            __syncthreads();
        }
        if (i < NBKT) bktOff[i] = carry + sh[t] - v;
        carry += sh[255];
        __syncthreads();
    }
    if (t == 0) bktOff[NBKT] = carry;   // == EALL
}

// scatter_e: re-read edges, place into bucket-grouped order via LDS base bump.
// pk = (dst_global << 16) | src_local  (both < 65536)
__global__ __launch_bounds__(256) void scatter_e(
    const int* __restrict__ src0, const int* __restrict__ dst0,
    const int* __restrict__ src1, const int* __restrict__ dst1,
    const int* __restrict__ hx, const int* __restrict__ bktOff,
    unsigned* __restrict__ ebkt) {
    __shared__ int base[NBKT];
    int blk = blockIdx.x, t = threadIdx.x;
    for (int k = t; k < NBKT; k += 256) base[k] = bktOff[k] + hx[k * NSCB + blk];
    __syncthreads();
    int e0 = blk * EPB, e1 = min(e0 + EPB, EALL);
    for (int e = e0 + t; e < e1; e += 256) {
        int s, d;
        if (e < E0c) { s = src0[e]; d = dst0[e]; }
        else         { s = src1[e - E0c]; d = N0c + dst1[e - E0c]; }
        int bkt = d >> 5;
        int pos = atomicAdd(&base[bkt], 1);
        ebkt[pos] = ((unsigned)d << 16) | (unsigned)s;
    }
}

// count_scan_n: block b owns nodes [b*256, b*256+256) = buckets [8b, 8b+8).
// Degree count from bucketed edges (LDS hist, block-owned nodes -> no global
// atomics), dinv = rsqrt(deg+1), block-level exclusive scan of degrees.
__global__ void count_scan_n(const unsigned* __restrict__ ebkt,
                             const int* __restrict__ bktOff, int n,
                             int* __restrict__ rp, int* __restrict__ blkSum,
                             float* __restrict__ dinv) {
    __shared__ int hist[256];
    __shared__ int sh[256];
    int b = blockIdx.x, t = threadIdx.x;
    hist[t] = 0; __syncthreads();
    int lo = bktOff[b * 8];
    int hi = bktOff[b * 8 + 8];
    for (int e = lo + t; e < hi; e += 256) {
        int d = (int)(ebkt[e] >> 16);
        atomicAdd(&hist[d - b * 256], 1);
    }
    __syncthreads();
    int i = b * 256 + t;
    int v = hist[t];
    if (i < n) dinv[i] = rsqrtf((float)(v + 1));
    sh[t] = v; __syncthreads();
    for (int off = 1; off < 256; off <<= 1) {
        int add = (t >= off) ? sh[t - off] : 0;
        __syncthreads();
        sh[t] += add;
        __syncthreads();
    }
    if (i < n) rp[i] = sh[t] - v;
    if (t == 255) blkSum[b] = sh[255];
}

__global__ void scan_sums(const int* __restrict__ blkSum, int nb, int* __restrict__ blkOff,
                          int* __restrict__ rp, int n) {
    __shared__ int sh[256];
    int t = threadIdx.x;
    int v = (t < nb) ? blkSum[t] : 0;
    sh[t] = v; __syncthreads();
    for (int off = 1; off < 256; off <<= 1) {
        int add = (t >= off) ? sh[t - off] : 0;
        __syncthreads();
        sh[t] += add;
        __syncthreads();
    }
    blkOff[t] = sh[t] - v;
    if (t == 255) rp[n] = sh[255];
}

// fill_csr: one block per bucket; LDS rank counters over the bucket's 32
// nodes place each edge at its final CSR slot. Tail blocks build rpf.
// r20: extra CLST blocks compute per-cluster cnt0 + bpool (moved out of the
// deleted pool_mean kernel; start0 is ready after prep1).
#define FILL_TAIL 129
#define FILL_CLST 12
__global__ __launch_bounds__(256) void fill_csr(
    const unsigned* __restrict__ ebkt, const int* __restrict__ bktOff,
    const int* __restrict__ rp, const int* __restrict__ blkOff,
    const float* __restrict__ dinv, unsigned* __restrict__ csw,
    int* __restrict__ rpf, const int* __restrict__ start0,
    const int* __restrict__ batch, int* __restrict__ cnt0,
    int* __restrict__ bpool) {
    int bx = blockIdx.x, t = threadIdx.x;
    if (bx < NBKT) {
        __shared__ int lrp[32];
        __shared__ float ldv[32];
        __shared__ int cnt[32];
        if (t < 32) {
            int node = bx * 32 + t;
            cnt[t] = 0;
            if (node < NALL) {
                lrp[t] = rp[node] + blkOff[node >> 8];
                ldv[t] = dinv[node];
            } else { lrp[t] = 0; ldv[t] = 0.f; }
        }
        __syncthreads();
        int lo = bktOff[bx], hi = bktOff[bx + 1];
        for (int e = lo + t; e < hi; e += 256) {
            unsigned pk = ebkt[e];
            int d = (int)(pk >> 16);
            int sloc = (int)(pk & 0xffffu);
            int dl = d & 31;
            int lr = atomicAdd(&cnt[dl], 1);
            int sg = (d >= N0c) ? (N0c + sloc) : sloc;
            float w = dinv[sg] * ldv[dl];
            csw[lrp[dl] + lr] = ((unsigned)bfbits(w) << 16) | (unsigned)sloc;
        }
    } else if (bx < NBKT + FILL_TAIL) {
        int i = (bx - NBKT) * 256 + t;
        if (i < NALL) rpf[i] = rp[i] + blkOff[i >> 8];
        else if (i == NALL) rpf[NALL] = rp[NALL];
    } else {
        int c = (bx - NBKT - FILL_TAIL) * 256 + t;
        if (c < N1c) {
            int s = start0[c], e = start0[c + 1];
            int cnt = e - s;
            cnt0[c] = cnt;
            int sb = 0;
            for (int i = s; i < e; ++i) sb += batch[i];
            bpool[c] = (int)rintf((float)sb / (float)max(cnt, 1));
        }
    }
}

// ---------------- aggregation (bf16 gather, fp32 accumulate) ----------------

static __device__ inline void acc8(float a[8], float w, uint4 v) {
    a[0] += w * __uint_as_float(v.x << 16);
    a[1] += w * __uint_as_float(v.x & 0xffff0000u);
    a[2] += w * __uint_as_float(v.y << 16);
    a[3] += w * __uint_as_float(v.y & 0xffff0000u);
    a[4] += w * __uint_as_float(v.z << 16);
    a[5] += w * __uint_as_float(v.z & 0xffff0000u);
    a[6] += w * __uint_as_float(v.w << 16);
    a[7] += w * __uint_as_float(v.w & 0xffff0000u);
}

// TWO nodes per wave, FOUR edge slots each (lane = ns*32 + par*8 + cl).
// NCHUNK chunks of 64 cols; chunk = blockIdx&(NCHUNK-1) keeps XCD pinning
// (64-col bf16 chunk of 30000 rows = 3.84MB, fits 4MB per-XCD L2).
// r19: per-lane direct csw loads (8 same-address lanes merge in L1), 4-deep
// gather pipeline, cndmask'd zero weights for the tail (exact no-op).
template <int RSU, int NCHUNK, bool OBF16>
__global__ __launch_bounds__(256) void agg_bf16(
    const unsigned short* __restrict__ x, const int* __restrict__ rp,
    const unsigned* __restrict__ csw, const float* __restrict__ dinv,
    void* __restrict__ zv, int N) {
    constexpr int SHIFT = (RSU == 32) ? 9 : 8;   // log2(row bytes)
    int b = blockIdx.x;
    int chunk = b & (NCHUNK - 1);
    int wave = threadIdx.x >> 6;
    int lane = threadIdx.x & 63;
    int ns = lane >> 5;                  // node sub (0/1)
    int par = (lane >> 3) & 3;           // edge slot (0..3)
    int cl = lane & 7;                   // 16B slice within 64-col chunk
    int node = (b / NCHUNK) * 8 + wave * 2 + ns;
    bool valid = node < N;
    int nclamp = valid ? node : 0;
    int c4 = chunk * 8 + cl;
    unsigned coff = (unsigned)c4 << 4;
    const char* xb = (const char*)x;
    float a[8] = {0.f, 0.f, 0.f, 0.f, 0.f, 0.f, 0.f, 0.f};
    int e0 = rp[nclamp];
    int e1 = valid ? rp[nclamp + 1] : e0;
    if (valid && par == 0) {             // self-loop term exactly once
        float di = dinv[node];
        uint4 v = *(const uint4*)(xb + (((unsigned)node << SHIFT) + coff));
        acc8(a, di * di, v);
    }
    int deg = e1 - e0;
    int mysteps = (deg + 3) >> 2;
    int steps = max(__shfl(mysteps, 0, 64), __shfl(mysteps, 32, 64));  // uniform
    int e = e0 + par;                    // this lane's first edge slot
    // direct loads (no clamp: csw padded; garbage is dead via the e<e1 select)
    unsigned cw0 = csw[e];      cw0 = (e      < e1) ? cw0 : 0u;
    unsigned cw1 = csw[e + 4];  cw1 = (e + 4  < e1) ? cw1 : 0u;
    unsigned cw2 = csw[e + 8];  cw2 = (e + 8  < e1) ? cw2 : 0u;
    unsigned cw3 = csw[e + 12]; cw3 = (e + 12 < e1) ? cw3 : 0u;
    int i = 0;
    for (; i + 3 < steps; i += 4) {
        // 4 gathers in flight (addresses depend only on already-loaded cw*)
        uint4 v0 = *(const uint4*)(xb + (((cw0 & 0xffffu) << SHIFT) + coff));
        uint4 v1 = *(const uint4*)(xb + (((cw1 & 0xffffu) << SHIFT) + coff));
        uint4 v2 = *(const uint4*)(xb + (((cw2 & 0xffffu) << SHIFT) + coff));
        uint4 v3 = *(const uint4*)(xb + (((cw3 & 0xffffu) << SHIFT) + coff));
        // prefetch next group's edge words under the gathers
        int en = e + 16;
        unsigned nw0 = csw[en];      nw0 = (en      < e1) ? nw0 : 0u;
        unsigned nw1 = csw[en + 4];  nw1 = (en + 4  < e1) ? nw1 : 0u;
        unsigned nw2 = csw[en + 8];  nw2 = (en + 8  < e1) ? nw2 : 0u;
        unsigned nw3 = csw[en + 12]; nw3 = (en + 12 < e1) ? nw3 : 0u;
        acc8(a, __uint_as_float(cw0 & 0xffff0000u), v0);
        acc8(a, __uint_as_float(cw1 & 0xffff0000u), v1);
        acc8(a, __uint_as_float(cw2 & 0xffff0000u), v2);
        acc8(a, __uint_as_float(cw3 & 0xffff0000u), v3);
        cw0 = nw0; cw1 = nw1; cw2 = nw2; cw3 = nw3;
        e = en;
    }
    // tail (steps is wave-uniform -> uniform branches; cw* already loaded)
    if (i < steps) {
        uint4 v = *(const uint4*)(xb + (((cw0 & 0xffffu) << SHIFT) + coff));
        acc8(a, __uint_as_float(cw0 & 0xffff0000u), v);
    }
    if (i + 1 < steps) {
        uint4 v = *(const uint4*)(xb + (((cw1 & 0xffffu) << SHIFT) + coff));
        acc8(a, __uint_as_float(cw1 & 0xffff0000u), v);
    }
    if (i + 2 < steps) {
        uint4 v = *(const uint4*)(xb + (((cw2 & 0xffffu) << SHIFT) + coff));
        acc8(a, __uint_as_float(cw2 & 0xffff0000u), v);
    }
    // reduce across the 4 edge slots (2 levels, stays within each node half)
#pragma unroll
    for (int m = 8; m < 32; m <<= 1) {
#pragma unroll
        for (int k = 0; k < 8; ++k) a[k] += __shfl_xor(a[k], m, 64);
    }
    if (valid && par == 0) {
        if (OBF16) {
            uint4 o;
            o.x = (unsigned)bfbits(a[0]) | ((unsigned)bfbits(a[1]) << 16);
            o.y = (unsigned)bfbits(a[2]) | ((unsigned)bfbits(a[3]) << 16);
            o.z = (unsigned)bfbits(a[4]) | ((unsigned)bfbits(a[5]) << 16);
            o.w = (unsigned)bfbits(a[6]) | ((unsigned)bfbits(a[7]) << 16);
            ((uint4*)zv)[(size_t)node * RSU + c4] = o;
        } else {
            float4* zp = (float4*)zv + (size_t)node * (RSU * 2) + c4 * 2;
            zp[0] = make_float4(a[0], a[1], a[2], a[3]);
            zp[1] = make_float4(a[4], a[5], a[6], a[7]);
        }
    }
}

// r20: fused layer-2 aggregation + mean-pool. pool1 is SORTED -> cluster c
// owns the contiguous node range [start0[c], start0[c+1]) AND the contiguous
// edge slice csw[rpf[start0[c]] .. rpf[start0[c+1]]). So Pool(Agg(x)) needs
// NO new CSR: aggregate edges straight into 3000 cluster rows, add per-member
// self-loop terms (dinv[m]^2 * x[m]), scale by 1/cnt, write 3MB fp32 (was:
// 30.7MB write + 30.7MB read + pool_mean kernel). Gather traffic unchanged.
template <int NCHUNK>
__global__ __launch_bounds__(256) void agg_pool(
    const unsigned short* __restrict__ x, const int* __restrict__ rpf,
    const unsigned* __restrict__ csw, const float* __restrict__ dinv,
    const int* __restrict__ start0, float* __restrict__ out, int N) {
    constexpr int SHIFT = 9;             // 256-col bf16 rows = 512 B
    int b = blockIdx.x;
    int chunk = b & (NCHUNK - 1);
    int wave = threadIdx.x >> 6;
    int lane = threadIdx.x & 63;
    int ns = lane >> 5;
    int par = (lane >> 3) & 3;
    int cl = lane & 7;
    int c = (b / NCHUNK) * 8 + wave * 2 + ns;
    bool valid = c < N;
    int cc = valid ? c : 0;
    int c4 = chunk * 8 + cl;
    unsigned coff = (unsigned)c4 << 4;
    const char* xb = (const char*)x;
    float a[8] = {0.f, 0.f, 0.f, 0.f, 0.f, 0.f, 0.f, 0.f};
    int s0 = start0[cc];
    int s1 = valid ? start0[cc + 1] : s0;
    int e0 = rpf[s0];
    int e1 = valid ? rpf[s1] : e0;
    // self-loop terms for member nodes, par-strided (members are contiguous)
    for (int m = s0 + par; m < s1; m += 4) {
        float di = dinv[m];
        uint4 v = *(const uint4*)(xb + (((unsigned)m << SHIFT) + coff));
        acc8(a, di * di, v);
    }
    int deg = e1 - e0;
    int mysteps = (deg + 3) >> 2;
    int steps = max(__shfl(mysteps, 0, 64), __shfl(mysteps, 32, 64));
    int e = e0 + par;
    unsigned cw0 = csw[e];      cw0 = (e      < e1) ? cw0 : 0u;
    unsigned cw1 = csw[e + 4];  cw1 = (e + 4  < e1) ? cw1 : 0u;
    unsigned cw2 = csw[e + 8];  cw2 = (e + 8  < e1) ? cw2 : 0u;
    unsigned cw3 = csw[e + 12]; cw3 = (e + 12 < e1) ? cw3 : 0u;
    int i = 0;
    for (; i + 3 < steps; i += 4) {
        uint4 v0 = *(const uint4*)(xb + (((cw0 & 0xffffu) << SHIFT) + coff));
        uint4 v1 = *(const uint4*)(xb + (((cw1 & 0xffffu) << SHIFT) + coff));
        uint4 v2 = *(const uint4*)(xb + (((cw2 & 0xffffu) << SHIFT) + coff));
        uint4 v3 = *(const uint4*)(xb + (((cw3 & 0xffffu) << SHIFT) + coff));
        int en = e + 16;
        unsigned nw0 = csw[en];      nw0 = (en      < e1) ? nw0 : 0u;
        unsigned nw1 = csw[en + 4];  nw1 = (en + 4  < e1) ? nw1 : 0u;
        unsigned nw2 = csw[en + 8];  nw2 = (en + 8  < e1) ? nw2 : 0u;
        unsigned nw3 = csw[en + 12]; nw3 = (en + 12 < e1) ? nw3 : 0u;
        acc8(a, __uint_as_float(cw0 & 0xffff0000u), v0);
        acc8(a, __uint_as_float(cw1 & 0xffff0000u), v1);
        acc8(a, __uint_as_float(cw2 & 0xffff0000u), v2);
        acc8(a, __uint_as_float(cw3 & 0xffff0000u), v3);
        cw0 = nw0; cw1 = nw1; cw2 = nw2; cw3 = nw3;
        e = en;
    }
    if (i < steps) {
        uint4 v = *(const uint4*)(xb + (((cw0 & 0xffffu) << SHIFT) + coff));
        acc8(a, __uint_as_float(cw0 & 0xffff0000u), v);
    }
    if (i + 1 < steps) {
        uint4 v = *(const uint4*)(xb + (((cw1 & 0xffffu) << SHIFT) + coff));
        acc8(a, __uint_as_float(cw1 & 0xffff0000u), v);
    }
    if (i + 2 < steps) {
        uint4 v = *(const uint4*)(xb + (((cw2 & 0xffffu) << SHIFT) + coff));
        acc8(a, __uint_as_float(cw2 & 0xffff0000u), v);
    }
#pragma unroll
    for (int m = 8; m < 32; m <<= 1) {
#pragma unroll
        for (int k = 0; k < 8; ++k) a[k] += __shfl_xor(a[k], m, 64);
    }
    if (valid && par == 0) {
        float inv = 1.0f / (float)max(s1 - s0, 1);
        float4* zp = (float4*)out + (size_t)c * 64 + c4 * 2;
        zp[0] = make_float4(a[0] * inv, a[1] * inv, a[2] * inv, a[3] * inv);
        zp[1] = make_float4(a[4] * inv, a[5] * inv, a[6] * inv, a[7] * inv);
    }
}

// ---------------- MFMA bf16 GEMM: (M x K)bf16 @ Wt(256 x K)bf16 -> bf16 out ----

template <int K>
__global__ __launch_bounds__(256) void gemm_mfma_bn(
    const unsigned short* __restrict__ A, const unsigned short* __restrict__ Wt,
    const float* __restrict__ sc, const float* __restrict__ sh,
    unsigned short* __restrict__ out, int M) {
    constexpr int LDS_S = 40;
    __shared__ unsigned short As[64 * LDS_S];
    __shared__ unsigned short Bs[256 * LDS_S];
    int tid = threadIdx.x;
    int w = tid >> 6, l = tid & 63;
    int quad = l >> 4, lm = l & 15;
    int row0 = blockIdx.x * 64;
    floatx4 acc[4][4];
#pragma unroll
    for (int i = 0; i < 4; ++i)
#pragma unroll
        for (int j = 0; j < 4; ++j) acc[i][j] = (floatx4){0.f, 0.f, 0.f, 0.f};

    int ar = tid >> 2;          // A staging: row 0..63
    int ac = (tid & 3) * 8;     // short offset 0,8,16,24

    for (int k0 = 0; k0 < K; k0 += 32) {
        uint4 av = make_uint4(0, 0, 0, 0);
        if (row0 + ar < M) av = *(const uint4*)(A + (size_t)(row0 + ar) * K + k0 + ac);
        *(uint4*)&As[ar * LDS_S + ac] = av;
#pragma unroll
        for (int c = 0; c < 4; ++c) {    // Bs: thread -> col tid, 4 k-chunks
            uint4 bv = *(const uint4*)(Wt + (size_t)tid * K + k0 + c * 8);
            *(uint4*)&Bs[tid * LDS_S + c * 8] = bv;
        }
        __syncthreads();
        short8 af[4], bf[4];
#pragma unroll
        for (int i = 0; i < 4; ++i)
            af[i] = *(const short8*)&As[(i * 16 + lm) * LDS_S + quad * 8];
#pragma unroll
        for (int j = 0; j < 4; ++j)
            bf[j] = *(const short8*)&Bs[(w * 64 + j * 16 + lm) * LDS_S + quad * 8];
#pragma unroll
        for (int i = 0; i < 4; ++i)
#pragma unroll
            for (int j = 0; j < 4; ++j)
                acc[i][j] = __builtin_amdgcn_mfma_f32_16x16x32_bf16(af[i], bf[j], acc[i][j], 0, 0, 0);
        __syncthreads();
    }
    // epilogue: C/D map col=lane&15, row=quad*4+reg [verified m89/m91]
#pragma unroll
    for (int j = 0; j < 4; ++j) {
        int col = w * 64 + j * 16 + lm;
        float s = sc[col], h = sh[col];
#pragma unroll
        for (int i = 0; i < 4; ++i) {
            int rb = row0 + i * 16 + quad * 4;
#pragma unroll
            for (int r = 0; r < 4; ++r) {
                int row = rb + r;
                if (row < M) {
                    float v = acc[i][j][r] * s + h;
                    v = fmaxf(v, 0.f);
                    out[(size_t)row * 256 + col] = bfbits(v);
                }
            }
        }
    }
}

// ---------------- fp32 vector GEMM (kept for small M=3000, precision-critical) --

template <int K, bool RELU, bool ZEROEMPTY, bool OBF16>
__global__ __launch_bounds__(256) void gemm_bn(
    const float* __restrict__ A, const float* __restrict__ W,
    const float* __restrict__ bias, const float* __restrict__ gam,
    const float* __restrict__ bet, const float* __restrict__ mu,
    const float* __restrict__ var, const int* __restrict__ cnt,
    void* __restrict__ outv, int M) {
    __shared__ __align__(16) float As[16][64];
    __shared__ __align__(16) float Bs[16][64];
    int tid = threadIdx.x;
    int tm = tid >> 4, tn = tid & 15;
    int row0 = blockIdx.x * 64, col0 = blockIdx.y * 64;
    float acc[4][4] = {};
    int ar = tid >> 2;
    int ak = (tid & 3) * 4;
    int bk = tid >> 4;
    int bn = (tid & 15) * 4;

    for (int kk = 0; kk < K; kk += 16) {
        float4 av = make_float4(0.f, 0.f, 0.f, 0.f);
        int grow = row0 + ar;
        if (grow < M) av = *(const float4*)(A + (size_t)grow * K + kk + ak);
        As[ak + 0][ar] = av.x;
        As[ak + 1][ar] = av.y;
        As[ak + 2][ar] = av.z;
        As[ak + 3][ar] = av.w;
        float4 bv = *(const float4*)(W + (size_t)(kk + bk) * 256 + col0 + bn);
        *(float4*)&Bs[bk][bn] = bv;
        __syncthreads();
#pragma unroll
        for (int k = 0; k < 16; ++k) {
            float4 a = *(const float4*)&As[k][tm * 4];
            float4 b = *(const float4*)&Bs[k][tn * 4];
            acc[0][0] += a.x * b.x; acc[0][1] += a.x * b.y; acc[0][2] += a.x * b.z; acc[0][3] += a.x * b.w;
            acc[1][0] += a.y * b.x; acc[1][1] += a.y * b.y; acc[1][2] += a.y * b.z; acc[1][3] += a.y * b.w;
            acc[2][0] += a.z * b.x; acc[2][1] += a.z * b.y; acc[2][2] += a.z * b.z; acc[2][3] += a.z * b.w;
            acc[3][0] += a.w * b.x; acc[3][1] += a.w * b.y; acc[3][2] += a.w * b.z; acc[3][3] += a.w * b.w;
        }
        __syncthreads();
    }
    float bcol[4], scol[4], mcol[4], ecol[4];
#pragma unroll
    for (int j = 0; j < 4; ++j) {
        int col = col0 + tn * 4 + j;
        bcol[j] = bias[col];
        scol[j] = gam[col] * rsqrtf(var[col] + EPSc);
        mcol[j] = mu[col];
        ecol[j] = bet[col];
    }
#pragma unroll
    for (int i = 0; i < 4; ++i) {
        int row = row0 + tm * 4 + i;
        if (row >= M) continue;
        bool zero = false;
        if (ZEROEMPTY) zero = (cnt[row] == 0);
        float r[4];
#pragma unroll
        for (int j = 0; j < 4; ++j) {
            float v = acc[i][j] + bcol[j];
            v = (v - mcol[j]) * scol[j] + ecol[j];
            if (RELU) v = fmaxf(v, 0.f);
            if (zero) v = 0.f;
            r[j] = v;
        }
        if (OBF16) {
            ushort4 o;
            o.x = bfbits(r[0]); o.y = bfbits(r[1]); o.z = bfbits(r[2]); o.w = bfbits(r[3]);
            *(ushort4*)((unsigned short*)outv + (size_t)row * 256 + col0 + tn * 4) = o;
        } else {
            float4 o = make_float4(r[0], r[1], r[2], r[3]);
            *(float4*)((float*)outv + (size_t)row * 256 + col0 + tn * 4) = o;
        }
    }
}

// fused: 17-wide aggregation (graph 1) + K=17 GEMM + BN + ReLU, bf16 out
__global__ void agg17_gemm_bn(const float* __restrict__ xb, const int* __restrict__ rp,
                              const unsigned* __restrict__ csw, const float* __restrict__ dinv,
                              const float* __restrict__ W, const float* __restrict__ bias,
                              const float* __restrict__ gam, const float* __restrict__ bet,
                              const float* __restrict__ mu, const float* __restrict__ var,
                              unsigned short* __restrict__ out) {
    int r = blockIdx.x, t = threadIdx.x;   // 256 threads
    __shared__ float zr[17];
    if (t < 17) {
        float di = dinv[r];
        float acc = di * di * xb[(size_t)r * 17 + t];
        int e0 = rp[r], e1 = rp[r + 1];
        for (int e = e0; e < e1; ++e) {
            unsigned ew = csw[e];
            acc += __uint_as_float(ew & 0xffff0000u) * xb[(size_t)(ew & 0xffffu) * 17 + t];
        }
        zr[t] = acc;
    }
    __syncthreads();
    float acc = bias[t];
#pragma unroll
    for (int k = 0; k < 17; ++k) acc += zr[k] * W[k * 256 + t];
    float s = gam[t] * rsqrtf(var[t] + EPSc);
    acc = (acc - mu[t]) * s + bet[t];
    acc = fmaxf(acc, 0.f);
    out[(size_t)r * 256 + t] = bfbits(acc);
}

// ---------------- pooling ----------------

// stage 1 of atomic-free 3000->16 reduction: 256 blocks = 16 graphs x 16 slices.
__global__ __launch_bounds__(256) void pool_b_partial(
    const float* __restrict__ zbb, const int* __restrict__ bpool,
    float* __restrict__ part, int* __restrict__ pcnt) {
    int b = blockIdx.x;          // 0..255
    int g = b & 15, s = b >> 4;
    int t = threadIdx.x;
    int i0 = s * SLICE;
    int n = min(N1c - i0, SLICE);
    __shared__ int bp[SLICE];
    for (int i = t; i < n; i += 256) bp[i] = bpool[i0 + i];
    __syncthreads();
    float acc = 0.f;
    int c = 0;
    for (int i = 0; i < n; ++i) {
        int hit = (bp[i] == g);
        float sel = hit ? 1.f : 0.f;
        acc += sel * zbb[(size_t)(i0 + i) * 256 + t];   // load NOT branch-gated
        c += hit;
    }
    part[(size_t)b * 256 + t] = acc;
    if (t == 0) pcnt[b] = c;
}

// ---------------- heads ----------------

__global__ void head0(const float* __restrict__ xp, const float* __restrict__ linW,
                      const float* __restrict__ linb, const float* __restrict__ xpool1,
                      float* __restrict__ outp, float* __restrict__ xb) {
    int r = blockIdx.x, t = threadIdx.x;  // 64 threads
    __shared__ float xr[256];
    __shared__ float lg[16];
    __shared__ float ex[16];
#pragma unroll
    for (int j = 0; j < 4; ++j) xr[t + 64 * j] = xp[(size_t)r * 256 + t + 64 * j];
    __syncthreads();
    if (t < 16) {
        float acc = linb[t];
        for (int k = 0; k < 256; ++k) acc += xr[k] * linW[k * 16 + t];
        lg[t] = acc;
    }
    __syncthreads();
    if (t < 16) {
        float mx = lg[0];
#pragma unroll
        for (int c = 1; c < 16; ++c) mx = fmaxf(mx, lg[c]);
        ex[t] = expf(lg[t] - mx);
    }
    __syncthreads();
    if (t < 16) {
        float sum = 0.f;
#pragma unroll
        for (int c = 0; c < 16; ++c) sum += ex[c];
        float pv = ex[t] / sum;
        outp[(size_t)r * 16 + t] = pv;
        xb[(size_t)r * 17 + t] = pv;
    }
    if (t == 16) xb[(size_t)r * 17 + 16] = xpool1[r];
}

// head1: sum 16 partials -> mean -> layer2 GEMM+BN -> logits -> softmax
__global__ void head1(const float* __restrict__ part, const int* __restrict__ pcnt,
                      const float* __restrict__ W, const float* __restrict__ bias,
                      const float* __restrict__ gam, const float* __restrict__ bet,
                      const float* __restrict__ mu, const float* __restrict__ var,
                      const float* __restrict__ linW, const float* __restrict__ linb,
                      float* __restrict__ outp) {
    int b = blockIdx.x, t = threadIdx.x;  // 16 blocks x 256 threads
    __shared__ float pr[256];
    __shared__ float yr[256];
    __shared__ float lg[16];
    __shared__ float ex[16];
    float acc0 = 0.f;
    int c = 0;
#pragma unroll
    for (int s = 0; s < 16; ++s) {
        int pb = s * 16 + b;
        acc0 += part[(size_t)pb * 256 + t];
        c += pcnt[pb];
    }
    float inv = 1.0f / (float)max(c, 1);
    pr[t] = acc0 * inv;
    __syncthreads();
    float acc = bias[t];
    for (int k = 0; k < 256; ++k) acc += pr[k] * W[k * 256 + t];
    float s = gam[t] * rsqrtf(var[t] + EPSc);
    acc = (acc - mu[t]) * s + bet[t];
    if (c == 0) acc = 0.f;
    yr[t] = acc;
    __syncthreads();
    if (t < 16) {
        float l = linb[t];
        for (int k = 0; k < 256; ++k) l += yr[k] * linW[k * 16 + t];
        lg[t] = l;
    }
    __syncthreads();
    if (t < 16) {
        float mx = lg[0];
#pragma unroll
        for (int cc = 1; cc < 16; ++cc) mx = fmaxf(mx, lg[cc]);
        ex[t] = expf(lg[t] - mx);
    }
    __syncthreads();
    if (t < 16) {
        float sum = 0.f;
#pragma unroll
        for (int cc = 0; cc < 16; ++cc) sum += ex[cc];
        outp[48000 + b * 16 + t] = ex[t] / sum;
    }
}

// ---------------- launch ----------------

extern "C" void kernel_launch(void* const* d_in, const int* in_sizes, int n_in,
                              void* d_out, int out_size, void* d_ws, size_t ws_size,
                              hipStream_t stream) {
    const float* x       = (const float*)d_in[0];
    const float* x_pool1 = (const float*)d_in[1];
    const float* W_in0   = (const float*)d_in[2];
    const float* W_h0    = (const float*)d_in[3];
    const float* b0      = (const float*)d_in[4];
    const float* g0      = (const float*)d_in[5];
    const float* be0     = (const float*)d_in[6];
    const float* m0      = (const float*)d_in[7];
    const float* v0      = (const float*)d_in[8];
    const float* W_in1   = (const float*)d_in[9];
    const float* W_h1    = (const float*)d_in[10];
    const float* b1      = (const float*)d_in[11];
    const float* g1      = (const float*)d_in[12];
    const float* be1     = (const float*)d_in[13];
    const float* m1      = (const float*)d_in[14];
    const float* v1      = (const float*)d_in[15];
    const float* linW0   = (const float*)d_in[16];
    const float* linb0   = (const float*)d_in[17];
    const float* linW1   = (const float*)d_in[18];
    const float* linb1   = (const float*)d_in[19];
    const int*   ei      = (const int*)d_in[20];
    const int*   batch   = (const int*)d_in[21];
    const int*   pool1   = (const int*)d_in[22];
    const int*   eip     = (const int*)d_in[23];
    float* outp = (float*)d_out;

    // carve workspace (256B-aligned); NO memset needed (every buffer fully written)
    char* p = (char*)d_ws;
    auto carve = [&](size_t bytes) -> void* {
        void* r = (void*)p;
        p += (bytes + 255) & ~(size_t)255;
        return r;
    };
    int* blockhist = (int*)carve((size_t)NBKT * NSCB * 4);
    int* hx        = (int*)carve((size_t)NBKT * NSCB * 4);
    int* bktSum    = (int*)carve((size_t)NBKT * 4);
    int* bktOff    = (int*)carve((size_t)(NBKT + 1) * 4);
    unsigned* ebkt = (unsigned*)carve((size_t)EALL * 4);

    int*   rp     = (int*)  carve((size_t)(NALL + 1) * 4);
    int*   rpf    = (int*)  carve((size_t)(NALL + 1) * 4);
    float* dinv   = (float*)carve((size_t)NALL * 4);
    int*   blkSum = (int*)  carve(256 * 4);
    int*   blkOff = (int*)  carve(256 * 4);
    unsigned* csw = (unsigned*)carve((size_t)EALL * 4 + 4096);  // +4KB overrun pad
    // region1: [xbf | z0bf] aliased later by g1bf (15.36 MB total)
    unsigned short* xbf  = (unsigned short*)carve((size_t)N0c * 256 * 2);
    unsigned short* z0bf = xbf + (size_t)N0c * 128;
    unsigned short* g1bf = xbf;                         // alias (xbf,z0bf dead)
    // region2: [g0bf | z1bf] (30.72 MB total)
    unsigned short* g0bf = (unsigned short*)carve((size_t)N0c * 256 * 4);
    unsigned short* z1bf = g0bf + (size_t)N0c * 256;

    unsigned short* Wt0 = (unsigned short*)carve((size_t)256 * 128 * 2);
    unsigned short* Wt1 = (unsigned short*)carve((size_t)256 * 256 * 2);
    float* sc0 = (float*)carve(256 * 4);
    float* sh0 = (float*)carve(256 * 4);
    float* sc1 = (float*)carve(256 * 4);
    float* sh1 = (float*)carve(256 * 4);

    int*   start0 = (int*)  carve((size_t)(N1c + 1) * 4);
    int*   cnt0   = (int*)  carve((size_t)N1c * 4);
    float* pmean  = (float*)carve((size_t)N1c * 256 * 4);
    float* xp     = (float*)carve((size_t)N1c * 256 * 4);
    float* xb     = (float*)carve((size_t)N1c * 17 * 4);
    int*   bpool  = (int*)  carve((size_t)N1c * 4);
    unsigned short* hbbbf = (unsigned short*)carve((size_t)N1c * 256 * 2);
    float* zbb    = (float*)carve((size_t)N1c * 256 * 4);
    float* part   = (float*)carve((size_t)256 * 256 * 4);
    int*   pcnt   = (int*)  carve((size_t)256 * 4);

    const int* src0 = ei;
    const int* dst0 = ei + E0c;
    const int* src1 = eip;
    const int* dst1 = eip + E1c;

    // ---- CSR build: bucket sort, zero global atomics ----
    prep1<<<P1_CNT + P1_CVT + P1_PW + P1_SEG, 256, 0, stream>>>(
        dst0, dst1, blockhist, x, xbf, W_in0, W_h0, b0, g0, be0, m0, v0,
        Wt0, Wt1, sc0, sh0, sc1, sh1, pool1, start0);
    scanh_block<<<NBKT, 256, 0, stream>>>(blockhist, hx, bktSum);
    scanh_sums<<<1, 256, 0, stream>>>(bktSum, bktOff);
    scatter_e<<<NSCB, 256, 0, stream>>>(src0, dst0, src1, dst1, hx, bktOff, ebkt);
    int nb = cdiv_i(NALL, 256);                         // 129
    count_scan_n<<<nb, 256, 0, stream>>>(ebkt, bktOff, NALL, rp, blkSum, dinv);
    scan_sums<<<1, 256, 0, stream>>>(blkSum, nb, blkOff, rp, NALL);
    fill_csr<<<NBKT + FILL_TAIL + FILL_CLST, 256, 0, stream>>>(
        ebkt, bktOff, rp, blkOff, dinv, csw, rpf, start0, batch, cnt0, bpool);

    const int*   rp1   = rpf + N0c;
    const float* dinv1 = dinv + N0c;

    // ---- phase A: 3 GCN layers on N0 (layers 0/1: bf16 MFMA path) ----
    agg_bf16<16, 2, true><<<2 * cdiv_i(N0c, 8), 256, 0, stream>>>(xbf, rpf, csw, dinv, z0bf, N0c);
    gemm_mfma_bn<128><<<cdiv_i(N0c, 64), 256, 0, stream>>>(z0bf, Wt0, sc0, sh0, g0bf, N0c);
    agg_bf16<32, 4, true><<<4 * cdiv_i(N0c, 8), 256, 0, stream>>>(g0bf, rpf, csw, dinv, z1bf, N0c);
    gemm_mfma_bn<256><<<cdiv_i(N0c, 64), 256, 0, stream>>>(z1bf, Wt1, sc1, sh1, g1bf, N0c);

    // layer 2: FUSED agg+mean-pool straight into 3000 cluster rows (r20)
    agg_pool<4><<<4 * cdiv_i(N1c, 8), 256, 0, stream>>>(g1bf, rpf, csw, dinv,
                                                        start0, pmean, N1c);
    gemm_bn<256, false, true, false><<<dim3(cdiv_i(N1c, 64), 4), 256, 0, stream>>>(
        pmean, W_h0 + Hc * Hc, b0 + 2 * Hc, g0 + 2 * Hc, be0 + 2 * Hc, m0 + 2 * Hc,
        v0 + 2 * Hc, cnt0, xp, N1c);

    // head0: logits + softmax -> d_out[0:48000], xb = [x0 | x_pool1]
    head0<<<N1c, 64, 0, stream>>>(xp, linW0, linb0, x_pool1, outp, xb);

    // ---- phase B: 3 GCN layers on N1 (fp32 vector GEMMs) ----
    agg17_gemm_bn<<<N1c, 256, 0, stream>>>(xb, rp1, csw, dinv1, W_in1, b1, g1, be1,
                                           m1, v1, hbbbf);
    agg_bf16<32, 4, false><<<4 * cdiv_i(N1c, 8), 256, 0, stream>>>(hbbbf, rp1, csw, dinv1, zbb, N1c);
    gemm_bn<256, true, false, true><<<dim3(cdiv_i(N1c, 64), 4), 256, 0, stream>>>(
        zbb, W_h1, b1 + Hc, g1 + Hc, be1 + Hc, m1 + Hc, v1 + Hc, nullptr, hbbbf, N1c);
    agg_bf16<32, 4, false><<<4 * cdiv_i(N1c, 8), 256, 0, stream>>>(hbbbf, rp1, csw, dinv1, zbb, N1c);

    // atomic-free 3000->16 reduction: 256-block partials, then head1 combines
    pool_b_partial<<<256, 256, 0, stream>>>(zbb, bpool, part, pcnt);
    head1<<<Bc, 256, 0, stream>>>(part, pcnt, W_h1 + Hc * Hc, b1 + 2 * Hc, g1 + 2 * Hc,
                                  be1 + 2 * Hc, m1 + 2 * Hc, v1 + 2 * Hc, linW1, linb1,
                                  outp);
}

// Round 6
// 387.461 us; speedup vs baseline: 1.0903x; 1.0249x over previous
//
#include <hip/hip_runtime.h>
#include <cstdint>
#include <cstddef>

// Problem constants
#define N0c 30000
#define F0c 128
#define Hc  256
#define Cc  16
#define N1c 3000
#define Bc  16
#define E0c 960000
#define E1c 48000
#define NALL 33000            // N0 + N1 (concatenated graphs)
#define EALL 1008000          // E0 + E1
#define EPSc 1e-5f
#define SLICE 188             // clusters per pool_b_partial slice (16*188 >= 3000)

// r17 bucket-sort CSR build: the 1M global atomicAdds were at a memory-side
// atomic throughput wall (~21/ns, 32MB sector writeback). LDS-histogram bucket
// sort: zero global atomics. bucket = dst>>5 (32 nodes), NBKT=1032.
#define NBKT 1032
#define NSCB 256
#define EPB  3938             // edges per scatter block (256*3938 >= EALL)

static __host__ __device__ inline int cdiv_i(int a, int b) { return (a + b - 1) / b; }

// round-to-nearest-even fp32 -> bf16 (returns the 16 bf16 bits)
static __device__ inline unsigned short bfbits(float f) {
    unsigned u = __float_as_uint(f);
    return (unsigned short)((u + 0x7fffu + ((u >> 16) & 1u)) >> 16);
}

typedef short short8 __attribute__((ext_vector_type(8)));   // 8 bf16 = 4 VGPRs
typedef float floatx4 __attribute__((ext_vector_type(4)));

// ---------------- prep1: bucket count (LDS hist) + indep prep work ------------
#define P1_CNT NSCB
#define P1_CVT 3750
#define P1_PW  386
#define P1_SEG 118

__global__ void prep1(const int* __restrict__ dst0, const int* __restrict__ dst1,
                      int* __restrict__ blockhist,
                      const float* __restrict__ x, unsigned short* __restrict__ xbf,
                      const float* __restrict__ W_in0, const float* __restrict__ W_h0,
                      const float* __restrict__ b0, const float* __restrict__ g0,
                      const float* __restrict__ be0, const float* __restrict__ m0,
                      const float* __restrict__ v0,
                      unsigned short* __restrict__ Wt0, unsigned short* __restrict__ Wt1,
                      float* __restrict__ sc0, float* __restrict__ sh0,
                      float* __restrict__ sc1, float* __restrict__ sh1,
                      const int* __restrict__ pool1, int* __restrict__ start0) {
    __shared__ int hist[NBKT];
    int bx = blockIdx.x, t = threadIdx.x;
    if (bx < P1_CNT) {
        for (int k = t; k < NBKT; k += 256) hist[k] = 0;
        __syncthreads();
        int e0 = bx * EPB, e1 = min(e0 + EPB, EALL);
        for (int e = e0 + t; e < e1; e += 256) {
            int d = (e < E0c) ? dst0[e] : (N0c + dst1[e - E0c]);
            atomicAdd(&hist[d >> 5], 1);
        }
        __syncthreads();
        for (int k = t; k < NBKT; k += 256) blockhist[k * NSCB + bx] = hist[k];
    } else if (bx < P1_CNT + P1_CVT) {
        int i = (bx - P1_CNT) * 256 + t;            // float4 index
        if (i >= N0c * 32) return;
        float4 v = ((const float4*)x)[i];
        ushort4 o;
        o.x = bfbits(v.x); o.y = bfbits(v.y); o.z = bfbits(v.z); o.w = bfbits(v.w);
        ((ushort4*)xbf)[i] = o;
    } else if (bx < P1_CNT + P1_CVT + P1_PW) {
        int pb = bx - P1_CNT - P1_CVT;
        if (pb < 128) {
            int i = pb * 256 + t;
            int k = i >> 8, col = i & 255;
            Wt0[col * 128 + k] = bfbits(W_in0[i]);
        } else if (pb < 384) {
            int i = (pb - 128) * 256 + t;
            int k = i >> 8, col = i & 255;
            Wt1[col * 256 + k] = bfbits(W_h0[i]);
        } else if (pb == 384) {
            float s = g0[t] * rsqrtf(v0[t] + EPSc);
            sc0[t] = s;
            sh0[t] = (b0[t] - m0[t]) * s + be0[t];
        } else {
            int tt = t + 256;
            float s = g0[tt] * rsqrtf(v0[tt] + EPSc);
            sc1[t] = s;
            sh1[t] = (b0[tt] - m0[tt]) * s + be0[tt];
        }
    } else {
        int i = (bx - P1_CNT - P1_CVT - P1_PW) * 256 + t;
        if (i > N0c) return;
        if (i == 0) {
            for (int c = 0; c <= pool1[0]; ++c) start0[c] = 0;
        } else if (i == N0c) {
            for (int c = pool1[N0c - 1] + 1; c <= N1c; ++c) start0[c] = N0c;
        } else {
            int a = pool1[i - 1], b = pool1[i];
            for (int c = a + 1; c <= b; ++c) start0[c] = i;
        }
    }
}

// scanh_block: block b = bucket b; exclusive scan of blockhist[b][0..255]
// -> hx (within-bucket offsets per scatter block) + bktSum[b] (bucket total)
__global__ void scanh_block(const int* __restrict__ blockhist, int* __restrict__ hx,
                            int* __restrict__ bktSum) {
    __shared__ int sh[256];
    int b = blockIdx.x, t = threadIdx.x;
    int v = blockhist[b * NSCB + t];
    sh[t] = v; __syncthreads();
    for (int off = 1; off < 256; off <<= 1) {
        int add = (t >= off) ? sh[t - off] : 0;
        __syncthreads();
        sh[t] += add;
        __syncthreads();
    }
    hx[b * NSCB + t] = sh[t] - v;
    if (t == 255) bktSum[b] = sh[255];
}

// scanh_sums: single block, carry-loop exclusive scan of NBKT bucket totals
__global__ void scanh_sums(const int* __restrict__ bktSum, int* __restrict__ bktOff) {
    __shared__ int sh[256];
    int t = threadIdx.x;
    int carry = 0;
    for (int k = 0; k < (NBKT + 255) / 256; ++k) {
        int i = k * 256 + t;
        int v = (i < NBKT) ? bktSum[i] : 0;
        sh[t] = v; __syncthreads();
        for (int off = 1; off < 256; off <<= 1) {
            int add = (t >= off) ? sh[t - off] : 0;
            __syncthreads();
            sh[t] += add;
            __syncthreads();
        }
        if (i < NBKT) bktOff[i] = carry + sh[t] - v;
        carry += sh[255];
        __syncthreads();
    }
    if (t == 0) bktOff[NBKT] = carry;   // == EALL
}

// scatter_e: re-read edges, place into bucket-grouped order via LDS base bump.
// pk = (dst_global << 16) | src_local  (both < 65536)
__global__ __launch_bounds__(256) void scatter_e(
    const int* __restrict__ src0, const int* __restrict__ dst0,
    const int* __restrict__ src1, const int* __restrict__ dst1,
    const int* __restrict__ hx, const int* __restrict__ bktOff,
    unsigned* __restrict__ ebkt) {
    __shared__ int base[NBKT];
    int blk = blockIdx.x, t = threadIdx.x;
    for (int k = t; k < NBKT; k += 256) base[k] = bktOff[k] + hx[k * NSCB + blk];
    __syncthreads();
    int e0 = blk * EPB, e1 = min(e0 + EPB, EALL);
    for (int e = e0 + t; e < e1; e += 256) {
        int s, d;
        if (e < E0c) { s = src0[e]; d = dst0[e]; }
        else         { s = src1[e - E0c]; d = N0c + dst1[e - E0c]; }
        int bkt = d >> 5;
        int pos = atomicAdd(&base[bkt], 1);
        ebkt[pos] = ((unsigned)d << 16) | (unsigned)s;
    }
}

// count_scan_n: block b owns nodes [b*256, b*256+256) = buckets [8b, 8b+8).
// Degree count from bucketed edges (LDS hist, block-owned nodes -> no global
// atomics), dinv = rsqrt(deg+1), block-level exclusive scan of degrees.
__global__ void count_scan_n(const unsigned* __restrict__ ebkt,
                             const int* __restrict__ bktOff, int n,
                             int* __restrict__ rp, int* __restrict__ blkSum,
                             float* __restrict__ dinv) {
    __shared__ int hist[256];
    __shared__ int sh[256];
    int b = blockIdx.x, t = threadIdx.x;
    hist[t] = 0; __syncthreads();
    int lo = bktOff[b * 8];
    int hi = bktOff[b * 8 + 8];
    for (int e = lo + t; e < hi; e += 256) {
        int d = (int)(ebkt[e] >> 16);
        atomicAdd(&hist[d - b * 256], 1);
    }
    __syncthreads();
    int i = b * 256 + t;
    int v = hist[t];
    if (i < n) dinv[i] = rsqrtf((float)(v + 1));
    sh[t] = v; __syncthreads();
    for (int off = 1; off < 256; off <<= 1) {
        int add = (t >= off) ? sh[t - off] : 0;
        __syncthreads();
        sh[t] += add;
        __syncthreads();
    }
    if (i < n) rp[i] = sh[t] - v;
    if (t == 255) blkSum[b] = sh[255];
}

__global__ void scan_sums(const int* __restrict__ blkSum, int nb, int* __restrict__ blkOff,
                          int* __restrict__ rp, int n) {
    __shared__ int sh[256];
    int t = threadIdx.x;
    int v = (t < nb) ? blkSum[t] : 0;
    sh[t] = v; __syncthreads();
    for (int off = 1; off < 256; off <<= 1) {
        int add = (t >= off) ? sh[t - off] : 0;
        __syncthreads();
        sh[t] += add;
        __syncthreads();
    }
    blkOff[t] = sh[t] - v;
    if (t == 255) rp[n] = sh[255];
}

// fill_csr: one block per bucket; LDS rank counters over the bucket's 32
// nodes place each edge at its final CSR slot. Tail blocks build rpf.
// r20: extra CLST blocks compute per-cluster cnt0 + bpool (moved out of the
// deleted pool_mean kernel; start0 is ready after prep1).
#define FILL_TAIL 129
#define FILL_CLST 12
__global__ __launch_bounds__(256) void fill_csr(
    const unsigned* __restrict__ ebkt, const int* __restrict__ bktOff,
    const int* __restrict__ rp, const int* __restrict__ blkOff,
    const float* __restrict__ dinv, unsigned* __restrict__ csw,
    int* __restrict__ rpf, const int* __restrict__ start0,
    const int* __restrict__ batch, int* __restrict__ cnt0,
    int* __restrict__ bpool) {
    int bx = blockIdx.x, t = threadIdx.x;
    if (bx < NBKT) {
        __shared__ int lrp[32];
        __shared__ float ldv[32];
        __shared__ int cnt[32];
        if (t < 32) {
            int node = bx * 32 + t;
            cnt[t] = 0;
            if (node < NALL) {
                lrp[t] = rp[node] + blkOff[node >> 8];
                ldv[t] = dinv[node];
            } else { lrp[t] = 0; ldv[t] = 0.f; }
        }
        __syncthreads();
        int lo = bktOff[bx], hi = bktOff[bx + 1];
        for (int e = lo + t; e < hi; e += 256) {
            unsigned pk = ebkt[e];
            int d = (int)(pk >> 16);
            int sloc = (int)(pk & 0xffffu);
            int dl = d & 31;
            int lr = atomicAdd(&cnt[dl], 1);
            int sg = (d >= N0c) ? (N0c + sloc) : sloc;
            float w = dinv[sg] * ldv[dl];
            csw[lrp[dl] + lr] = ((unsigned)bfbits(w) << 16) | (unsigned)sloc;
        }
    } else if (bx < NBKT + FILL_TAIL) {
        int i = (bx - NBKT) * 256 + t;
        if (i < NALL) rpf[i] = rp[i] + blkOff[i >> 8];
        else if (i == NALL) rpf[NALL] = rp[NALL];
    } else {
        int c = (bx - NBKT - FILL_TAIL) * 256 + t;
        if (c < N1c) {
            int s = start0[c], e = start0[c + 1];
            int cnt = e - s;
            cnt0[c] = cnt;
            int sb = 0;
            for (int i = s; i < e; ++i) sb += batch[i];
            bpool[c] = (int)rintf((float)sb / (float)max(cnt, 1));
        }
    }
}

// ---------------- aggregation (bf16 gather, fp32 accumulate) ----------------

static __device__ inline void acc8(float a[8], float w, uint4 v) {
    a[0] += w * __uint_as_float(v.x << 16);
    a[1] += w * __uint_as_float(v.x & 0xffff0000u);
    a[2] += w * __uint_as_float(v.y << 16);
    a[3] += w * __uint_as_float(v.y & 0xffff0000u);
    a[4] += w * __uint_as_float(v.z << 16);
    a[5] += w * __uint_as_float(v.z & 0xffff0000u);
    a[6] += w * __uint_as_float(v.w << 16);
    a[7] += w * __uint_as_float(v.w & 0xffff0000u);
}

// TWO nodes per wave, FOUR edge slots each (lane = ns*32 + par*8 + cl).
// NCHUNK chunks of 64 cols; chunk = blockIdx&(NCHUNK-1) keeps XCD pinning
// (64-col bf16 chunk of 30000 rows = 3.84MB, fits 4MB per-XCD L2).
// r19: per-lane direct csw loads (8 same-address lanes merge in L1), 4-deep
// gather pipeline, cndmask'd zero weights for the tail (exact no-op).
template <int RSU, int NCHUNK, bool OBF16>
__global__ __launch_bounds__(256) void agg_bf16(
    const unsigned short* __restrict__ x, const int* __restrict__ rp,
    const unsigned* __restrict__ csw, const float* __restrict__ dinv,
    void* __restrict__ zv, int N) {
    constexpr int SHIFT = (RSU == 32) ? 9 : 8;   // log2(row bytes)
    int b = blockIdx.x;
    int chunk = b & (NCHUNK - 1);
    int wave = threadIdx.x >> 6;
    int lane = threadIdx.x & 63;
    int ns = lane >> 5;                  // node sub (0/1)
    int par = (lane >> 3) & 3;           // edge slot (0..3)
    int cl = lane & 7;                   // 16B slice within 64-col chunk
    int node = (b / NCHUNK) * 8 + wave * 2 + ns;
    bool valid = node < N;
    int nclamp = valid ? node : 0;
    int c4 = chunk * 8 + cl;
    unsigned coff = (unsigned)c4 << 4;
    const char* xb = (const char*)x;
    float a[8] = {0.f, 0.f, 0.f, 0.f, 0.f, 0.f, 0.f, 0.f};
    int e0 = rp[nclamp];
    int e1 = valid ? rp[nclamp + 1] : e0;
    if (valid && par == 0) {             // self-loop term exactly once
        float di = dinv[node];
        uint4 v = *(const uint4*)(xb + (((unsigned)node << SHIFT) + coff));
        acc8(a, di * di, v);
    }
    int deg = e1 - e0;
    int mysteps = (deg + 3) >> 2;
    int steps = max(__shfl(mysteps, 0, 64), __shfl(mysteps, 32, 64));  // uniform
    int e = e0 + par;                    // this lane's first edge slot
    // direct loads (no clamp: csw padded; garbage is dead via the e<e1 select)
    unsigned cw0 = csw[e];      cw0 = (e      < e1) ? cw0 : 0u;
    unsigned cw1 = csw[e + 4];  cw1 = (e + 4  < e1) ? cw1 : 0u;
    unsigned cw2 = csw[e + 8];  cw2 = (e + 8  < e1) ? cw2 : 0u;
    unsigned cw3 = csw[e + 12]; cw3 = (e + 12 < e1) ? cw3 : 0u;
    int i = 0;
    for (; i + 3 < steps; i += 4) {
        // 4 gathers in flight (addresses depend only on already-loaded cw*)
        uint4 v0 = *(const uint4*)(xb + (((cw0 & 0xffffu) << SHIFT) + coff));
        uint4 v1 = *(const uint4*)(xb + (((cw1 & 0xffffu) << SHIFT) + coff));
        uint4 v2 = *(const uint4*)(xb + (((cw2 & 0xffffu) << SHIFT) + coff));
        uint4 v3 = *(const uint4*)(xb + (((cw3 & 0xffffu) << SHIFT) + coff));
        // prefetch next group's edge words under the gathers
        int en = e + 16;
        unsigned nw0 = csw[en];      nw0 = (en      < e1) ? nw0 : 0u;
        unsigned nw1 = csw[en + 4];  nw1 = (en + 4  < e1) ? nw1 : 0u;
        unsigned nw2 = csw[en + 8];  nw2 = (en + 8  < e1) ? nw2 : 0u;
        unsigned nw3 = csw[en + 12]; nw3 = (en + 12 < e1) ? nw3 : 0u;
        acc8(a, __uint_as_float(cw0 & 0xffff0000u), v0);
        acc8(a, __uint_as_float(cw1 & 0xffff0000u), v1);
        acc8(a, __uint_as_float(cw2 & 0xffff0000u), v2);
        acc8(a, __uint_as_float(cw3 & 0xffff0000u), v3);
        cw0 = nw0; cw1 = nw1; cw2 = nw2; cw3 = nw3;
        e = en;
    }
    // tail (steps is wave-uniform -> uniform branches; cw* already loaded)
    if (i < steps) {
        uint4 v = *(const uint4*)(xb + (((cw0 & 0xffffu) << SHIFT) + coff));
        acc8(a, __uint_as_float(cw0 & 0xffff0000u), v);
    }
    if (i + 1 < steps) {
        uint4 v = *(const uint4*)(xb + (((cw1 & 0xffffu) << SHIFT) + coff));
        acc8(a, __uint_as_float(cw1 & 0xffff0000u), v);
    }
    if (i + 2 < steps) {
        uint4 v = *(const uint4*)(xb + (((cw2 & 0xffffu) << SHIFT) + coff));
        acc8(a, __uint_as_float(cw2 & 0xffff0000u), v);
    }
    // reduce across the 4 edge slots (2 levels, stays within each node half)
#pragma unroll
    for (int m = 8; m < 32; m <<= 1) {
#pragma unroll
        for (int k = 0; k < 8; ++k) a[k] += __shfl_xor(a[k], m, 64);
    }
    if (valid && par == 0) {
        if (OBF16) {
            uint4 o;
            o.x = (unsigned)bfbits(a[0]) | ((unsigned)bfbits(a[1]) << 16);
            o.y = (unsigned)bfbits(a[2]) | ((unsigned)bfbits(a[3]) << 16);
            o.z = (unsigned)bfbits(a[4]) | ((unsigned)bfbits(a[5]) << 16);
            o.w = (unsigned)bfbits(a[6]) | ((unsigned)bfbits(a[7]) << 16);
            ((uint4*)zv)[(size_t)node * RSU + c4] = o;
        } else {
            float4* zp = (float4*)zv + (size_t)node * (RSU * 2) + c4 * 2;
            zp[0] = make_float4(a[0], a[1], a[2], a[3]);
            zp[1] = make_float4(a[4], a[5], a[6], a[7]);
        }
    }
}

// r20/r21: fused layer-2 aggregation + mean-pool. pool1 is SORTED -> cluster c
// owns the contiguous node range [start0[c], start0[c+1]) AND the contiguous
// edge slice csw[rpf[start0[c]] .. rpf[start0[c+1]]). r21: ONE cluster per
// wave, EIGHT edge slots (lane = par*8 + cl) — r20's 2-clusters/4-slots shape
// had 32% occupancy + ~84-step serial chains (mean cluster deg ~336). Now:
// 2x waves (3000 blocks), steps = deg/8 ~ 42, 32 edges in flight per wave,
// per-wave-uniform trip count (no cross-pair max).
template <int NCHUNK>
__global__ __launch_bounds__(256) void agg_pool(
    const unsigned short* __restrict__ x, const int* __restrict__ rpf,
    const unsigned* __restrict__ csw, const float* __restrict__ dinv,
    const int* __restrict__ start0, float* __restrict__ out, int N) {
    constexpr int SHIFT = 9;             // 256-col bf16 rows = 512 B
    int b = blockIdx.x;
    int chunk = b & (NCHUNK - 1);
    int wave = threadIdx.x >> 6;
    int lane = threadIdx.x & 63;
    int par = lane >> 3;                 // edge slot (0..7)
    int cl = lane & 7;                   // 16B slice within 64-col chunk
    int c = (b / NCHUNK) * 4 + wave;
    bool valid = c < N;
    int cc = valid ? c : 0;
    int c4 = chunk * 8 + cl;
    unsigned coff = (unsigned)c4 << 4;
    const char* xb = (const char*)x;
    float a[8] = {0.f, 0.f, 0.f, 0.f, 0.f, 0.f, 0.f, 0.f};
    int s0 = start0[cc];
    int s1 = valid ? start0[cc + 1] : s0;
    int e0 = rpf[s0];
    int e1 = valid ? rpf[s1] : e0;
    // self-loop terms for member nodes, par-strided (members are contiguous)
    for (int m = s0 + par; m < s1; m += 8) {
        float di = dinv[m];
        uint4 v = *(const uint4*)(xb + (((unsigned)m << SHIFT) + coff));
        acc8(a, di * di, v);
    }
    int deg = e1 - e0;
    int steps = (deg + 7) >> 3;          // wave-uniform (one cluster per wave)
    int e = e0 + par;
    unsigned cw0 = csw[e];      cw0 = (e      < e1) ? cw0 : 0u;
    unsigned cw1 = csw[e + 8];  cw1 = (e + 8  < e1) ? cw1 : 0u;
    unsigned cw2 = csw[e + 16]; cw2 = (e + 16 < e1) ? cw2 : 0u;
    unsigned cw3 = csw[e + 24]; cw3 = (e + 24 < e1) ? cw3 : 0u;
    int i = 0;
    for (; i + 3 < steps; i += 4) {
        uint4 v0 = *(const uint4*)(xb + (((cw0 & 0xffffu) << SHIFT) + coff));
        uint4 v1 = *(const uint4*)(xb + (((cw1 & 0xffffu) << SHIFT) + coff));
        uint4 v2 = *(const uint4*)(xb + (((cw2 & 0xffffu) << SHIFT) + coff));
        uint4 v3 = *(const uint4*)(xb + (((cw3 & 0xffffu) << SHIFT) + coff));
        int en = e + 32;
        unsigned nw0 = csw[en];      nw0 = (en      < e1) ? nw0 : 0u;
        unsigned nw1 = csw[en + 8];  nw1 = (en + 8  < e1) ? nw1 : 0u;
        unsigned nw2 = csw[en + 16]; nw2 = (en + 16 < e1) ? nw2 : 0u;
        unsigned nw3 = csw[en + 24]; nw3 = (en + 24 < e1) ? nw3 : 0u;
        acc8(a, __uint_as_float(cw0 & 0xffff0000u), v0);
        acc8(a, __uint_as_float(cw1 & 0xffff0000u), v1);
        acc8(a, __uint_as_float(cw2 & 0xffff0000u), v2);
        acc8(a, __uint_as_float(cw3 & 0xffff0000u), v3);
        cw0 = nw0; cw1 = nw1; cw2 = nw2; cw3 = nw3;
        e = en;
    }
    if (i < steps) {
        uint4 v = *(const uint4*)(xb + (((cw0 & 0xffffu) << SHIFT) + coff));
        acc8(a, __uint_as_float(cw0 & 0xffff0000u), v);
    }
    if (i + 1 < steps) {
        uint4 v = *(const uint4*)(xb + (((cw1 & 0xffffu) << SHIFT) + coff));
        acc8(a, __uint_as_float(cw1 & 0xffff0000u), v);
    }
    if (i + 2 < steps) {
        uint4 v = *(const uint4*)(xb + (((cw2 & 0xffffu) << SHIFT) + coff));
        acc8(a, __uint_as_float(cw2 & 0xffff0000u), v);
    }
    // reduce across the 8 edge slots (3 levels, full wave)
#pragma unroll
    for (int m = 8; m < 64; m <<= 1) {
#pragma unroll
        for (int k = 0; k < 8; ++k) a[k] += __shfl_xor(a[k], m, 64);
    }
    if (valid && par == 0) {
        float inv = 1.0f / (float)max(s1 - s0, 1);
        float4* zp = (float4*)out + (size_t)c * 64 + c4 * 2;
        zp[0] = make_float4(a[0] * inv, a[1] * inv, a[2] * inv, a[3] * inv);
        zp[1] = make_float4(a[4] * inv, a[5] * inv, a[6] * inv, a[7] * inv);
    }
}

// ---------------- MFMA bf16 GEMM: (M x K)bf16 @ Wt(256 x K)bf16 -> bf16 out ----

template <int K>
__global__ __launch_bounds__(256) void gemm_mfma_bn(
    const unsigned short* __restrict__ A, const unsigned short* __restrict__ Wt,
    const float* __restrict__ sc, const float* __restrict__ sh,
    unsigned short* __restrict__ out, int M) {
    constexpr int LDS_S = 40;
    __shared__ unsigned short As[64 * LDS_S];
    __shared__ unsigned short Bs[256 * LDS_S];
    int tid = threadIdx.x;
    int w = tid >> 6, l = tid & 63;
    int quad = l >> 4, lm = l & 15;
    int row0 = blockIdx.x * 64;
    floatx4 acc[4][4];
#pragma unroll
    for (int i = 0; i < 4; ++i)
#pragma unroll
        for (int j = 0; j < 4; ++j) acc[i][j] = (floatx4){0.f, 0.f, 0.f, 0.f};

    int ar = tid >> 2;          // A staging: row 0..63
    int ac = (tid & 3) * 8;     // short offset 0,8,16,24

    for (int k0 = 0; k0 < K; k0 += 32) {
        uint4 av = make_uint4(0, 0, 0, 0);
        if (row0 + ar < M) av = *(const uint4*)(A + (size_t)(row0 + ar) * K + k0 + ac);
        *(uint4*)&As[ar * LDS_S + ac] = av;
#pragma unroll
        for (int c = 0; c < 4; ++c) {    // Bs: thread -> col tid, 4 k-chunks
            uint4 bv = *(const uint4*)(Wt + (size_t)tid * K + k0 + c * 8);
            *(uint4*)&Bs[tid * LDS_S + c * 8] = bv;
        }
        __syncthreads();
        short8 af[4], bf[4];
#pragma unroll
        for (int i = 0; i < 4; ++i)
            af[i] = *(const short8*)&As[(i * 16 + lm) * LDS_S + quad * 8];
#pragma unroll
        for (int j = 0; j < 4; ++j)
            bf[j] = *(const short8*)&Bs[(w * 64 + j * 16 + lm) * LDS_S + quad * 8];
#pragma unroll
        for (int i = 0; i < 4; ++i)
#pragma unroll
            for (int j = 0; j < 4; ++j)
                acc[i][j] = __builtin_amdgcn_mfma_f32_16x16x32_bf16(af[i], bf[j], acc[i][j], 0, 0, 0);
        __syncthreads();
    }
    // epilogue: C/D map col=lane&15, row=quad*4+reg [verified m89/m91]
#pragma unroll
    for (int j = 0; j < 4; ++j) {
        int col = w * 64 + j * 16 + lm;
        float s = sc[col], h = sh[col];
#pragma unroll
        for (int i = 0; i < 4; ++i) {
            int rb = row0 + i * 16 + quad * 4;
#pragma unroll
            for (int r = 0; r < 4; ++r) {
                int row = rb + r;
                if (row < M) {
                    float v = acc[i][j][r] * s + h;
                    v = fmaxf(v, 0.f);
                    out[(size_t)row * 256 + col] = bfbits(v);
                }
            }
        }
    }
}

// ---------------- fp32 vector GEMM (kept for small M=3000, precision-critical) --

template <int K, bool RELU, bool ZEROEMPTY, bool OBF16>
__global__ __launch_bounds__(256) void gemm_bn(
    const float* __restrict__ A, const float* __restrict__ W,
    const float* __restrict__ bias, const float* __restrict__ gam,
    const float* __restrict__ bet, const float* __restrict__ mu,
    const float* __restrict__ var, const int* __restrict__ cnt,
    void* __restrict__ outv, int M) {
    __shared__ __align__(16) float As[16][64];
    __shared__ __align__(16) float Bs[16][64];
    int tid = threadIdx.x;
    int tm = tid >> 4, tn = tid & 15;
    int row0 = blockIdx.x * 64, col0 = blockIdx.y * 64;
    float acc[4][4] = {};
    int ar = tid >> 2;
    int ak = (tid & 3) * 4;
    int bk = tid >> 4;
    int bn = (tid & 15) * 4;

    for (int kk = 0; kk < K; kk += 16) {
        float4 av = make_float4(0.f, 0.f, 0.f, 0.f);
        int grow = row0 + ar;
        if (grow < M) av = *(const float4*)(A + (size_t)grow * K + kk + ak);
        As[ak + 0][ar] = av.x;
        As[ak + 1][ar] = av.y;
        As[ak + 2][ar] = av.z;
        As[ak + 3][ar] = av.w;
        float4 bv = *(const float4*)(W + (size_t)(kk + bk) * 256 + col0 + bn);
        *(float4*)&Bs[bk][bn] = bv;
        __syncthreads();
#pragma unroll
        for (int k = 0; k < 16; ++k) {
            float4 a = *(const float4*)&As[k][tm * 4];
            float4 b = *(const float4*)&Bs[k][tn * 4];
            acc[0][0] += a.x * b.x; acc[0][1] += a.x * b.y; acc[0][2] += a.x * b.z; acc[0][3] += a.x * b.w;
            acc[1][0] += a.y * b.x; acc[1][1] += a.y * b.y; acc[1][2] += a.y * b.z; acc[1][3] += a.y * b.w;
            acc[2][0] += a.z * b.x; acc[2][1] += a.z * b.y; acc[2][2] += a.z * b.z; acc[2][3] += a.z * b.w;
            acc[3][0] += a.w * b.x; acc[3][1] += a.w * b.y; acc[3][2] += a.w * b.z; acc[3][3] += a.w * b.w;
        }
        __syncthreads();
    }
    float bcol[4], scol[4], mcol[4], ecol[4];
#pragma unroll
    for (int j = 0; j < 4; ++j) {
        int col = col0 + tn * 4 + j;
        bcol[j] = bias[col];
        scol[j] = gam[col] * rsqrtf(var[col] + EPSc);
        mcol[j] = mu[col];
        ecol[j] = bet[col];
    }
#pragma unroll
    for (int i = 0; i < 4; ++i) {
        int row = row0 + tm * 4 + i;
        if (row >= M) continue;
        bool zero = false;
        if (ZEROEMPTY) zero = (cnt[row] == 0);
        float r[4];
#pragma unroll
        for (int j = 0; j < 4; ++j) {
            float v = acc[i][j] + bcol[j];
            v = (v - mcol[j]) * scol[j] + ecol[j];
            if (RELU) v = fmaxf(v, 0.f);
            if (zero) v = 0.f;
            r[j] = v;
        }
        if (OBF16) {
            ushort4 o;
            o.x = bfbits(r[0]); o.y = bfbits(r[1]); o.z = bfbits(r[2]); o.w = bfbits(r[3]);
            *(ushort4*)((unsigned short*)outv + (size_t)row * 256 + col0 + tn * 4) = o;
        } else {
            float4 o = make_float4(r[0], r[1], r[2], r[3]);
            *(float4*)((float*)outv + (size_t)row * 256 + col0 + tn * 4) = o;
        }
    }
}

// fused: 17-wide aggregation (graph 1) + K=17 GEMM + BN + ReLU, bf16 out
__global__ void agg17_gemm_bn(const float* __restrict__ xb, const int* __restrict__ rp,
                              const unsigned* __restrict__ csw, const float* __restrict__ dinv,
                              const float* __restrict__ W, const float* __restrict__ bias,
                              const float* __restrict__ gam, const float* __restrict__ bet,
                              const float* __restrict__ mu, const float* __restrict__ var,
                              unsigned short* __restrict__ out) {
    int r = blockIdx.x, t = threadIdx.x;   // 256 threads
    __shared__ float zr[17];
    if (t < 17) {
        float di = dinv[r];
        float acc = di * di * xb[(size_t)r * 17 + t];
        int e0 = rp[r], e1 = rp[r + 1];
        for (int e = e0; e < e1; ++e) {
            unsigned ew = csw[e];
            acc += __uint_as_float(ew & 0xffff0000u) * xb[(size_t)(ew & 0xffffu) * 17 + t];
        }
        zr[t] = acc;
    }
    __syncthreads();
    float acc = bias[t];
#pragma unroll
    for (int k = 0; k < 17; ++k) acc += zr[k] * W[k * 256 + t];
    float s = gam[t] * rsqrtf(var[t] + EPSc);
    acc = (acc - mu[t]) * s + bet[t];
    acc = fmaxf(acc, 0.f);
    out[(size_t)r * 256 + t] = bfbits(acc);
}

// ---------------- pooling ----------------

// stage 1 of atomic-free 3000->16 reduction: 256 blocks = 16 graphs x 16 slices.
__global__ __launch_bounds__(256) void pool_b_partial(
    const float* __restrict__ zbb, const int* __restrict__ bpool,
    float* __restrict__ part, int* __restrict__ pcnt) {
    int b = blockIdx.x;          // 0..255
    int g = b & 15, s = b >> 4;
    int t = threadIdx.x;
    int i0 = s * SLICE;
    int n = min(N1c - i0, SLICE);
    __shared__ int bp[SLICE];
    for (int i = t; i < n; i += 256) bp[i] = bpool[i0 + i];
    __syncthreads();
    float acc = 0.f;
    int c = 0;
    for (int i = 0; i < n; ++i) {
        int hit = (bp[i] == g);
        float sel = hit ? 1.f : 0.f;
        acc += sel * zbb[(size_t)(i0 + i) * 256 + t];   // load NOT branch-gated
        c += hit;
    }
    part[(size_t)b * 256 + t] = acc;
    if (t == 0) pcnt[b] = c;
}

// ---------------- heads ----------------

__global__ void head0(const float* __restrict__ xp, const float* __restrict__ linW,
                      const float* __restrict__ linb, const float* __restrict__ xpool1,
                      float* __restrict__ outp, float* __restrict__ xb) {
    int r = blockIdx.x, t = threadIdx.x;  // 64 threads
    __shared__ float xr[256];
    __shared__ float lg[16];
    __shared__ float ex[16];
#pragma unroll
    for (int j = 0; j < 4; ++j) xr[t + 64 * j] = xp[(size_t)r * 256 + t + 64 * j];
    __syncthreads();
    if (t < 16) {
        float acc = linb[t];
        for (int k = 0; k < 256; ++k) acc += xr[k] * linW[k * 16 + t];
        lg[t] = acc;
    }
    __syncthreads();
    if (t < 16) {
        float mx = lg[0];
#pragma unroll
        for (int c = 1; c < 16; ++c) mx = fmaxf(mx, lg[c]);
        ex[t] = expf(lg[t] - mx);
    }
    __syncthreads();
    if (t < 16) {
        float sum = 0.f;
#pragma unroll
        for (int c = 0; c < 16; ++c) sum += ex[c];
        float pv = ex[t] / sum;
        outp[(size_t)r * 16 + t] = pv;
        xb[(size_t)r * 17 + t] = pv;
    }
    if (t == 16) xb[(size_t)r * 17 + 16] = xpool1[r];
}

// head1: sum 16 partials -> mean -> layer2 GEMM+BN -> logits -> softmax
__global__ void head1(const float* __restrict__ part, const int* __restrict__ pcnt,
                      const float* __restrict__ W, const float* __restrict__ bias,
                      const float* __restrict__ gam, const float* __restrict__ bet,
                      const float* __restrict__ mu, const float* __restrict__ var,
                      const float* __restrict__ linW, const float* __restrict__ linb,
                      float* __restrict__ outp) {
    int b = blockIdx.x, t = threadIdx.x;  // 16 blocks x 256 threads
    __shared__ float pr[256];
    __shared__ float yr[256];
    __shared__ float lg[16];
    __shared__ float ex[16];
    float acc0 = 0.f;
    int c = 0;
#pragma unroll
    for (int s = 0; s < 16; ++s) {
        int pb = s * 16 + b;
        acc0 += part[(size_t)pb * 256 + t];
        c += pcnt[pb];
    }
    float inv = 1.0f / (float)max(c, 1);
    pr[t] = acc0 * inv;
    __syncthreads();
    float acc = bias[t];
    for (int k = 0; k < 256; ++k) acc += pr[k] * W[k * 256 + t];
    float s = gam[t] * rsqrtf(var[t] + EPSc);
    acc = (acc - mu[t]) * s + bet[t];
    if (c == 0) acc = 0.f;
    yr[t] = acc;
    __syncthreads();
    if (t < 16) {
        float l = linb[t];
        for (int k = 0; k < 256; ++k) l += yr[k] * linW[k * 16 + t];
        lg[t] = l;
    }
    __syncthreads();
    if (t < 16) {
        float mx = lg[0];
#pragma unroll
        for (int cc = 1; cc < 16; ++cc) mx = fmaxf(mx, lg[cc]);
        ex[t] = expf(lg[t] - mx);
    }
    __syncthreads();
    if (t < 16) {
        float sum = 0.f;
#pragma unroll
        for (int cc = 0; cc < 16; ++cc) sum += ex[cc];
        outp[48000 + b * 16 + t] = ex[t] / sum;
    }
}

// ---------------- launch ----------------

extern "C" void kernel_launch(void* const* d_in, const int* in_sizes, int n_in,
                              void* d_out, int out_size, void* d_ws, size_t ws_size,
                              hipStream_t stream) {
    const float* x       = (const float*)d_in[0];
    const float* x_pool1 = (const float*)d_in[1];
    const float* W_in0   = (const float*)d_in[2];
    const float* W_h0    = (const float*)d_in[3];
    const float* b0      = (const float*)d_in[4];
    const float* g0      = (const float*)d_in[5];
    const float* be0     = (const float*)d_in[6];
    const float* m0      = (const float*)d_in[7];
    const float* v0      = (const float*)d_in[8];
    const float* W_in1   = (const float*)d_in[9];
    const float* W_h1    = (const float*)d_in[10];
    const float* b1      = (const float*)d_in[11];
    const float* g1      = (const float*)d_in[12];
    const float* be1     = (const float*)d_in[13];
    const float* m1      = (const float*)d_in[14];
    const float* v1      = (const float*)d_in[15];
    const float* linW0   = (const float*)d_in[16];
    const float* linb0   = (const float*)d_in[17];
    const float* linW1   = (const float*)d_in[18];
    const float* linb1   = (const float*)d_in[19];
    const int*   ei      = (const int*)d_in[20];
    const int*   batch   = (const int*)d_in[21];
    const int*   pool1   = (const int*)d_in[22];
    const int*   eip     = (const int*)d_in[23];
    float* outp = (float*)d_out;

    // carve workspace (256B-aligned); NO memset needed (every buffer fully written)
    char* p = (char*)d_ws;
    auto carve = [&](size_t bytes) -> void* {
        void* r = (void*)p;
        p += (bytes + 255) & ~(size_t)255;
        return r;
    };
    int* blockhist = (int*)carve((size_t)NBKT * NSCB * 4);
    int* hx        = (int*)carve((size_t)NBKT * NSCB * 4);
    int* bktSum    = (int*)carve((size_t)NBKT * 4);
    int* bktOff    = (int*)carve((size_t)(NBKT + 1) * 4);
    unsigned* ebkt = (unsigned*)carve((size_t)EALL * 4);

    int*   rp     = (int*)  carve((size_t)(NALL + 1) * 4);
    int*   rpf    = (int*)  carve((size_t)(NALL + 1) * 4);
    float* dinv   = (float*)carve((size_t)NALL * 4);
    int*   blkSum = (int*)  carve(256 * 4);
    int*   blkOff = (int*)  carve(256 * 4);
    unsigned* csw = (unsigned*)carve((size_t)EALL * 4 + 4096);  // +4KB overrun pad
    // region1: [xbf | z0bf] aliased later by g1bf (15.36 MB total)
    unsigned short* xbf  = (unsigned short*)carve((size_t)N0c * 256 * 2);
    unsigned short* z0bf = xbf + (size_t)N0c * 128;
    unsigned short* g1bf = xbf;                         // alias (xbf,z0bf dead)
    // region2: [g0bf | z1bf] (30.72 MB total)
    unsigned short* g0bf = (unsigned short*)carve((size_t)N0c * 256 * 4);
    unsigned short* z1bf = g0bf + (size_t)N0c * 256;

    unsigned short* Wt0 = (unsigned short*)carve((size_t)256 * 128 * 2);
    unsigned short* Wt1 = (unsigned short*)carve((size_t)256 * 256 * 2);
    float* sc0 = (float*)carve(256 * 4);
    float* sh0 = (float*)carve(256 * 4);
    float* sc1 = (float*)carve(256 * 4);
    float* sh1 = (float*)carve(256 * 4);

    int*   start0 = (int*)  carve((size_t)(N1c + 1) * 4);
    int*   cnt0   = (int*)  carve((size_t)N1c * 4);
    float* pmean  = (float*)carve((size_t)N1c * 256 * 4);
    float* xp     = (float*)carve((size_t)N1c * 256 * 4);
    float* xb     = (float*)carve((size_t)N1c * 17 * 4);
    int*   bpool  = (int*)  carve((size_t)N1c * 4);
    unsigned short* hbbbf = (unsigned short*)carve((size_t)N1c * 256 * 2);
    float* zbb    = (float*)carve((size_t)N1c * 256 * 4);
    float* part   = (float*)carve((size_t)256 * 256 * 4);
    int*   pcnt   = (int*)  carve((size_t)256 * 4);

    const int* src0 = ei;
    const int* dst0 = ei + E0c;
    const int* src1 = eip;
    const int* dst1 = eip + E1c;

    // ---- CSR build: bucket sort, zero global atomics ----
    prep1<<<P1_CNT + P1_CVT + P1_PW + P1_SEG, 256, 0, stream>>>(
        dst0, dst1, blockhist, x, xbf, W_in0, W_h0, b0, g0, be0, m0, v0,
        Wt0, Wt1, sc0, sh0, sc1, sh1, pool1, start0);
    scanh_block<<<NBKT, 256, 0, stream>>>(blockhist, hx, bktSum);
    scanh_sums<<<1, 256, 0, stream>>>(bktSum, bktOff);
    scatter_e<<<NSCB, 256, 0, stream>>>(src0, dst0, src1, dst1, hx, bktOff, ebkt);
    int nb = cdiv_i(NALL, 256);                         // 129
    count_scan_n<<<nb, 256, 0, stream>>>(ebkt, bktOff, NALL, rp, blkSum, dinv);
    scan_sums<<<1, 256, 0, stream>>>(blkSum, nb, blkOff, rp, NALL);
    fill_csr<<<NBKT + FILL_TAIL + FILL_CLST, 256, 0, stream>>>(
        ebkt, bktOff, rp, blkOff, dinv, csw, rpf, start0, batch, cnt0, bpool);

    const int*   rp1   = rpf + N0c;
    const float* dinv1 = dinv + N0c;

    // ---- phase A: 3 GCN layers on N0 (layers 0/1: bf16 MFMA path) ----
    agg_bf16<16, 2, true><<<2 * cdiv_i(N0c, 8), 256, 0, stream>>>(xbf, rpf, csw, dinv, z0bf, N0c);
    gemm_mfma_bn<128><<<cdiv_i(N0c, 64), 256, 0, stream>>>(z0bf, Wt0, sc0, sh0, g0bf, N0c);
    agg_bf16<32, 4, true><<<4 * cdiv_i(N0c, 8), 256, 0, stream>>>(g0bf, rpf, csw, dinv, z1bf, N0c);
    gemm_mfma_bn<256><<<cdiv_i(N0c, 64), 256, 0, stream>>>(z1bf, Wt1, sc1, sh1, g1bf, N0c);

    // layer 2: FUSED agg+mean-pool straight into 3000 cluster rows (r20/r21)
    agg_pool<4><<<4 * cdiv_i(N1c, 4), 256, 0, stream>>>(g1bf, rpf, csw, dinv,
                                                        start0, pmean, N1c);
    gemm_bn<256, false, true, false><<<dim3(cdiv_i(N1c, 64), 4), 256, 0, stream>>>(
        pmean, W_h0 + Hc * Hc, b0 + 2 * Hc, g0 + 2 * Hc, be0 + 2 * Hc, m0 + 2 * Hc,
        v0 + 2 * Hc, cnt0, xp, N1c);

    // head0: logits + softmax -> d_out[0:48000], xb = [x0 | x_pool1]
    head0<<<N1c, 64, 0, stream>>>(xp, linW0, linb0, x_pool1, outp, xb);

    // ---- phase B: 3 GCN layers on N1 (fp32 vector GEMMs) ----
    agg17_gemm_bn<<<N1c, 256, 0, stream>>>(xb, rp1, csw, dinv1, W_in1, b1, g1, be1,
                                           m1, v1, hbbbf);
    agg_bf16<32, 4, false><<<4 * cdiv_i(N1c, 8), 256, 0, stream>>>(hbbbf, rp1, csw, dinv1, zbb, N1c);
    gemm_bn<256, true, false, true><<<dim3(cdiv_i(N1c, 64), 4), 256, 0, stream>>>(
        zbb, W_h1, b1 + Hc, g1 + Hc, be1 + Hc, m1 + Hc, v1 + Hc, nullptr, hbbbf, N1c);
    agg_bf16<32, 4, false><<<4 * cdiv_i(N1c, 8), 256, 0, stream>>>(hbbbf, rp1, csw, dinv1, zbb, N1c);

    // atomic-free 3000->16 reduction: 256-block partials, then head1 combines
    pool_b_partial<<<256, 256, 0, stream>>>(zbb, bpool, part, pcnt);
    head1<<<Bc, 256, 0, stream>>>(part, pcnt, W_h1 + Hc * Hc, b1 + 2 * Hc, g1 + 2 * Hc,
                                  be1 + 2 * Hc, m1 + 2 * Hc, v1 + 2 * Hc, linW1, linb1,
                                  outp);
}

// Round 7
// 385.703 us; speedup vs baseline: 1.0953x; 1.0046x over previous
//
#include <hip/hip_runtime.h>
#include <cstdint>
#include <cstddef>

// Problem constants
#define N0c 30000
#define F0c 128
#define Hc  256
#define Cc  16
#define N1c 3000
#define Bc  16
#define E0c 960000
#define E1c 48000
#define NALL 33000            // N0 + N1 (concatenated graphs)
#define EALL 1008000          // E0 + E1
#define EPSc 1e-5f
#define SLICE 188             // clusters per pool_b_partial slice (16*188 >= 3000)

// r17 bucket-sort CSR build: the 1M global atomicAdds were at a memory-side
// atomic throughput wall (~21/ns, 32MB sector writeback). LDS-histogram bucket
// sort: zero global atomics. bucket = dst>>5 (32 nodes), NBKT=1032.
#define NBKT 1032
#define NSCB 256
#define EPB  3938             // edges per scatter block (256*3938 >= EALL)

static __host__ __device__ inline int cdiv_i(int a, int b) { return (a + b - 1) / b; }

// round-to-nearest-even fp32 -> bf16 (returns the 16 bf16 bits)
static __device__ inline unsigned short bfbits(float f) {
    unsigned u = __float_as_uint(f);
    return (unsigned short)((u + 0x7fffu + ((u >> 16) & 1u)) >> 16);
}

typedef short short8 __attribute__((ext_vector_type(8)));   // 8 bf16 = 4 VGPRs
typedef float floatx4 __attribute__((ext_vector_type(4)));

// ---------------- prep1: bucket count (LDS hist) + indep prep work ------------
#define P1_CNT NSCB
#define P1_CVT 3750
#define P1_PW  386
#define P1_SEG 118

__global__ void prep1(const int* __restrict__ dst0, const int* __restrict__ dst1,
                      int* __restrict__ blockhist,
                      const float* __restrict__ x, unsigned short* __restrict__ xbf,
                      const float* __restrict__ W_in0, const float* __restrict__ W_h0,
                      const float* __restrict__ b0, const float* __restrict__ g0,
                      const float* __restrict__ be0, const float* __restrict__ m0,
                      const float* __restrict__ v0,
                      unsigned short* __restrict__ Wt0, unsigned short* __restrict__ Wt1,
                      float* __restrict__ sc0, float* __restrict__ sh0,
                      float* __restrict__ sc1, float* __restrict__ sh1,
                      const int* __restrict__ pool1, int* __restrict__ start0) {
    __shared__ int hist[NBKT];
    int bx = blockIdx.x, t = threadIdx.x;
    if (bx < P1_CNT) {
        for (int k = t; k < NBKT; k += 256) hist[k] = 0;
        __syncthreads();
        int e0 = bx * EPB, e1 = min(e0 + EPB, EALL);
        for (int e = e0 + t; e < e1; e += 256) {
            int d = (e < E0c) ? dst0[e] : (N0c + dst1[e - E0c]);
            atomicAdd(&hist[d >> 5], 1);
        }
        __syncthreads();
        for (int k = t; k < NBKT; k += 256) blockhist[k * NSCB + bx] = hist[k];
    } else if (bx < P1_CNT + P1_CVT) {
        int i = (bx - P1_CNT) * 256 + t;            // float4 index
        if (i >= N0c * 32) return;
        float4 v = ((const float4*)x)[i];
        ushort4 o;
        o.x = bfbits(v.x); o.y = bfbits(v.y); o.z = bfbits(v.z); o.w = bfbits(v.w);
        ((ushort4*)xbf)[i] = o;
    } else if (bx < P1_CNT + P1_CVT + P1_PW) {
        int pb = bx - P1_CNT - P1_CVT;
        if (pb < 128) {
            int i = pb * 256 + t;
            int k = i >> 8, col = i & 255;
            Wt0[col * 128 + k] = bfbits(W_in0[i]);
        } else if (pb < 384) {
            int i = (pb - 128) * 256 + t;
            int k = i >> 8, col = i & 255;
            Wt1[col * 256 + k] = bfbits(W_h0[i]);
        } else if (pb == 384) {
            float s = g0[t] * rsqrtf(v0[t] + EPSc);
            sc0[t] = s;
            sh0[t] = (b0[t] - m0[t]) * s + be0[t];
        } else {
            int tt = t + 256;
            float s = g0[tt] * rsqrtf(v0[tt] + EPSc);
            sc1[t] = s;
            sh1[t] = (b0[tt] - m0[tt]) * s + be0[tt];
        }
    } else {
        int i = (bx - P1_CNT - P1_CVT - P1_PW) * 256 + t;
        if (i > N0c) return;
        if (i == 0) {
            for (int c = 0; c <= pool1[0]; ++c) start0[c] = 0;
        } else if (i == N0c) {
            for (int c = pool1[N0c - 1] + 1; c <= N1c; ++c) start0[c] = N0c;
        } else {
            int a = pool1[i - 1], b = pool1[i];
            for (int c = a + 1; c <= b; ++c) start0[c] = i;
        }
    }
}

// scanh_block: block b = bucket b; exclusive scan of blockhist[b][0..255]
// -> hx (within-bucket offsets per scatter block) + bktSum[b] (bucket total)
__global__ void scanh_block(const int* __restrict__ blockhist, int* __restrict__ hx,
                            int* __restrict__ bktSum) {
    __shared__ int sh[256];
    int b = blockIdx.x, t = threadIdx.x;
    int v = blockhist[b * NSCB + t];
    sh[t] = v; __syncthreads();
    for (int off = 1; off < 256; off <<= 1) {
        int add = (t >= off) ? sh[t - off] : 0;
        __syncthreads();
        sh[t] += add;
        __syncthreads();
    }
    hx[b * NSCB + t] = sh[t] - v;
    if (t == 255) bktSum[b] = sh[255];
}

// scanh_sums: single block, carry-loop exclusive scan of NBKT bucket totals
__global__ void scanh_sums(const int* __restrict__ bktSum, int* __restrict__ bktOff) {
    __shared__ int sh[256];
    int t = threadIdx.x;
    int carry = 0;
    for (int k = 0; k < (NBKT + 255) / 256; ++k) {
        int i = k * 256 + t;
        int v = (i < NBKT) ? bktSum[i] : 0;
        sh[t] = v; __syncthreads();
        for (int off = 1; off < 256; off <<= 1) {
            int add = (t >= off) ? sh[t - off] : 0;
            __syncthreads();
            sh[t] += add;
            __syncthreads();
        }
        if (i < NBKT) bktOff[i] = carry + sh[t] - v;
        carry += sh[255];
        __syncthreads();
    }
    if (t == 0) bktOff[NBKT] = carry;   // == EALL
}

// scatter_e: re-read edges, place into bucket-grouped order via LDS base bump.
// pk = (dst_global << 16) | src_local  (both < 65536)
__global__ __launch_bounds__(256) void scatter_e(
    const int* __restrict__ src0, const int* __restrict__ dst0,
    const int* __restrict__ src1, const int* __restrict__ dst1,
    const int* __restrict__ hx, const int* __restrict__ bktOff,
    unsigned* __restrict__ ebkt) {
    __shared__ int base[NBKT];
    int blk = blockIdx.x, t = threadIdx.x;
    for (int k = t; k < NBKT; k += 256) base[k] = bktOff[k] + hx[k * NSCB + blk];
    __syncthreads();
    int e0 = blk * EPB, e1 = min(e0 + EPB, EALL);
    for (int e = e0 + t; e < e1; e += 256) {
        int s, d;
        if (e < E0c) { s = src0[e]; d = dst0[e]; }
        else         { s = src1[e - E0c]; d = N0c + dst1[e - E0c]; }
        int bkt = d >> 5;
        int pos = atomicAdd(&base[bkt], 1);
        ebkt[pos] = ((unsigned)d << 16) | (unsigned)s;
    }
}

// count_scan_n: block b owns nodes [b*256, b*256+256) = buckets [8b, 8b+8).
// Degree count from bucketed edges (LDS hist, block-owned nodes -> no global
// atomics), dinv = rsqrt(deg+1), block-level exclusive scan of degrees.
__global__ void count_scan_n(const unsigned* __restrict__ ebkt,
                             const int* __restrict__ bktOff, int n,
                             int* __restrict__ rp, int* __restrict__ blkSum,
                             float* __restrict__ dinv) {
    __shared__ int hist[256];
    __shared__ int sh[256];
    int b = blockIdx.x, t = threadIdx.x;
    hist[t] = 0; __syncthreads();
    int lo = bktOff[b * 8];
    int hi = bktOff[b * 8 + 8];
    for (int e = lo + t; e < hi; e += 256) {
        int d = (int)(ebkt[e] >> 16);
        atomicAdd(&hist[d - b * 256], 1);
    }
    __syncthreads();
    int i = b * 256 + t;
    int v = hist[t];
    if (i < n) dinv[i] = rsqrtf((float)(v + 1));
    sh[t] = v; __syncthreads();
    for (int off = 1; off < 256; off <<= 1) {
        int add = (t >= off) ? sh[t - off] : 0;
        __syncthreads();
        sh[t] += add;
        __syncthreads();
    }
    if (i < n) rp[i] = sh[t] - v;
    if (t == 255) blkSum[b] = sh[255];
}

__global__ void scan_sums(const int* __restrict__ blkSum, int nb, int* __restrict__ blkOff,
                          int* __restrict__ rp, int n) {
    __shared__ int sh[256];
    int t = threadIdx.x;
    int v = (t < nb) ? blkSum[t] : 0;
    sh[t] = v; __syncthreads();
    for (int off = 1; off < 256; off <<= 1) {
        int add = (t >= off) ? sh[t - off] : 0;
        __syncthreads();
        sh[t] += add;
        __syncthreads();
    }
    blkOff[t] = sh[t] - v;
    if (t == 255) rp[n] = sh[255];
}

// fill_csr: one block per bucket; LDS rank counters over the bucket's 32
// nodes place each edge at its final CSR slot. Tail blocks build rpf.
// r20: extra CLST blocks compute per-cluster cnt0 + bpool.
#define FILL_TAIL 129
#define FILL_CLST 12
__global__ __launch_bounds__(256) void fill_csr(
    const unsigned* __restrict__ ebkt, const int* __restrict__ bktOff,
    const int* __restrict__ rp, const int* __restrict__ blkOff,
    const float* __restrict__ dinv, unsigned* __restrict__ csw,
    int* __restrict__ rpf, const int* __restrict__ start0,
    const int* __restrict__ batch, int* __restrict__ cnt0,
    int* __restrict__ bpool) {
    int bx = blockIdx.x, t = threadIdx.x;
    if (bx < NBKT) {
        __shared__ int lrp[32];
        __shared__ float ldv[32];
        __shared__ int cnt[32];
        if (t < 32) {
            int node = bx * 32 + t;
            cnt[t] = 0;
            if (node < NALL) {
                lrp[t] = rp[node] + blkOff[node >> 8];
                ldv[t] = dinv[node];
            } else { lrp[t] = 0; ldv[t] = 0.f; }
        }
        __syncthreads();
        int lo = bktOff[bx], hi = bktOff[bx + 1];
        for (int e = lo + t; e < hi; e += 256) {
            unsigned pk = ebkt[e];
            int d = (int)(pk >> 16);
            int sloc = (int)(pk & 0xffffu);
            int dl = d & 31;
            int lr = atomicAdd(&cnt[dl], 1);
            int sg = (d >= N0c) ? (N0c + sloc) : sloc;
            float w = dinv[sg] * ldv[dl];
            csw[lrp[dl] + lr] = ((unsigned)bfbits(w) << 16) | (unsigned)sloc;
        }
    } else if (bx < NBKT + FILL_TAIL) {
        int i = (bx - NBKT) * 256 + t;
        if (i < NALL) rpf[i] = rp[i] + blkOff[i >> 8];
        else if (i == NALL) rpf[NALL] = rp[NALL];
    } else {
        int c = (bx - NBKT - FILL_TAIL) * 256 + t;
        if (c < N1c) {
            int s = start0[c], e = start0[c + 1];
            int cnt = e - s;
            cnt0[c] = cnt;
            int sb = 0;
            for (int i = s; i < e; ++i) sb += batch[i];
            bpool[c] = (int)rintf((float)sb / (float)max(cnt, 1));
        }
    }
}

// ---------------- aggregation (bf16 gather, fp32 accumulate) ----------------

static __device__ inline void acc8(float a[8], float w, uint4 v) {
    a[0] += w * __uint_as_float(v.x << 16);
    a[1] += w * __uint_as_float(v.x & 0xffff0000u);
    a[2] += w * __uint_as_float(v.y << 16);
    a[3] += w * __uint_as_float(v.y & 0xffff0000u);
    a[4] += w * __uint_as_float(v.z << 16);
    a[5] += w * __uint_as_float(v.z & 0xffff0000u);
    a[6] += w * __uint_as_float(v.w << 16);
    a[7] += w * __uint_as_float(v.w & 0xffff0000u);
}

// r22: paired-edge accumulate via v_dot2_f32_bf16 (VOP3P, CDNA3+):
// a[c] += wA*va[c] + wB*vb[c] in ONE instruction per column, operands built
// with v_perm_b32. Halves the acc VALU cost vs 2x acc8 (16 vs 32 ops per
// edge-pair per 8 cols). wp = (wA lo16 | wB hi16); zero-padded edges have
// bf16 weight +0.0 and row index 0 (finite data) -> exact no-op, as before.
static __device__ inline void accd(float a[8], unsigned wp, uint4 va, uint4 vb) {
#define DOT2P(k, A, B) { \
    unsigned plo = __builtin_amdgcn_perm(B, A, 0x05040100u); /* (A.lo,B.lo) */ \
    unsigned phi = __builtin_amdgcn_perm(B, A, 0x07060302u); /* (A.hi,B.hi) */ \
    asm("v_dot2_f32_bf16 %0, %1, %2, %0" : "+v"(a[k])     : "v"(plo), "v"(wp)); \
    asm("v_dot2_f32_bf16 %0, %1, %2, %0" : "+v"(a[k + 1]) : "v"(phi), "v"(wp)); }
    DOT2P(0, va.x, vb.x)
    DOT2P(2, va.y, vb.y)
    DOT2P(4, va.z, vb.z)
    DOT2P(6, va.w, vb.w)
#undef DOT2P
}

// TWO nodes per wave, FOUR edge slots each (lane = ns*32 + par*8 + cl).
// NCHUNK chunks of 64 cols; chunk = blockIdx&(NCHUNK-1) keeps XCD pinning.
// r19: per-lane direct csw loads (8 same-address lanes merge in L1), 4-deep
// gather pipeline. r22: paired v_dot2_f32_bf16 accumulate (VALU-issue-bound
// per r21 counters: VALUBusy 70%, HBM 17%).
template <int RSU, int NCHUNK, bool OBF16>
__global__ __launch_bounds__(256) void agg_bf16(
    const unsigned short* __restrict__ x, const int* __restrict__ rp,
    const unsigned* __restrict__ csw, const float* __restrict__ dinv,
    void* __restrict__ zv, int N) {
    constexpr int SHIFT = (RSU == 32) ? 9 : 8;   // log2(row bytes)
    int b = blockIdx.x;
    int chunk = b & (NCHUNK - 1);
    int wave = threadIdx.x >> 6;
    int lane = threadIdx.x & 63;
    int ns = lane >> 5;                  // node sub (0/1)
    int par = (lane >> 3) & 3;           // edge slot (0..3)
    int cl = lane & 7;                   // 16B slice within 64-col chunk
    int node = (b / NCHUNK) * 8 + wave * 2 + ns;
    bool valid = node < N;
    int nclamp = valid ? node : 0;
    int c4 = chunk * 8 + cl;
    unsigned coff = (unsigned)c4 << 4;
    const char* xb = (const char*)x;
    float a[8] = {0.f, 0.f, 0.f, 0.f, 0.f, 0.f, 0.f, 0.f};
    int e0 = rp[nclamp];
    int e1 = valid ? rp[nclamp + 1] : e0;
    if (valid && par == 0) {             // self-loop term exactly once
        float di = dinv[node];
        uint4 v = *(const uint4*)(xb + (((unsigned)node << SHIFT) + coff));
        acc8(a, di * di, v);
    }
    int deg = e1 - e0;
    int mysteps = (deg + 3) >> 2;
    int steps = max(__shfl(mysteps, 0, 64), __shfl(mysteps, 32, 64));  // uniform
    int e = e0 + par;                    // this lane's first edge slot
    // direct loads (no clamp: csw padded; garbage is dead via the e<e1 select)
    unsigned cw0 = csw[e];      cw0 = (e      < e1) ? cw0 : 0u;
    unsigned cw1 = csw[e + 4];  cw1 = (e + 4  < e1) ? cw1 : 0u;
    unsigned cw2 = csw[e + 8];  cw2 = (e + 8  < e1) ? cw2 : 0u;
    unsigned cw3 = csw[e + 12]; cw3 = (e + 12 < e1) ? cw3 : 0u;
    int i = 0;
    for (; i + 3 < steps; i += 4) {
        // 4 gathers in flight (addresses depend only on already-loaded cw*)
        uint4 v0 = *(const uint4*)(xb + (((cw0 & 0xffffu) << SHIFT) + coff));
        uint4 v1 = *(const uint4*)(xb + (((cw1 & 0xffffu) << SHIFT) + coff));
        uint4 v2 = *(const uint4*)(xb + (((cw2 & 0xffffu) << SHIFT) + coff));
        uint4 v3 = *(const uint4*)(xb + (((cw3 & 0xffffu) << SHIFT) + coff));
        // prefetch next group's edge words under the gathers
        int en = e + 16;
        unsigned nw0 = csw[en];      nw0 = (en      < e1) ? nw0 : 0u;
        unsigned nw1 = csw[en + 4];  nw1 = (en + 4  < e1) ? nw1 : 0u;
        unsigned nw2 = csw[en + 8];  nw2 = (en + 8  < e1) ? nw2 : 0u;
        unsigned nw3 = csw[en + 12]; nw3 = (en + 12 < e1) ? nw3 : 0u;
        unsigned wp01 = __builtin_amdgcn_perm(cw1, cw0, 0x07060302u);
        unsigned wp23 = __builtin_amdgcn_perm(cw3, cw2, 0x07060302u);
        accd(a, wp01, v0, v1);
        accd(a, wp23, v2, v3);
        cw0 = nw0; cw1 = nw1; cw2 = nw2; cw3 = nw3;
        e = en;
    }
    // tail (steps is wave-uniform -> uniform branches; cw* already loaded)
    if (i + 1 < steps) {                 // >= 2 left: pair (cw0, cw1)
        uint4 v0 = *(const uint4*)(xb + (((cw0 & 0xffffu) << SHIFT) + coff));
        uint4 v1 = *(const uint4*)(xb + (((cw1 & 0xffffu) << SHIFT) + coff));
        unsigned wp01 = __builtin_amdgcn_perm(cw1, cw0, 0x07060302u);
        accd(a, wp01, v0, v1);
        if (i + 2 < steps) {             // third
            uint4 v2 = *(const uint4*)(xb + (((cw2 & 0xffffu) << SHIFT) + coff));
            acc8(a, __uint_as_float(cw2 & 0xffff0000u), v2);
        }
    } else if (i < steps) {              // exactly one
        uint4 v0 = *(const uint4*)(xb + (((cw0 & 0xffffu) << SHIFT) + coff));
        acc8(a, __uint_as_float(cw0 & 0xffff0000u), v0);
    }
    // reduce across the 4 edge slots (2 levels, stays within each node half)
#pragma unroll
    for (int m = 8; m < 32; m <<= 1) {
#pragma unroll
        for (int k = 0; k < 8; ++k) a[k] += __shfl_xor(a[k], m, 64);
    }
    if (valid && par == 0) {
        if (OBF16) {
            uint4 o;
            o.x = (unsigned)bfbits(a[0]) | ((unsigned)bfbits(a[1]) << 16);
            o.y = (unsigned)bfbits(a[2]) | ((unsigned)bfbits(a[3]) << 16);
            o.z = (unsigned)bfbits(a[4]) | ((unsigned)bfbits(a[5]) << 16);
            o.w = (unsigned)bfbits(a[6]) | ((unsigned)bfbits(a[7]) << 16);
            ((uint4*)zv)[(size_t)node * RSU + c4] = o;
        } else {
            float4* zp = (float4*)zv + (size_t)node * (RSU * 2) + c4 * 2;
            zp[0] = make_float4(a[0], a[1], a[2], a[3]);
            zp[1] = make_float4(a[4], a[5], a[6], a[7]);
        }
    }
}

// r20/r21/r22: fused layer-2 aggregation + mean-pool. pool1 is SORTED ->
// cluster c owns the contiguous node range [start0[c], start0[c+1]) AND the
// contiguous edge slice csw[rpf[start0[c]] .. rpf[start0[c+1]]). ONE cluster
// per wave, EIGHT edge slots; r22: paired dot2 accumulate.
template <int NCHUNK>
__global__ __launch_bounds__(256) void agg_pool(
    const unsigned short* __restrict__ x, const int* __restrict__ rpf,
    const unsigned* __restrict__ csw, const float* __restrict__ dinv,
    const int* __restrict__ start0, float* __restrict__ out, int N) {
    constexpr int SHIFT = 9;             // 256-col bf16 rows = 512 B
    int b = blockIdx.x;
    int chunk = b & (NCHUNK - 1);
    int wave = threadIdx.x >> 6;
    int lane = threadIdx.x & 63;
    int par = lane >> 3;                 // edge slot (0..7)
    int cl = lane & 7;                   // 16B slice within 64-col chunk
    int c = (b / NCHUNK) * 4 + wave;
    bool valid = c < N;
    int cc = valid ? c : 0;
    int c4 = chunk * 8 + cl;
    unsigned coff = (unsigned)c4 << 4;
    const char* xb = (const char*)x;
    float a[8] = {0.f, 0.f, 0.f, 0.f, 0.f, 0.f, 0.f, 0.f};
    int s0 = start0[cc];
    int s1 = valid ? start0[cc + 1] : s0;
    int e0 = rpf[s0];
    int e1 = valid ? rpf[s1] : e0;
    // self-loop terms for member nodes, par-strided (members are contiguous)
    for (int m = s0 + par; m < s1; m += 8) {
        float di = dinv[m];
        uint4 v = *(const uint4*)(xb + (((unsigned)m << SHIFT) + coff));
        acc8(a, di * di, v);
    }
    int deg = e1 - e0;
    int steps = (deg + 7) >> 3;          // wave-uniform (one cluster per wave)
    int e = e0 + par;
    unsigned cw0 = csw[e];      cw0 = (e      < e1) ? cw0 : 0u;
    unsigned cw1 = csw[e + 8];  cw1 = (e + 8  < e1) ? cw1 : 0u;
    unsigned cw2 = csw[e + 16]; cw2 = (e + 16 < e1) ? cw2 : 0u;
    unsigned cw3 = csw[e + 24]; cw3 = (e + 24 < e1) ? cw3 : 0u;
    int i = 0;
    for (; i + 3 < steps; i += 4) {
        uint4 v0 = *(const uint4*)(xb + (((cw0 & 0xffffu) << SHIFT) + coff));
        uint4 v1 = *(const uint4*)(xb + (((cw1 & 0xffffu) << SHIFT) + coff));
        uint4 v2 = *(const uint4*)(xb + (((cw2 & 0xffffu) << SHIFT) + coff));
        uint4 v3 = *(const uint4*)(xb + (((cw3 & 0xffffu) << SHIFT) + coff));
        int en = e + 32;
        unsigned nw0 = csw[en];      nw0 = (en      < e1) ? nw0 : 0u;
        unsigned nw1 = csw[en + 8];  nw1 = (en + 8  < e1) ? nw1 : 0u;
        unsigned nw2 = csw[en + 16]; nw2 = (en + 16 < e1) ? nw2 : 0u;
        unsigned nw3 = csw[en + 24]; nw3 = (en + 24 < e1) ? nw3 : 0u;
        unsigned wp01 = __builtin_amdgcn_perm(cw1, cw0, 0x07060302u);
        unsigned wp23 = __builtin_amdgcn_perm(cw3, cw2, 0x07060302u);
        accd(a, wp01, v0, v1);
        accd(a, wp23, v2, v3);
        cw0 = nw0; cw1 = nw1; cw2 = nw2; cw3 = nw3;
        e = en;
    }
    if (i + 1 < steps) {                 // >= 2 left: pair (cw0, cw1)
        uint4 v0 = *(const uint4*)(xb + (((cw0 & 0xffffu) << SHIFT) + coff));
        uint4 v1 = *(const uint4*)(xb + (((cw1 & 0xffffu) << SHIFT) + coff));
        unsigned wp01 = __builtin_amdgcn_perm(cw1, cw0, 0x07060302u);
        accd(a, wp01, v0, v1);
        if (i + 2 < steps) {
            uint4 v2 = *(const uint4*)(xb + (((cw2 & 0xffffu) << SHIFT) + coff));
            acc8(a, __uint_as_float(cw2 & 0xffff0000u), v2);
        }
    } else if (i < steps) {
        uint4 v0 = *(const uint4*)(xb + (((cw0 & 0xffffu) << SHIFT) + coff));
        acc8(a, __uint_as_float(cw0 & 0xffff0000u), v0);
    }
    // reduce across the 8 edge slots (3 levels, full wave)
#pragma unroll
    for (int m = 8; m < 64; m <<= 1) {
#pragma unroll
        for (int k = 0; k < 8; ++k) a[k] += __shfl_xor(a[k], m, 64);
    }
    if (valid && par == 0) {
        float inv = 1.0f / (float)max(s1 - s0, 1);
        float4* zp = (float4*)out + (size_t)c * 64 + c4 * 2;
        zp[0] = make_float4(a[0] * inv, a[1] * inv, a[2] * inv, a[3] * inv);
        zp[1] = make_float4(a[4] * inv, a[5] * inv, a[6] * inv, a[7] * inv);
    }
}

// ---------------- MFMA bf16 GEMM: (M x K)bf16 @ Wt(256 x K)bf16 -> bf16 out ----

template <int K>
__global__ __launch_bounds__(256) void gemm_mfma_bn(
    const unsigned short* __restrict__ A, const unsigned short* __restrict__ Wt,
    const float* __restrict__ sc, const float* __restrict__ sh,
    unsigned short* __restrict__ out, int M) {
    constexpr int LDS_S = 40;
    __shared__ unsigned short As[64 * LDS_S];
    __shared__ unsigned short Bs[256 * LDS_S];
    int tid = threadIdx.x;
    int w = tid >> 6, l = tid & 63;
    int quad = l >> 4, lm = l & 15;
    int row0 = blockIdx.x * 64;
    floatx4 acc[4][4];
#pragma unroll
    for (int i = 0; i < 4; ++i)
#pragma unroll
        for (int j = 0; j < 4; ++j) acc[i][j] = (floatx4){0.f, 0.f, 0.f, 0.f};

    int ar = tid >> 2;          // A staging: row 0..63
    int ac = (tid & 3) * 8;     // short offset 0,8,16,24

    for (int k0 = 0; k0 < K; k0 += 32) {
        uint4 av = make_uint4(0, 0, 0, 0);
        if (row0 + ar < M) av = *(const uint4*)(A + (size_t)(row0 + ar) * K + k0 + ac);
        *(uint4*)&As[ar * LDS_S + ac] = av;
#pragma unroll
        for (int c = 0; c < 4; ++c) {    // Bs: thread -> col tid, 4 k-chunks
            uint4 bv = *(const uint4*)(Wt + (size_t)tid * K + k0 + c * 8);
            *(uint4*)&Bs[tid * LDS_S + c * 8] = bv;
        }
        __syncthreads();
        short8 af[4], bf[4];
#pragma unroll
        for (int i = 0; i < 4; ++i)
            af[i] = *(const short8*)&As[(i * 16 + lm) * LDS_S + quad * 8];
#pragma unroll
        for (int j = 0; j < 4; ++j)
            bf[j] = *(const short8*)&Bs[(w * 64 + j * 16 + lm) * LDS_S + quad * 8];
#pragma unroll
        for (int i = 0; i < 4; ++i)
#pragma unroll
            for (int j = 0; j < 4; ++j)
                acc[i][j] = __builtin_amdgcn_mfma_f32_16x16x32_bf16(af[i], bf[j], acc[i][j], 0, 0, 0);
        __syncthreads();
    }
    // epilogue: C/D map col=lane&15, row=quad*4+reg [verified m89/m91]
#pragma unroll
    for (int j = 0; j < 4; ++j) {
        int col = w * 64 + j * 16 + lm;
        float s = sc[col], h = sh[col];
#pragma unroll
        for (int i = 0; i < 4; ++i) {
            int rb = row0 + i * 16 + quad * 4;
#pragma unroll
            for (int r = 0; r < 4; ++r) {
                int row = rb + r;
                if (row < M) {
                    float v = acc[i][j][r] * s + h;
                    v = fmaxf(v, 0.f);
                    out[(size_t)row * 256 + col] = bfbits(v);
                }
            }
        }
    }
}

// ---------------- fp32 vector GEMM (kept for small M=3000, precision-critical) --

template <int K, bool RELU, bool ZEROEMPTY, bool OBF16>
__global__ __launch_bounds__(256) void gemm_bn(
    const float* __restrict__ A, const float* __restrict__ W,
    const float* __restrict__ bias, const float* __restrict__ gam,
    const float* __restrict__ bet, const float* __restrict__ mu,
    const float* __restrict__ var, const int* __restrict__ cnt,
    void* __restrict__ outv, int M) {
    __shared__ __align__(16) float As[16][64];
    __shared__ __align__(16) float Bs[16][64];
    int tid = threadIdx.x;
    int tm = tid >> 4, tn = tid & 15;
    int row0 = blockIdx.x * 64, col0 = blockIdx.y * 64;
    float acc[4][4] = {};
    int ar = tid >> 2;
    int ak = (tid & 3) * 4;
    int bk = tid >> 4;
    int bn = (tid & 15) * 4;

    for (int kk = 0; kk < K; kk += 16) {
        float4 av = make_float4(0.f, 0.f, 0.f, 0.f);
        int grow = row0 + ar;
        if (grow < M) av = *(const float4*)(A + (size_t)grow * K + kk + ak);
        As[ak + 0][ar] = av.x;
        As[ak + 1][ar] = av.y;
        As[ak + 2][ar] = av.z;
        As[ak + 3][ar] = av.w;
        float4 bv = *(const float4*)(W + (size_t)(kk + bk) * 256 + col0 + bn);
        *(float4*)&Bs[bk][bn] = bv;
        __syncthreads();
#pragma unroll
        for (int k = 0; k < 16; ++k) {
            float4 a = *(const float4*)&As[k][tm * 4];
            float4 b = *(const float4*)&Bs[k][tn * 4];
            acc[0][0] += a.x * b.x; acc[0][1] += a.x * b.y; acc[0][2] += a.x * b.z; acc[0][3] += a.x * b.w;
            acc[1][0] += a.y * b.x; acc[1][1] += a.y * b.y; acc[1][2] += a.y * b.z; acc[1][3] += a.y * b.w;
            acc[2][0] += a.z * b.x; acc[2][1] += a.z * b.y; acc[2][2] += a.z * b.z; acc[2][3] += a.z * b.w;
            acc[3][0] += a.w * b.x; acc[3][1] += a.w * b.y; acc[3][2] += a.w * b.z; acc[3][3] += a.w * b.w;
        }
        __syncthreads();
    }
    float bcol[4], scol[4], mcol[4], ecol[4];
#pragma unroll
    for (int j = 0; j < 4; ++j) {
        int col = col0 + tn * 4 + j;
        bcol[j] = bias[col];
        scol[j] = gam[col] * rsqrtf(var[col] + EPSc);
        mcol[j] = mu[col];
        ecol[j] = bet[col];
    }
#pragma unroll
    for (int i = 0; i < 4; ++i) {
        int row = row0 + tm * 4 + i;
        if (row >= M) continue;
        bool zero = false;
        if (ZEROEMPTY) zero = (cnt[row] == 0);
        float r[4];
#pragma unroll
        for (int j = 0; j < 4; ++j) {
            float v = acc[i][j] + bcol[j];
            v = (v - mcol[j]) * scol[j] + ecol[j];
            if (RELU) v = fmaxf(v, 0.f);
            if (zero) v = 0.f;
            r[j] = v;
        }
        if (OBF16) {
            ushort4 o;
            o.x = bfbits(r[0]); o.y = bfbits(r[1]); o.z = bfbits(r[2]); o.w = bfbits(r[3]);
            *(ushort4*)((unsigned short*)outv + (size_t)row * 256 + col0 + tn * 4) = o;
        } else {
            float4 o = make_float4(r[0], r[1], r[2], r[3]);
            *(float4*)((float*)outv + (size_t)row * 256 + col0 + tn * 4) = o;
        }
    }
}

// fused: 17-wide aggregation (graph 1) + K=17 GEMM + BN + ReLU, bf16 out
__global__ void agg17_gemm_bn(const float* __restrict__ xb, const int* __restrict__ rp,
                              const unsigned* __restrict__ csw, const float* __restrict__ dinv,
                              const float* __restrict__ W, const float* __restrict__ bias,
                              const float* __restrict__ gam, const float* __restrict__ bet,
                              const float* __restrict__ mu, const float* __restrict__ var,
                              unsigned short* __restrict__ out) {
    int r = blockIdx.x, t = threadIdx.x;   // 256 threads
    __shared__ float zr[17];
    if (t < 17) {
        float di = dinv[r];
        float acc = di * di * xb[(size_t)r * 17 + t];
        int e0 = rp[r], e1 = rp[r + 1];
        for (int e = e0; e < e1; ++e) {
            unsigned ew = csw[e];
            acc += __uint_as_float(ew & 0xffff0000u) * xb[(size_t)(ew & 0xffffu) * 17 + t];
        }
        zr[t] = acc;
    }
    __syncthreads();
    float acc = bias[t];
#pragma unroll
    for (int k = 0; k < 17; ++k) acc += zr[k] * W[k * 256 + t];
    float s = gam[t] * rsqrtf(var[t] + EPSc);
    acc = (acc - mu[t]) * s + bet[t];
    acc = fmaxf(acc, 0.f);
    out[(size_t)r * 256 + t] = bfbits(acc);
}

// ---------------- pooling ----------------

// stage 1 of atomic-free 3000->16 reduction: 256 blocks = 16 graphs x 16 slices.
__global__ __launch_bounds__(256) void pool_b_partial(
    const float* __restrict__ zbb, const int* __restrict__ bpool,
    float* __restrict__ part, int* __restrict__ pcnt) {
    int b = blockIdx.x;          // 0..255
    int g = b & 15, s = b >> 4;
    int t = threadIdx.x;
    int i0 = s * SLICE;
    int n = min(N1c - i0, SLICE);
    __shared__ int bp[SLICE];
    for (int i = t; i < n; i += 256) bp[i] = bpool[i0 + i];
    __syncthreads();
    float acc = 0.f;
    int c = 0;
    for (int i = 0; i < n; ++i) {
        int hit = (bp[i] == g);
        float sel = hit ? 1.f : 0.f;
        acc += sel * zbb[(size_t)(i0 + i) * 256 + t];   // load NOT branch-gated
        c += hit;
    }
    part[(size_t)b * 256 + t] = acc;
    if (t == 0) pcnt[b] = c;
}

// ---------------- heads ----------------

__global__ void head0(const float* __restrict__ xp, const float* __restrict__ linW,
                      const float* __restrict__ linb, const float* __restrict__ xpool1,
                      float* __restrict__ outp, float* __restrict__ xb) {
    int r = blockIdx.x, t = threadIdx.x;  // 64 threads
    __shared__ float xr[256];
    __shared__ float lg[16];
    __shared__ float ex[16];
#pragma unroll
    for (int j = 0; j < 4; ++j) xr[t + 64 * j] = xp[(size_t)r * 256 + t + 64 * j];
    __syncthreads();
    if (t < 16) {
        float acc = linb[t];
        for (int k = 0; k < 256; ++k) acc += xr[k] * linW[k * 16 + t];
        lg[t] = acc;
    }
    __syncthreads();
    if (t < 16) {
        float mx = lg[0];
#pragma unroll
        for (int c = 1; c < 16; ++c) mx = fmaxf(mx, lg[c]);
        ex[t] = expf(lg[t] - mx);
    }
    __syncthreads();
    if (t < 16) {
        float sum = 0.f;
#pragma unroll
        for (int c = 0; c < 16; ++c) sum += ex[c];
        float pv = ex[t] / sum;
        outp[(size_t)r * 16 + t] = pv;
        xb[(size_t)r * 17 + t] = pv;
    }
    if (t == 16) xb[(size_t)r * 17 + 16] = xpool1[r];
}

// head1: sum 16 partials -> mean -> layer2 GEMM+BN -> logits -> softmax
__global__ void head1(const float* __restrict__ part, const int* __restrict__ pcnt,
                      const float* __restrict__ W, const float* __restrict__ bias,
                      const float* __restrict__ gam, const float* __restrict__ bet,
                      const float* __restrict__ mu, const float* __restrict__ var,
                      const float* __restrict__ linW, const float* __restrict__ linb,
                      float* __restrict__ outp) {
    int b = blockIdx.x, t = threadIdx.x;  // 16 blocks x 256 threads
    __shared__ float pr[256];
    __shared__ float yr[256];
    __shared__ float lg[16];
    __shared__ float ex[16];
    float acc0 = 0.f;
    int c = 0;
#pragma unroll
    for (int s = 0; s < 16; ++s) {
        int pb = s * 16 + b;
        acc0 += part[(size_t)pb * 256 + t];
        c += pcnt[pb];
    }
    float inv = 1.0f / (float)max(c, 1);
    pr[t] = acc0 * inv;
    __syncthreads();
    float acc = bias[t];
    for (int k = 0; k < 256; ++k) acc += pr[k] * W[k * 256 + t];
    float s = gam[t] * rsqrtf(var[t] + EPSc);
    acc = (acc - mu[t]) * s + bet[t];
    if (c == 0) acc = 0.f;
    yr[t] = acc;
    __syncthreads();
    if (t < 16) {
        float l = linb[t];
        for (int k = 0; k < 256; ++k) l += yr[k] * linW[k * 16 + t];
        lg[t] = l;
    }
    __syncthreads();
    if (t < 16) {
        float mx = lg[0];
#pragma unroll
        for (int cc = 1; cc < 16; ++cc) mx = fmaxf(mx, lg[cc]);
        ex[t] = expf(lg[t] - mx);
    }
    __syncthreads();
    if (t < 16) {
        float sum = 0.f;
#pragma unroll
        for (int cc = 0; cc < 16; ++cc) sum += ex[cc];
        outp[48000 + b * 16 + t] = ex[t] / sum;
    }
}

// ---------------- launch ----------------

extern "C" void kernel_launch(void* const* d_in, const int* in_sizes, int n_in,
                              void* d_out, int out_size, void* d_ws, size_t ws_size,
                              hipStream_t stream) {
    const float* x       = (const float*)d_in[0];
    const float* x_pool1 = (const float*)d_in[1];
    const float* W_in0   = (const float*)d_in[2];
    const float* W_h0    = (const float*)d_in[3];
    const float* b0      = (const float*)d_in[4];
    const float* g0      = (const float*)d_in[5];
    const float* be0     = (const float*)d_in[6];
    const float* m0      = (const float*)d_in[7];
    const float* v0      = (const float*)d_in[8];
    const float* W_in1   = (const float*)d_in[9];
    const float* W_h1    = (const float*)d_in[10];
    const float* b1      = (const float*)d_in[11];
    const float* g1      = (const float*)d_in[12];
    const float* be1     = (const float*)d_in[13];
    const float* m1      = (const float*)d_in[14];
    const float* v1      = (const float*)d_in[15];
    const float* linW0   = (const float*)d_in[16];
    const float* linb0   = (const float*)d_in[17];
    const float* linW1   = (const float*)d_in[18];
    const float* linb1   = (const float*)d_in[19];
    const int*   ei      = (const int*)d_in[20];
    const int*   batch   = (const int*)d_in[21];
    const int*   pool1   = (const int*)d_in[22];
    const int*   eip     = (const int*)d_in[23];
    float* outp = (float*)d_out;

    // carve workspace (256B-aligned); NO memset needed (every buffer fully written)
    char* p = (char*)d_ws;
    auto carve = [&](size_t bytes) -> void* {
        void* r = (void*)p;
        p += (bytes + 255) & ~(size_t)255;
        return r;
    };
    int* blockhist = (int*)carve((size_t)NBKT * NSCB * 4);
    int* hx        = (int*)carve((size_t)NBKT * NSCB * 4);
    int* bktSum    = (int*)carve((size_t)NBKT * 4);
    int* bktOff    = (int*)carve((size_t)(NBKT + 1) * 4);
    unsigned* ebkt = (unsigned*)carve((size_t)EALL * 4);

    int*   rp     = (int*)  carve((size_t)(NALL + 1) * 4);
    int*   rpf    = (int*)  carve((size_t)(NALL + 1) * 4);
    float* dinv   = (float*)carve((size_t)NALL * 4);
    int*   blkSum = (int*)  carve(256 * 4);
    int*   blkOff = (int*)  carve(256 * 4);
    unsigned* csw = (unsigned*)carve((size_t)EALL * 4 + 4096);  // +4KB overrun pad
    // region1: [xbf | z0bf] aliased later by g1bf (15.36 MB total)
    unsigned short* xbf  = (unsigned short*)carve((size_t)N0c * 256 * 2);
    unsigned short* z0bf = xbf + (size_t)N0c * 128;
    unsigned short* g1bf = xbf;                         // alias (xbf,z0bf dead)
    // region2: [g0bf | z1bf] (30.72 MB total)
    unsigned short* g0bf = (unsigned short*)carve((size_t)N0c * 256 * 4);
    unsigned short* z1bf = g0bf + (size_t)N0c * 256;

    unsigned short* Wt0 = (unsigned short*)carve((size_t)256 * 128 * 2);
    unsigned short* Wt1 = (unsigned short*)carve((size_t)256 * 256 * 2);
    float* sc0 = (float*)carve(256 * 4);
    float* sh0 = (float*)carve(256 * 4);
    float* sc1 = (float*)carve(256 * 4);
    float* sh1 = (float*)carve(256 * 4);

    int*   start0 = (int*)  carve((size_t)(N1c + 1) * 4);
    int*   cnt0   = (int*)  carve((size_t)N1c * 4);
    float* pmean  = (float*)carve((size_t)N1c * 256 * 4);
    float* xp     = (float*)carve((size_t)N1c * 256 * 4);
    float* xb     = (float*)carve((size_t)N1c * 17 * 4);
    int*   bpool  = (int*)  carve((size_t)N1c * 4);
    unsigned short* hbbbf = (unsigned short*)carve((size_t)N1c * 256 * 2);
    float* zbb    = (float*)carve((size_t)N1c * 256 * 4);
    float* part   = (float*)carve((size_t)256 * 256 * 4);
    int*   pcnt   = (int*)  carve((size_t)256 * 4);

    const int* src0 = ei;
    const int* dst0 = ei + E0c;
    const int* src1 = eip;
    const int* dst1 = eip + E1c;

    // ---- CSR build: bucket sort, zero global atomics ----
    prep1<<<P1_CNT + P1_CVT + P1_PW + P1_SEG, 256, 0, stream>>>(
        dst0, dst1, blockhist, x, xbf, W_in0, W_h0, b0, g0, be0, m0, v0,
        Wt0, Wt1, sc0, sh0, sc1, sh1, pool1, start0);
    scanh_block<<<NBKT, 256, 0, stream>>>(blockhist, hx, bktSum);
    scanh_sums<<<1, 256, 0, stream>>>(bktSum, bktOff);
    scatter_e<<<NSCB, 256, 0, stream>>>(src0, dst0, src1, dst1, hx, bktOff, ebkt);
    int nb = cdiv_i(NALL, 256);                         // 129
    count_scan_n<<<nb, 256, 0, stream>>>(ebkt, bktOff, NALL, rp, blkSum, dinv);
    scan_sums<<<1, 256, 0, stream>>>(blkSum, nb, blkOff, rp, NALL);
    fill_csr<<<NBKT + FILL_TAIL + FILL_CLST, 256, 0, stream>>>(
        ebkt, bktOff, rp, blkOff, dinv, csw, rpf, start0, batch, cnt0, bpool);

    const int*   rp1   = rpf + N0c;
    const float* dinv1 = dinv + N0c;

    // ---- phase A: 3 GCN layers on N0 (layers 0/1: bf16 MFMA path) ----
    agg_bf16<16, 2, true><<<2 * cdiv_i(N0c, 8), 256, 0, stream>>>(xbf, rpf, csw, dinv, z0bf, N0c);
    gemm_mfma_bn<128><<<cdiv_i(N0c, 64), 256, 0, stream>>>(z0bf, Wt0, sc0, sh0, g0bf, N0c);
    agg_bf16<32, 4, true><<<4 * cdiv_i(N0c, 8), 256, 0, stream>>>(g0bf, rpf, csw, dinv, z1bf, N0c);
    gemm_mfma_bn<256><<<cdiv_i(N0c, 64), 256, 0, stream>>>(z1bf, Wt1, sc1, sh1, g1bf, N0c);

    // layer 2: FUSED agg+mean-pool straight into 3000 cluster rows (r20/r21)
    agg_pool<4><<<4 * cdiv_i(N1c, 4), 256, 0, stream>>>(g1bf, rpf, csw, dinv,
                                                        start0, pmean, N1c);
    gemm_bn<256, false, true, false><<<dim3(cdiv_i(N1c, 64), 4), 256, 0, stream>>>(
        pmean, W_h0 + Hc * Hc, b0 + 2 * Hc, g0 + 2 * Hc, be0 + 2 * Hc, m0 + 2 * Hc,
        v0 + 2 * Hc, cnt0, xp, N1c);

    // head0: logits + softmax -> d_out[0:48000], xb = [x0 | x_pool1]
    head0<<<N1c, 64, 0, stream>>>(xp, linW0, linb0, x_pool1, outp, xb);

    // ---- phase B: 3 GCN layers on N1 (fp32 vector GEMMs) ----
    agg17_gemm_bn<<<N1c, 256, 0, stream>>>(xb, rp1, csw, dinv1, W_in1, b1, g1, be1,
                                           m1, v1, hbbbf);
    agg_bf16<32, 4, false><<<4 * cdiv_i(N1c, 8), 256, 0, stream>>>(hbbbf, rp1, csw, dinv1, zbb, N1c);
    gemm_bn<256, true, false, true><<<dim3(cdiv_i(N1c, 64), 4), 256, 0, stream>>>(
        zbb, W_h1, b1 + Hc, g1 + Hc, be1 + Hc, m1 + Hc, v1 + Hc, nullptr, hbbbf, N1c);
    agg_bf16<32, 4, false><<<4 * cdiv_i(N1c, 8), 256, 0, stream>>>(hbbbf, rp1, csw, dinv1, zbb, N1c);

    // atomic-free 3000->16 reduction: 256-block partials, then head1 combines
    pool_b_partial<<<256, 256, 0, stream>>>(zbb, bpool, part, pcnt);
    head1<<<Bc, 256, 0, stream>>>(part, pcnt, W_h1 + Hc * Hc, b1 + 2 * Hc, g1 + 2 * Hc,
                                  be1 + 2 * Hc, m1 + 2 * Hc, v1 + 2 * Hc, linW1, linb1,
                                  outp);
}

// Round 8
// 384.105 us; speedup vs baseline: 1.0999x; 1.0042x over previous
//
#include <hip/hip_runtime.h>
#include <cstdint>
#include <cstddef>

// Problem constants
#define N0c 30000
#define F0c 128
#define Hc  256
#define Cc  16
#define N1c 3000
#define Bc  16
#define E0c 960000
#define E1c 48000
#define NALL 33000            // N0 + N1 (concatenated graphs)
#define EALL 1008000          // E0 + E1
#define EPSc 1e-5f
#define SLICE 188             // clusters per pool_b_partial slice (16*188 >= 3000)

// r17 bucket-sort CSR build: the 1M global atomicAdds were at a memory-side
// atomic throughput wall (~21/ns, 32MB sector writeback). LDS-histogram bucket
// sort: zero global atomics. bucket = dst>>5 (32 nodes), NBKT=1032.
#define NBKT 1032
#define NSCB 256
#define EPB  3938             // edges per scatter block (256*3938 >= EALL)

static __host__ __device__ inline int cdiv_i(int a, int b) { return (a + b - 1) / b; }

// round-to-nearest-even fp32 -> bf16 (returns the 16 bf16 bits)
static __device__ inline unsigned short bfbits(float f) {
    unsigned u = __float_as_uint(f);
    return (unsigned short)((u + 0x7fffu + ((u >> 16) & 1u)) >> 16);
}

typedef short short8 __attribute__((ext_vector_type(8)));   // 8 bf16 = 4 VGPRs
typedef float floatx4 __attribute__((ext_vector_type(4)));

// ---------------- prep1: bucket count (LDS hist) + indep prep work ------------
#define P1_CNT NSCB
#define P1_CVT 3750
#define P1_PW  386
#define P1_SEG 118

__global__ void prep1(const int* __restrict__ dst0, const int* __restrict__ dst1,
                      int* __restrict__ blockhist,
                      const float* __restrict__ x, unsigned short* __restrict__ xbf,
                      const float* __restrict__ W_in0, const float* __restrict__ W_h0,
                      const float* __restrict__ b0, const float* __restrict__ g0,
                      const float* __restrict__ be0, const float* __restrict__ m0,
                      const float* __restrict__ v0,
                      unsigned short* __restrict__ Wt0, unsigned short* __restrict__ Wt1,
                      float* __restrict__ sc0, float* __restrict__ sh0,
                      float* __restrict__ sc1, float* __restrict__ sh1,
                      const int* __restrict__ pool1, int* __restrict__ start0) {
    __shared__ int hist[NBKT];
    int bx = blockIdx.x, t = threadIdx.x;
    if (bx < P1_CNT) {
        for (int k = t; k < NBKT; k += 256) hist[k] = 0;
        __syncthreads();
        int e0 = bx * EPB, e1 = min(e0 + EPB, EALL);
        for (int e = e0 + t; e < e1; e += 256) {
            int d = (e < E0c) ? dst0[e] : (N0c + dst1[e - E0c]);
            atomicAdd(&hist[d >> 5], 1);
        }
        __syncthreads();
        for (int k = t; k < NBKT; k += 256) blockhist[k * NSCB + bx] = hist[k];
    } else if (bx < P1_CNT + P1_CVT) {
        int i = (bx - P1_CNT) * 256 + t;            // float4 index
        if (i >= N0c * 32) return;
        float4 v = ((const float4*)x)[i];
        ushort4 o;
        o.x = bfbits(v.x); o.y = bfbits(v.y); o.z = bfbits(v.z); o.w = bfbits(v.w);
        ((ushort4*)xbf)[i] = o;
    } else if (bx < P1_CNT + P1_CVT + P1_PW) {
        int pb = bx - P1_CNT - P1_CVT;
        if (pb < 128) {
            int i = pb * 256 + t;
            int k = i >> 8, col = i & 255;
            Wt0[col * 128 + k] = bfbits(W_in0[i]);
        } else if (pb < 384) {
            int i = (pb - 128) * 256 + t;
            int k = i >> 8, col = i & 255;
            Wt1[col * 256 + k] = bfbits(W_h0[i]);
        } else if (pb == 384) {
            float s = g0[t] * rsqrtf(v0[t] + EPSc);
            sc0[t] = s;
            sh0[t] = (b0[t] - m0[t]) * s + be0[t];
        } else {
            int tt = t + 256;
            float s = g0[tt] * rsqrtf(v0[tt] + EPSc);
            sc1[t] = s;
            sh1[t] = (b0[tt] - m0[tt]) * s + be0[tt];
        }
    } else {
        int i = (bx - P1_CNT - P1_CVT - P1_PW) * 256 + t;
        if (i > N0c) return;
        if (i == 0) {
            for (int c = 0; c <= pool1[0]; ++c) start0[c] = 0;
        } else if (i == N0c) {
            for (int c = pool1[N0c - 1] + 1; c <= N1c; ++c) start0[c] = N0c;
        } else {
            int a = pool1[i - 1], b = pool1[i];
            for (int c = a + 1; c <= b; ++c) start0[c] = i;
        }
    }
}

// scanh_block: block b = bucket b; exclusive scan of blockhist[b][0..255]
// -> hx (within-bucket offsets per scatter block) + bktSum[b] (bucket total)
__global__ void scanh_block(const int* __restrict__ blockhist, int* __restrict__ hx,
                            int* __restrict__ bktSum) {
    __shared__ int sh[256];
    int b = blockIdx.x, t = threadIdx.x;
    int v = blockhist[b * NSCB + t];
    sh[t] = v; __syncthreads();
    for (int off = 1; off < 256; off <<= 1) {
        int add = (t >= off) ? sh[t - off] : 0;
        __syncthreads();
        sh[t] += add;
        __syncthreads();
    }
    hx[b * NSCB + t] = sh[t] - v;
    if (t == 255) bktSum[b] = sh[255];
}

// scanh_sums: single block, carry-loop exclusive scan of NBKT bucket totals
__global__ void scanh_sums(const int* __restrict__ bktSum, int* __restrict__ bktOff) {
    __shared__ int sh[256];
    int t = threadIdx.x;
    int carry = 0;
    for (int k = 0; k < (NBKT + 255) / 256; ++k) {
        int i = k * 256 + t;
        int v = (i < NBKT) ? bktSum[i] : 0;
        sh[t] = v; __syncthreads();
        for (int off = 1; off < 256; off <<= 1) {
            int add = (t >= off) ? sh[t - off] : 0;
            __syncthreads();
            sh[t] += add;
            __syncthreads();
        }
        if (i < NBKT) bktOff[i] = carry + sh[t] - v;
        carry += sh[255];
        __syncthreads();
    }
    if (t == 0) bktOff[NBKT] = carry;   // == EALL
}

// scatter_e: re-read edges, place into bucket-grouped order via LDS base bump.
// pk = (dst_global << 16) | src_local  (both < 65536)
__global__ __launch_bounds__(256) void scatter_e(
    const int* __restrict__ src0, const int* __restrict__ dst0,
    const int* __restrict__ src1, const int* __restrict__ dst1,
    const int* __restrict__ hx, const int* __restrict__ bktOff,
    unsigned* __restrict__ ebkt) {
    __shared__ int base[NBKT];
    int blk = blockIdx.x, t = threadIdx.x;
    for (int k = t; k < NBKT; k += 256) base[k] = bktOff[k] + hx[k * NSCB + blk];
    __syncthreads();
    int e0 = blk * EPB, e1 = min(e0 + EPB, EALL);
    for (int e = e0 + t; e < e1; e += 256) {
        int s, d;
        if (e < E0c) { s = src0[e]; d = dst0[e]; }
        else         { s = src1[e - E0c]; d = N0c + dst1[e - E0c]; }
        int bkt = d >> 5;
        int pos = atomicAdd(&base[bkt], 1);
        ebkt[pos] = ((unsigned)d << 16) | (unsigned)s;
    }
}

// count_scan_n: block b owns nodes [b*256, b*256+256) = buckets [8b, 8b+8).
// Degree count from bucketed edges (LDS hist, block-owned nodes -> no global
// atomics), dinv = rsqrt(deg+1), block-level exclusive scan of degrees.
__global__ void count_scan_n(const unsigned* __restrict__ ebkt,
                             const int* __restrict__ bktOff, int n,
                             int* __restrict__ rp, int* __restrict__ blkSum,
                             float* __restrict__ dinv) {
    __shared__ int hist[256];
    __shared__ int sh[256];
    int b = blockIdx.x, t = threadIdx.x;
    hist[t] = 0; __syncthreads();
    int lo = bktOff[b * 8];
    int hi = bktOff[b * 8 + 8];
    for (int e = lo + t; e < hi; e += 256) {
        int d = (int)(ebkt[e] >> 16);
        atomicAdd(&hist[d - b * 256], 1);
    }
    __syncthreads();
    int i = b * 256 + t;
    int v = hist[t];
    if (i < n) dinv[i] = rsqrtf((float)(v + 1));
    sh[t] = v; __syncthreads();
    for (int off = 1; off < 256; off <<= 1) {
        int add = (t >= off) ? sh[t - off] : 0;
        __syncthreads();
        sh[t] += add;
        __syncthreads();
    }
    if (i < n) rp[i] = sh[t] - v;
    if (t == 255) blkSum[b] = sh[255];
}

__global__ void scan_sums(const int* __restrict__ blkSum, int nb, int* __restrict__ blkOff,
                          int* __restrict__ rp, int n) {
    __shared__ int sh[256];
    int t = threadIdx.x;
    int v = (t < nb) ? blkSum[t] : 0;
    sh[t] = v; __syncthreads();
    for (int off = 1; off < 256; off <<= 1) {
        int add = (t >= off) ? sh[t - off] : 0;
        __syncthreads();
        sh[t] += add;
        __syncthreads();
    }
    blkOff[t] = sh[t] - v;
    if (t == 255) rp[n] = sh[255];
}

// fill_csr: one block per bucket; LDS rank counters over the bucket's 32
// nodes place each edge at its final CSR slot. Tail blocks build rpf.
// r20: extra CLST blocks compute per-cluster cnt0 + bpool.
#define FILL_TAIL 129
#define FILL_CLST 12
__global__ __launch_bounds__(256) void fill_csr(
    const unsigned* __restrict__ ebkt, const int* __restrict__ bktOff,
    const int* __restrict__ rp, const int* __restrict__ blkOff,
    const float* __restrict__ dinv, unsigned* __restrict__ csw,
    int* __restrict__ rpf, const int* __restrict__ start0,
    const int* __restrict__ batch, int* __restrict__ cnt0,
    int* __restrict__ bpool) {
    int bx = blockIdx.x, t = threadIdx.x;
    if (bx < NBKT) {
        __shared__ int lrp[32];
        __shared__ float ldv[32];
        __shared__ int cnt[32];
        if (t < 32) {
            int node = bx * 32 + t;
            cnt[t] = 0;
            if (node < NALL) {
                lrp[t] = rp[node] + blkOff[node >> 8];
                ldv[t] = dinv[node];
            } else { lrp[t] = 0; ldv[t] = 0.f; }
        }
        __syncthreads();
        int lo = bktOff[bx], hi = bktOff[bx + 1];
        for (int e = lo + t; e < hi; e += 256) {
            unsigned pk = ebkt[e];
            int d = (int)(pk >> 16);
            int sloc = (int)(pk & 0xffffu);
            int dl = d & 31;
            int lr = atomicAdd(&cnt[dl], 1);
            int sg = (d >= N0c) ? (N0c + sloc) : sloc;
            float w = dinv[sg] * ldv[dl];
            csw[lrp[dl] + lr] = ((unsigned)bfbits(w) << 16) | (unsigned)sloc;
        }
    } else if (bx < NBKT + FILL_TAIL) {
        int i = (bx - NBKT) * 256 + t;
        if (i < NALL) rpf[i] = rp[i] + blkOff[i >> 8];
        else if (i == NALL) rpf[NALL] = rp[NALL];
    } else {
        int c = (bx - NBKT - FILL_TAIL) * 256 + t;
        if (c < N1c) {
            int s = start0[c], e = start0[c + 1];
            int cnt = e - s;
            cnt0[c] = cnt;
            int sb = 0;
            for (int i = s; i < e; ++i) sb += batch[i];
            bpool[c] = (int)rintf((float)sb / (float)max(cnt, 1));
        }
    }
}

// ---------------- aggregation (bf16 gather, fp32 accumulate) ----------------

static __device__ inline void acc8(float a[8], float w, uint4 v) {
    a[0] += w * __uint_as_float(v.x << 16);
    a[1] += w * __uint_as_float(v.x & 0xffff0000u);
    a[2] += w * __uint_as_float(v.y << 16);
    a[3] += w * __uint_as_float(v.y & 0xffff0000u);
    a[4] += w * __uint_as_float(v.z << 16);
    a[5] += w * __uint_as_float(v.z & 0xffff0000u);
    a[6] += w * __uint_as_float(v.w << 16);
    a[7] += w * __uint_as_float(v.w & 0xffff0000u);
}

// r22: paired-edge accumulate via v_dot2_f32_bf16 (VOP3P, CDNA3+):
// a[c] += wA*va[c] + wB*vb[c] in ONE instruction per column, operands built
// with v_perm_b32. wp = (wA lo16 | wB hi16); zero-padded edges have bf16
// weight +0.0 and row index 0 (finite data) -> exact no-op.
static __device__ inline void accd(float a[8], unsigned wp, uint4 va, uint4 vb) {
#define DOT2P(k, A, B) { \
    unsigned plo = __builtin_amdgcn_perm(B, A, 0x05040100u); /* (A.lo,B.lo) */ \
    unsigned phi = __builtin_amdgcn_perm(B, A, 0x07060302u); /* (A.hi,B.hi) */ \
    asm("v_dot2_f32_bf16 %0, %1, %2, %0" : "+v"(a[k])     : "v"(plo), "v"(wp)); \
    asm("v_dot2_f32_bf16 %0, %1, %2, %0" : "+v"(a[k + 1]) : "v"(phi), "v"(wp)); }
    DOT2P(0, va.x, vb.x)
    DOT2P(2, va.y, vb.y)
    DOT2P(4, va.z, vb.z)
    DOT2P(6, va.w, vb.w)
#undef DOT2P
}

// TWO nodes per wave, FOUR edge slots each (lane = ns*32 + par*8 + cl).
// NCHUNK chunks of 64 cols; chunk = blockIdx&(NCHUNK-1) keeps XCD pinning.
// r19: per-lane direct csw loads. r22: paired v_dot2_f32_bf16 accumulate.
// r23: pipeline deepened 4 -> 6 edge-groups in flight (prefetch distance 24
// slots). r22's null (30% VALU cut, dur flat) showed the kernel is
// latency/MLP-bound, not issue-bound; 6-deep stays <= 64 VGPR (occupancy
// halves past 64 per m69, which would cancel the MLP gain).
template <int RSU, int NCHUNK, bool OBF16>
__global__ __launch_bounds__(256) void agg_bf16(
    const unsigned short* __restrict__ x, const int* __restrict__ rp,
    const unsigned* __restrict__ csw, const float* __restrict__ dinv,
    void* __restrict__ zv, int N) {
    constexpr int SHIFT = (RSU == 32) ? 9 : 8;   // log2(row bytes)
    int b = blockIdx.x;
    int chunk = b & (NCHUNK - 1);
    int wave = threadIdx.x >> 6;
    int lane = threadIdx.x & 63;
    int ns = lane >> 5;                  // node sub (0/1)
    int par = (lane >> 3) & 3;           // edge slot (0..3)
    int cl = lane & 7;                   // 16B slice within 64-col chunk
    int node = (b / NCHUNK) * 8 + wave * 2 + ns;
    bool valid = node < N;
    int nclamp = valid ? node : 0;
    int c4 = chunk * 8 + cl;
    unsigned coff = (unsigned)c4 << 4;
    const char* xb = (const char*)x;
    float a[8] = {0.f, 0.f, 0.f, 0.f, 0.f, 0.f, 0.f, 0.f};
    int e0 = rp[nclamp];
    int e1 = valid ? rp[nclamp + 1] : e0;
    if (valid && par == 0) {             // self-loop term exactly once
        float di = dinv[node];
        uint4 v = *(const uint4*)(xb + (((unsigned)node << SHIFT) + coff));
        acc8(a, di * di, v);
    }
    int deg = e1 - e0;
    int mysteps = (deg + 3) >> 2;
    int steps = max(__shfl(mysteps, 0, 64), __shfl(mysteps, 32, 64));  // uniform
    int e = e0 + par;                    // this lane's first edge slot
    // direct loads (no clamp: csw padded; garbage is dead via the e<e1 select)
    unsigned cw0 = csw[e];      cw0 = (e      < e1) ? cw0 : 0u;
    unsigned cw1 = csw[e + 4];  cw1 = (e + 4  < e1) ? cw1 : 0u;
    unsigned cw2 = csw[e + 8];  cw2 = (e + 8  < e1) ? cw2 : 0u;
    unsigned cw3 = csw[e + 12]; cw3 = (e + 12 < e1) ? cw3 : 0u;
    unsigned cw4 = csw[e + 16]; cw4 = (e + 16 < e1) ? cw4 : 0u;
    unsigned cw5 = csw[e + 20]; cw5 = (e + 20 < e1) ? cw5 : 0u;
    int i = 0;
    for (; i + 5 < steps; i += 6) {
        // 6 gathers in flight (addresses depend only on already-loaded cw*)
        uint4 v0 = *(const uint4*)(xb + (((cw0 & 0xffffu) << SHIFT) + coff));
        uint4 v1 = *(const uint4*)(xb + (((cw1 & 0xffffu) << SHIFT) + coff));
        uint4 v2 = *(const uint4*)(xb + (((cw2 & 0xffffu) << SHIFT) + coff));
        uint4 v3 = *(const uint4*)(xb + (((cw3 & 0xffffu) << SHIFT) + coff));
        uint4 v4 = *(const uint4*)(xb + (((cw4 & 0xffffu) << SHIFT) + coff));
        uint4 v5 = *(const uint4*)(xb + (((cw5 & 0xffffu) << SHIFT) + coff));
        // prefetch next group's edge words under the gathers
        int en = e + 24;
        unsigned nw0 = csw[en];      nw0 = (en      < e1) ? nw0 : 0u;
        unsigned nw1 = csw[en + 4];  nw1 = (en + 4  < e1) ? nw1 : 0u;
        unsigned nw2 = csw[en + 8];  nw2 = (en + 8  < e1) ? nw2 : 0u;
        unsigned nw3 = csw[en + 12]; nw3 = (en + 12 < e1) ? nw3 : 0u;
        unsigned nw4 = csw[en + 16]; nw4 = (en + 16 < e1) ? nw4 : 0u;
        unsigned nw5 = csw[en + 20]; nw5 = (en + 20 < e1) ? nw5 : 0u;
        unsigned wp01 = __builtin_amdgcn_perm(cw1, cw0, 0x07060302u);
        unsigned wp23 = __builtin_amdgcn_perm(cw3, cw2, 0x07060302u);
        unsigned wp45 = __builtin_amdgcn_perm(cw5, cw4, 0x07060302u);
        accd(a, wp01, v0, v1);
        accd(a, wp23, v2, v3);
        accd(a, wp45, v4, v5);
        cw0 = nw0; cw1 = nw1; cw2 = nw2; cw3 = nw3; cw4 = nw4; cw5 = nw5;
        e = en;
    }
    // tail: r = steps - i in [0,5]; wave-uniform branches; cw* already loaded
    int r = steps - i;
    if (r >= 2) {
        uint4 v0 = *(const uint4*)(xb + (((cw0 & 0xffffu) << SHIFT) + coff));
        uint4 v1 = *(const uint4*)(xb + (((cw1 & 0xffffu) << SHIFT) + coff));
        unsigned wp01 = __builtin_amdgcn_perm(cw1, cw0, 0x07060302u);
        accd(a, wp01, v0, v1);
    }
    if (r >= 4) {
        uint4 v2 = *(const uint4*)(xb + (((cw2 & 0xffffu) << SHIFT) + coff));
        uint4 v3 = *(const uint4*)(xb + (((cw3 & 0xffffu) << SHIFT) + coff));
        unsigned wp23 = __builtin_amdgcn_perm(cw3, cw2, 0x07060302u);
        accd(a, wp23, v2, v3);
    }
    if (r & 1) {
        unsigned cwo = (r == 1) ? cw0 : ((r == 3) ? cw2 : cw4);
        uint4 v = *(const uint4*)(xb + (((cwo & 0xffffu) << SHIFT) + coff));
        acc8(a, __uint_as_float(cwo & 0xffff0000u), v);
    }
    // reduce across the 4 edge slots (2 levels, stays within each node half)
#pragma unroll
    for (int m = 8; m < 32; m <<= 1) {
#pragma unroll
        for (int k = 0; k < 8; ++k) a[k] += __shfl_xor(a[k], m, 64);
    }
    if (valid && par == 0) {
        if (OBF16) {
            uint4 o;
            o.x = (unsigned)bfbits(a[0]) | ((unsigned)bfbits(a[1]) << 16);
            o.y = (unsigned)bfbits(a[2]) | ((unsigned)bfbits(a[3]) << 16);
            o.z = (unsigned)bfbits(a[4]) | ((unsigned)bfbits(a[5]) << 16);
            o.w = (unsigned)bfbits(a[6]) | ((unsigned)bfbits(a[7]) << 16);
            ((uint4*)zv)[(size_t)node * RSU + c4] = o;
        } else {
            float4* zp = (float4*)zv + (size_t)node * (RSU * 2) + c4 * 2;
            zp[0] = make_float4(a[0], a[1], a[2], a[3]);
            zp[1] = make_float4(a[4], a[5], a[6], a[7]);
        }
    }
}

// r20/r21/r22/r23: fused layer-2 aggregation + mean-pool. pool1 is SORTED ->
// cluster c owns the contiguous node range [start0[c], start0[c+1]) AND the
// contiguous edge slice csw[rpf[start0[c]] .. rpf[start0[c+1]]). ONE cluster
// per wave, EIGHT edge slots; paired dot2 accumulate; 6-deep pipeline.
template <int NCHUNK>
__global__ __launch_bounds__(256) void agg_pool(
    const unsigned short* __restrict__ x, const int* __restrict__ rpf,
    const unsigned* __restrict__ csw, const float* __restrict__ dinv,
    const int* __restrict__ start0, float* __restrict__ out, int N) {
    constexpr int SHIFT = 9;             // 256-col bf16 rows = 512 B
    int b = blockIdx.x;
    int chunk = b & (NCHUNK - 1);
    int wave = threadIdx.x >> 6;
    int lane = threadIdx.x & 63;
    int par = lane >> 3;                 // edge slot (0..7)
    int cl = lane & 7;                   // 16B slice within 64-col chunk
    int c = (b / NCHUNK) * 4 + wave;
    bool valid = c < N;
    int cc = valid ? c : 0;
    int c4 = chunk * 8 + cl;
    unsigned coff = (unsigned)c4 << 4;
    const char* xb = (const char*)x;
    float a[8] = {0.f, 0.f, 0.f, 0.f, 0.f, 0.f, 0.f, 0.f};
    int s0 = start0[cc];
    int s1 = valid ? start0[cc + 1] : s0;
    int e0 = rpf[s0];
    int e1 = valid ? rpf[s1] : e0;
    // self-loop terms for member nodes, par-strided (members are contiguous)
    for (int m = s0 + par; m < s1; m += 8) {
        float di = dinv[m];
        uint4 v = *(const uint4*)(xb + (((unsigned)m << SHIFT) + coff));
        acc8(a, di * di, v);
    }
    int deg = e1 - e0;
    int steps = (deg + 7) >> 3;          // wave-uniform (one cluster per wave)
    int e = e0 + par;
    unsigned cw0 = csw[e];      cw0 = (e      < e1) ? cw0 : 0u;
    unsigned cw1 = csw[e + 8];  cw1 = (e + 8  < e1) ? cw1 : 0u;
    unsigned cw2 = csw[e + 16]; cw2 = (e + 16 < e1) ? cw2 : 0u;
    unsigned cw3 = csw[e + 24]; cw3 = (e + 24 < e1) ? cw3 : 0u;
    unsigned cw4 = csw[e + 32]; cw4 = (e + 32 < e1) ? cw4 : 0u;
    unsigned cw5 = csw[e + 40]; cw5 = (e + 40 < e1) ? cw5 : 0u;
    int i = 0;
    for (; i + 5 < steps; i += 6) {
        uint4 v0 = *(const uint4*)(xb + (((cw0 & 0xffffu) << SHIFT) + coff));
        uint4 v1 = *(const uint4*)(xb + (((cw1 & 0xffffu) << SHIFT) + coff));
        uint4 v2 = *(const uint4*)(xb + (((cw2 & 0xffffu) << SHIFT) + coff));
        uint4 v3 = *(const uint4*)(xb + (((cw3 & 0xffffu) << SHIFT) + coff));
        uint4 v4 = *(const uint4*)(xb + (((cw4 & 0xffffu) << SHIFT) + coff));
        uint4 v5 = *(const uint4*)(xb + (((cw5 & 0xffffu) << SHIFT) + coff));
        int en = e + 48;
        unsigned nw0 = csw[en];      nw0 = (en      < e1) ? nw0 : 0u;
        unsigned nw1 = csw[en + 8];  nw1 = (en + 8  < e1) ? nw1 : 0u;
        unsigned nw2 = csw[en + 16]; nw2 = (en + 16 < e1) ? nw2 : 0u;
        unsigned nw3 = csw[en + 24]; nw3 = (en + 24 < e1) ? nw3 : 0u;
        unsigned nw4 = csw[en + 32]; nw4 = (en + 32 < e1) ? nw4 : 0u;
        unsigned nw5 = csw[en + 40]; nw5 = (en + 40 < e1) ? nw5 : 0u;
        unsigned wp01 = __builtin_amdgcn_perm(cw1, cw0, 0x07060302u);
        unsigned wp23 = __builtin_amdgcn_perm(cw3, cw2, 0x07060302u);
        unsigned wp45 = __builtin_amdgcn_perm(cw5, cw4, 0x07060302u);
        accd(a, wp01, v0, v1);
        accd(a, wp23, v2, v3);
        accd(a, wp45, v4, v5);
        cw0 = nw0; cw1 = nw1; cw2 = nw2; cw3 = nw3; cw4 = nw4; cw5 = nw5;
        e = en;
    }
    int r = steps - i;
    if (r >= 2) {
        uint4 v0 = *(const uint4*)(xb + (((cw0 & 0xffffu) << SHIFT) + coff));
        uint4 v1 = *(const uint4*)(xb + (((cw1 & 0xffffu) << SHIFT) + coff));
        unsigned wp01 = __builtin_amdgcn_perm(cw1, cw0, 0x07060302u);
        accd(a, wp01, v0, v1);
    }
    if (r >= 4) {
        uint4 v2 = *(const uint4*)(xb + (((cw2 & 0xffffu) << SHIFT) + coff));
        uint4 v3 = *(const uint4*)(xb + (((cw3 & 0xffffu) << SHIFT) + coff));
        unsigned wp23 = __builtin_amdgcn_perm(cw3, cw2, 0x07060302u);
        accd(a, wp23, v2, v3);
    }
    if (r & 1) {
        unsigned cwo = (r == 1) ? cw0 : ((r == 3) ? cw2 : cw4);
        uint4 v = *(const uint4*)(xb + (((cwo & 0xffffu) << SHIFT) + coff));
        acc8(a, __uint_as_float(cwo & 0xffff0000u), v);
    }
    // reduce across the 8 edge slots (3 levels, full wave)
#pragma unroll
    for (int m = 8; m < 64; m <<= 1) {
#pragma unroll
        for (int k = 0; k < 8; ++k) a[k] += __shfl_xor(a[k], m, 64);
    }
    if (valid && par == 0) {
        float inv = 1.0f / (float)max(s1 - s0, 1);
        float4* zp = (float4*)out + (size_t)c * 64 + c4 * 2;
        zp[0] = make_float4(a[0] * inv, a[1] * inv, a[2] * inv, a[3] * inv);
        zp[1] = make_float4(a[4] * inv, a[5] * inv, a[6] * inv, a[7] * inv);
    }
}

// ---------------- MFMA bf16 GEMM: (M x K)bf16 @ Wt(256 x K)bf16 -> bf16 out ----

template <int K>
__global__ __launch_bounds__(256) void gemm_mfma_bn(
    const unsigned short* __restrict__ A, const unsigned short* __restrict__ Wt,
    const float* __restrict__ sc, const float* __restrict__ sh,
    unsigned short* __restrict__ out, int M) {
    constexpr int LDS_S = 40;
    __shared__ unsigned short As[64 * LDS_S];
    __shared__ unsigned short Bs[256 * LDS_S];
    int tid = threadIdx.x;
    int w = tid >> 6, l = tid & 63;
    int quad = l >> 4, lm = l & 15;
    int row0 = blockIdx.x * 64;
    floatx4 acc[4][4];
#pragma unroll
    for (int i = 0; i < 4; ++i)
#pragma unroll
        for (int j = 0; j < 4; ++j) acc[i][j] = (floatx4){0.f, 0.f, 0.f, 0.f};

    int ar = tid >> 2;          // A staging: row 0..63
    int ac = (tid & 3) * 8;     // short offset 0,8,16,24

    for (int k0 = 0; k0 < K; k0 += 32) {
        uint4 av = make_uint4(0, 0, 0, 0);
        if (row0 + ar < M) av = *(const uint4*)(A + (size_t)(row0 + ar) * K + k0 + ac);
        *(uint4*)&As[ar * LDS_S + ac] = av;
#pragma unroll
        for (int c = 0; c < 4; ++c) {    // Bs: thread -> col tid, 4 k-chunks
            uint4 bv = *(const uint4*)(Wt + (size_t)tid * K + k0 + c * 8);
            *(uint4*)&Bs[tid * LDS_S + c * 8] = bv;
        }
        __syncthreads();
        short8 af[4], bf[4];
#pragma unroll
        for (int i = 0; i < 4; ++i)
            af[i] = *(const short8*)&As[(i * 16 + lm) * LDS_S + quad * 8];
#pragma unroll
        for (int j = 0; j < 4; ++j)
            bf[j] = *(const short8*)&Bs[(w * 64 + j * 16 + lm) * LDS_S + quad * 8];
#pragma unroll
        for (int i = 0; i < 4; ++i)
#pragma unroll
            for (int j = 0; j < 4; ++j)
                acc[i][j] = __builtin_amdgcn_mfma_f32_16x16x32_bf16(af[i], bf[j], acc[i][j], 0, 0, 0);
        __syncthreads();
    }
    // epilogue: C/D map col=lane&15, row=quad*4+reg [verified m89/m91]
#pragma unroll
    for (int j = 0; j < 4; ++j) {
        int col = w * 64 + j * 16 + lm;
        float s = sc[col], h = sh[col];
#pragma unroll
        for (int i = 0; i < 4; ++i) {
            int rb = row0 + i * 16 + quad * 4;
#pragma unroll
            for (int r = 0; r < 4; ++r) {
                int row = rb + r;
                if (row < M) {
                    float v = acc[i][j][r] * s + h;
                    v = fmaxf(v, 0.f);
                    out[(size_t)row * 256 + col] = bfbits(v);
                }
            }
        }
    }
}

// ---------------- fp32 vector GEMM (kept for small M=3000, precision-critical) --

template <int K, bool RELU, bool ZEROEMPTY, bool OBF16>
__global__ __launch_bounds__(256) void gemm_bn(
    const float* __restrict__ A, const float* __restrict__ W,
    const float* __restrict__ bias, const float* __restrict__ gam,
    const float* __restrict__ bet, const float* __restrict__ mu,
    const float* __restrict__ var, const int* __restrict__ cnt,
    void* __restrict__ outv, int M) {
    __shared__ __align__(16) float As[16][64];
    __shared__ __align__(16) float Bs[16][64];
    int tid = threadIdx.x;
    int tm = tid >> 4, tn = tid & 15;
    int row0 = blockIdx.x * 64, col0 = blockIdx.y * 64;
    float acc[4][4] = {};
    int ar = tid >> 2;
    int ak = (tid & 3) * 4;
    int bk = tid >> 4;
    int bn = (tid & 15) * 4;

    for (int kk = 0; kk < K; kk += 16) {
        float4 av = make_float4(0.f, 0.f, 0.f, 0.f);
        int grow = row0 + ar;
        if (grow < M) av = *(const float4*)(A + (size_t)grow * K + kk + ak);
        As[ak + 0][ar] = av.x;
        As[ak + 1][ar] = av.y;
        As[ak + 2][ar] = av.z;
        As[ak + 3][ar] = av.w;
        float4 bv = *(const float4*)(W + (size_t)(kk + bk) * 256 + col0 + bn);
        *(float4*)&Bs[bk][bn] = bv;
        __syncthreads();
#pragma unroll
        for (int k = 0; k < 16; ++k) {
            float4 a = *(const float4*)&As[k][tm * 4];
            float4 b = *(const float4*)&Bs[k][tn * 4];
            acc[0][0] += a.x * b.x; acc[0][1] += a.x * b.y; acc[0][2] += a.x * b.z; acc[0][3] += a.x * b.w;
            acc[1][0] += a.y * b.x; acc[1][1] += a.y * b.y; acc[1][2] += a.y * b.z; acc[1][3] += a.y * b.w;
            acc[2][0] += a.z * b.x; acc[2][1] += a.z * b.y; acc[2][2] += a.z * b.z; acc[2][3] += a.z * b.w;
            acc[3][0] += a.w * b.x; acc[3][1] += a.w * b.y; acc[3][2] += a.w * b.z; acc[3][3] += a.w * b.w;
        }
        __syncthreads();
    }
    float bcol[4], scol[4], mcol[4], ecol[4];
#pragma unroll
    for (int j = 0; j < 4; ++j) {
        int col = col0 + tn * 4 + j;
        bcol[j] = bias[col];
        scol[j] = gam[col] * rsqrtf(var[col] + EPSc);
        mcol[j] = mu[col];
        ecol[j] = bet[col];
    }
#pragma unroll
    for (int i = 0; i < 4; ++i) {
        int row = row0 + tm * 4 + i;
        if (row >= M) continue;
        bool zero = false;
        if (ZEROEMPTY) zero = (cnt[row] == 0);
        float r[4];
#pragma unroll
        for (int j = 0; j < 4; ++j) {
            float v = acc[i][j] + bcol[j];
            v = (v - mcol[j]) * scol[j] + ecol[j];
            if (RELU) v = fmaxf(v, 0.f);
            if (zero) v = 0.f;
            r[j] = v;
        }
        if (OBF16) {
            ushort4 o;
            o.x = bfbits(r[0]); o.y = bfbits(r[1]); o.z = bfbits(r[2]); o.w = bfbits(r[3]);
            *(ushort4*)((unsigned short*)outv + (size_t)row * 256 + col0 + tn * 4) = o;
        } else {
            float4 o = make_float4(r[0], r[1], r[2], r[3]);
            *(float4*)((float*)outv + (size_t)row * 256 + col0 + tn * 4) = o;
        }
    }
}

// fused: 17-wide aggregation (graph 1) + K=17 GEMM + BN + ReLU, bf16 out
__global__ void agg17_gemm_bn(const float* __restrict__ xb, const int* __restrict__ rp,
                              const unsigned* __restrict__ csw, const float* __restrict__ dinv,
                              const float* __restrict__ W, const float* __restrict__ bias,
                              const float* __restrict__ gam, const float* __restrict__ bet,
                              const float* __restrict__ mu, const float* __restrict__ var,
                              unsigned short* __restrict__ out) {
    int r = blockIdx.x, t = threadIdx.x;   // 256 threads
    __shared__ float zr[17];
    if (t < 17) {
        float di = dinv[r];
        float acc = di * di * xb[(size_t)r * 17 + t];
        int e0 = rp[r], e1 = rp[r + 1];
        for (int e = e0; e < e1; ++e) {
            unsigned ew = csw[e];
            acc += __uint_as_float(ew & 0xffff0000u) * xb[(size_t)(ew & 0xffffu) * 17 + t];
        }
        zr[t] = acc;
    }
    __syncthreads();
    float acc = bias[t];
#pragma unroll
    for (int k = 0; k < 17; ++k) acc += zr[k] * W[k * 256 + t];
    float s = gam[t] * rsqrtf(var[t] + EPSc);
    acc = (acc - mu[t]) * s + bet[t];
    acc = fmaxf(acc, 0.f);
    out[(size_t)r * 256 + t] = bfbits(acc);
}

// ---------------- pooling ----------------

// stage 1 of atomic-free 3000->16 reduction: 256 blocks = 16 graphs x 16 slices.
__global__ __launch_bounds__(256) void pool_b_partial(
    const float* __restrict__ zbb, const int* __restrict__ bpool,
    float* __restrict__ part, int* __restrict__ pcnt) {
    int b = blockIdx.x;          // 0..255
    int g = b & 15, s = b >> 4;
    int t = threadIdx.x;
    int i0 = s * SLICE;
    int n = min(N1c - i0, SLICE);
    __shared__ int bp[SLICE];
    for (int i = t; i < n; i += 256) bp[i] = bpool[i0 + i];
    __syncthreads();
    float acc = 0.f;
    int c = 0;
    for (int i = 0; i < n; ++i) {
        int hit = (bp[i] == g);
        float sel = hit ? 1.f : 0.f;
        acc += sel * zbb[(size_t)(i0 + i) * 256 + t];   // load NOT branch-gated
        c += hit;
    }
    part[(size_t)b * 256 + t] = acc;
    if (t == 0) pcnt[b] = c;
}

// ---------------- heads ----------------

__global__ void head0(const float* __restrict__ xp, const float* __restrict__ linW,
                      const float* __restrict__ linb, const float* __restrict__ xpool1,
                      float* __restrict__ outp, float* __restrict__ xb) {
    int r = blockIdx.x, t = threadIdx.x;  // 64 threads
    __shared__ float xr[256];
    __shared__ float lg[16];
    __shared__ float ex[16];
#pragma unroll
    for (int j = 0; j < 4; ++j) xr[t + 64 * j] = xp[(size_t)r * 256 + t + 64 * j];
    __syncthreads();
    if (t < 16) {
        float acc = linb[t];
        for (int k = 0; k < 256; ++k) acc += xr[k] * linW[k * 16 + t];
        lg[t] = acc;
    }
    __syncthreads();
    if (t < 16) {
        float mx = lg[0];
#pragma unroll
        for (int c = 1; c < 16; ++c) mx = fmaxf(mx, lg[c]);
        ex[t] = expf(lg[t] - mx);
    }
    __syncthreads();
    if (t < 16) {
        float sum = 0.f;
#pragma unroll
        for (int c = 0; c < 16; ++c) sum += ex[c];
        float pv = ex[t] / sum;
        outp[(size_t)r * 16 + t] = pv;
        xb[(size_t)r * 17 + t] = pv;
    }
    if (t == 16) xb[(size_t)r * 17 + 16] = xpool1[r];
}

// head1: sum 16 partials -> mean -> layer2 GEMM+BN -> logits -> softmax
__global__ void head1(const float* __restrict__ part, const int* __restrict__ pcnt,
                      const float* __restrict__ W, const float* __restrict__ bias,
                      const float* __restrict__ gam, const float* __restrict__ bet,
                      const float* __restrict__ mu, const float* __restrict__ var,
                      const float* __restrict__ linW, const float* __restrict__ linb,
                      float* __restrict__ outp) {
    int b = blockIdx.x, t = threadIdx.x;  // 16 blocks x 256 threads
    __shared__ float pr[256];
    __shared__ float yr[256];
    __shared__ float lg[16];
    __shared__ float ex[16];
    float acc0 = 0.f;
    int c = 0;
#pragma unroll
    for (int s = 0; s < 16; ++s) {
        int pb = s * 16 + b;
        acc0 += part[(size_t)pb * 256 + t];
        c += pcnt[pb];
    }
    float inv = 1.0f / (float)max(c, 1);
    pr[t] = acc0 * inv;
    __syncthreads();
    float acc = bias[t];
    for (int k = 0; k < 256; ++k) acc += pr[k] * W[k * 256 + t];
    float s = gam[t] * rsqrtf(var[t] + EPSc);
    acc = (acc - mu[t]) * s + bet[t];
    if (c == 0) acc = 0.f;
    yr[t] = acc;
    __syncthreads();
    if (t < 16) {
        float l = linb[t];
        for (int k = 0; k < 256; ++k) l += yr[k] * linW[k * 16 + t];
        lg[t] = l;
    }
    __syncthreads();
    if (t < 16) {
        float mx = lg[0];
#pragma unroll
        for (int cc = 1; cc < 16; ++cc) mx = fmaxf(mx, lg[cc]);
        ex[t] = expf(lg[t] - mx);
    }
    __syncthreads();
    if (t < 16) {
        float sum = 0.f;
#pragma unroll
        for (int cc = 0; cc < 16; ++cc) sum += ex[cc];
        outp[48000 + b * 16 + t] = ex[t] / sum;
    }
}

// ---------------- launch ----------------

extern "C" void kernel_launch(void* const* d_in, const int* in_sizes, int n_in,
                              void* d_out, int out_size, void* d_ws, size_t ws_size,
                              hipStream_t stream) {
    const float* x       = (const float*)d_in[0];
    const float* x_pool1 = (const float*)d_in[1];
    const float* W_in0   = (const float*)d_in[2];
    const float* W_h0    = (const float*)d_in[3];
    const float* b0      = (const float*)d_in[4];
    const float* g0      = (const float*)d_in[5];
    const float* be0     = (const float*)d_in[6];
    const float* m0      = (const float*)d_in[7];
    const float* v0      = (const float*)d_in[8];
    const float* W_in1   = (const float*)d_in[9];
    const float* W_h1    = (const float*)d_in[10];
    const float* b1      = (const float*)d_in[11];
    const float* g1      = (const float*)d_in[12];
    const float* be1     = (const float*)d_in[13];
    const float* m1      = (const float*)d_in[14];
    const float* v1      = (const float*)d_in[15];
    const float* linW0   = (const float*)d_in[16];
    const float* linb0   = (const float*)d_in[17];
    const float* linW1   = (const float*)d_in[18];
    const float* linb1   = (const float*)d_in[19];
    const int*   ei      = (const int*)d_in[20];
    const int*   batch   = (const int*)d_in[21];
    const int*   pool1   = (const int*)d_in[22];
    const int*   eip     = (const int*)d_in[23];
    float* outp = (float*)d_out;

    // carve workspace (256B-aligned); NO memset needed (every buffer fully written)
    char* p = (char*)d_ws;
    auto carve = [&](size_t bytes) -> void* {
        void* r = (void*)p;
        p += (bytes + 255) & ~(size_t)255;
        return r;
    };
    int* blockhist = (int*)carve((size_t)NBKT * NSCB * 4);
    int* hx        = (int*)carve((size_t)NBKT * NSCB * 4);
    int* bktSum    = (int*)carve((size_t)NBKT * 4);
    int* bktOff    = (int*)carve((size_t)(NBKT + 1) * 4);
    unsigned* ebkt = (unsigned*)carve((size_t)EALL * 4);

    int*   rp     = (int*)  carve((size_t)(NALL + 1) * 4);
    int*   rpf    = (int*)  carve((size_t)(NALL + 1) * 4);
    float* dinv   = (float*)carve((size_t)NALL * 4);
    int*   blkSum = (int*)  carve(256 * 4);
    int*   blkOff = (int*)  carve(256 * 4);
    unsigned* csw = (unsigned*)carve((size_t)EALL * 4 + 8192);  // +8KB overrun pad
    // region1: [xbf | z0bf] aliased later by g1bf (15.36 MB total)
    unsigned short* xbf  = (unsigned short*)carve((size_t)N0c * 256 * 2);
    unsigned short* z0bf = xbf + (size_t)N0c * 128;
    unsigned short* g1bf = xbf;                         // alias (xbf,z0bf dead)
    // region2: [g0bf | z1bf] (30.72 MB total)
    unsigned short* g0bf = (unsigned short*)carve((size_t)N0c * 256 * 4);
    unsigned short* z1bf = g0bf + (size_t)N0c * 256;

    unsigned short* Wt0 = (unsigned short*)carve((size_t)256 * 128 * 2);
    unsigned short* Wt1 = (unsigned short*)carve((size_t)256 * 256 * 2);
    float* sc0 = (float*)carve(256 * 4);
    float* sh0 = (float*)carve(256 * 4);
    float* sc1 = (float*)carve(256 * 4);
    float* sh1 = (float*)carve(256 * 4);

    int*   start0 = (int*)  carve((size_t)(N1c + 1) * 4);
    int*   cnt0   = (int*)  carve((size_t)N1c * 4);
    float* pmean  = (float*)carve((size_t)N1c * 256 * 4);
    float* xp     = (float*)carve((size_t)N1c * 256 * 4);
    float* xb     = (float*)carve((size_t)N1c * 17 * 4);
    int*   bpool  = (int*)  carve((size_t)N1c * 4);
    unsigned short* hbbbf = (unsigned short*)carve((size_t)N1c * 256 * 2);
    float* zbb    = (float*)carve((size_t)N1c * 256 * 4);
    float* part   = (float*)carve((size_t)256 * 256 * 4);
    int*   pcnt   = (int*)  carve((size_t)256 * 4);

    const int* src0 = ei;
    const int* dst0 = ei + E0c;
    const int* src1 = eip;
    const int* dst1 = eip + E1c;

    // ---- CSR build: bucket sort, zero global atomics ----
    prep1<<<P1_CNT + P1_CVT + P1_PW + P1_SEG, 256, 0, stream>>>(
        dst0, dst1, blockhist, x, xbf, W_in0, W_h0, b0, g0, be0, m0, v0,
        Wt0, Wt1, sc0, sh0, sc1, sh1, pool1, start0);
    scanh_block<<<NBKT, 256, 0, stream>>>(blockhist, hx, bktSum);
    scanh_sums<<<1, 256, 0, stream>>>(bktSum, bktOff);
    scatter_e<<<NSCB, 256, 0, stream>>>(src0, dst0, src1, dst1, hx, bktOff, ebkt);
    int nb = cdiv_i(NALL, 256);                         // 129
    count_scan_n<<<nb, 256, 0, stream>>>(ebkt, bktOff, NALL, rp, blkSum, dinv);
    scan_sums<<<1, 256, 0, stream>>>(blkSum, nb, blkOff, rp, NALL);
    fill_csr<<<NBKT + FILL_TAIL + FILL_CLST, 256, 0, stream>>>(
        ebkt, bktOff, rp, blkOff, dinv, csw, rpf, start0, batch, cnt0, bpool);

    const int*   rp1   = rpf + N0c;
    const float* dinv1 = dinv + N0c;

    // ---- phase A: 3 GCN layers on N0 (layers 0/1: bf16 MFMA path) ----
    agg_bf16<16, 2, true><<<2 * cdiv_i(N0c, 8), 256, 0, stream>>>(xbf, rpf, csw, dinv, z0bf, N0c);
    gemm_mfma_bn<128><<<cdiv_i(N0c, 64), 256, 0, stream>>>(z0bf, Wt0, sc0, sh0, g0bf, N0c);
    agg_bf16<32, 4, true><<<4 * cdiv_i(N0c, 8), 256, 0, stream>>>(g0bf, rpf, csw, dinv, z1bf, N0c);
    gemm_mfma_bn<256><<<cdiv_i(N0c, 64), 256, 0, stream>>>(z1bf, Wt1, sc1, sh1, g1bf, N0c);

    // layer 2: FUSED agg+mean-pool straight into 3000 cluster rows (r20/r21)
    agg_pool<4><<<4 * cdiv_i(N1c, 4), 256, 0, stream>>>(g1bf, rpf, csw, dinv,
                                                        start0, pmean, N1c);
    gemm_bn<256, false, true, false><<<dim3(cdiv_i(N1c, 64), 4), 256, 0, stream>>>(
        pmean, W_h0 + Hc * Hc, b0 + 2 * Hc, g0 + 2 * Hc, be0 + 2 * Hc, m0 + 2 * Hc,
        v0 + 2 * Hc, cnt0, xp, N1c);

    // head0: logits + softmax -> d_out[0:48000], xb = [x0 | x_pool1]
    head0<<<N1c, 64, 0, stream>>>(xp, linW0, linb0, x_pool1, outp, xb);

    // ---- phase B: 3 GCN layers on N1 (fp32 vector GEMMs) ----
    agg17_gemm_bn<<<N1c, 256, 0, stream>>>(xb, rp1, csw, dinv1, W_in1, b1, g1, be1,
                                           m1, v1, hbbbf);
    agg_bf16<32, 4, false><<<4 * cdiv_i(N1c, 8), 256, 0, stream>>>(hbbbf, rp1, csw, dinv1, zbb, N1c);
    gemm_bn<256, true, false, true><<<dim3(cdiv_i(N1c, 64), 4), 256, 0, stream>>>(
        zbb, W_h1, b1 + Hc, g1 + Hc, be1 + Hc, m1 + Hc, v1 + Hc, nullptr, hbbbf, N1c);
    agg_bf16<32, 4, false><<<4 * cdiv_i(N1c, 8), 256, 0, stream>>>(hbbbf, rp1, csw, dinv1, zbb, N1c);

    // atomic-free 3000->16 reduction: 256-block partials, then head1 combines
    pool_b_partial<<<256, 256, 0, stream>>>(zbb, bpool, part, pcnt);
    head1<<<Bc, 256, 0, stream>>>(part, pcnt, W_h1 + Hc * Hc, b1 + 2 * Hc, g1 + 2 * Hc,
                                  be1 + 2 * Hc, m1 + 2 * Hc, v1 + 2 * Hc, linW1, linb1,
                                  outp);
}